// Round 1
// 2989.536 us; speedup vs baseline: 1.1605x; 1.1605x over previous
//
#include <hip/hip_runtime.h>

#define BATCH 32
#define HW_ 900
#define NL_ 20
#define DIM_ 512
#define LIN_ 768
#define SPAD 912        // S row stride (zero-padded cols 900..911)

#define BM 128
#define BN 64
#define BK 32

// ---------------------------------------------------------------------------
// f32 TN GEMM: C = act( A1*W1^T [+ A2*W2^T] + b1 [+ b2] )  [+ C_prev if ADDC]
// A (M x K) lda, W (N x K) row-major ldw. 128x64 tile, BK=32, 256 threads,
// 8x4 acc per thread, register prefetch of next K-tile.
// Requires K % 32 == 0, N % 4 == 0.
// ADDC=1: epilogue reads existing C and adds it (C += act(...)).
// ---------------------------------------------------------------------------
template<int ACT, int PAIRS, int ADDC>
__global__ __launch_bounds__(256)
void sgemm_tn(const float* __restrict__ A1, const float* __restrict__ W1,
              const float* __restrict__ A2, const float* __restrict__ W2,
              const float* __restrict__ b1, const float* __restrict__ b2,
              float* __restrict__ C,
              int M, int N, int K1, int lda, int ldw,
              int K2, int lda2, int ldw2, int ldc)
{
  __shared__ float As[BK][BM + 4];   // 16896 B
  __shared__ float Ws[BK][BN + 4];   // 8704 B
  const int m0 = blockIdx.x * BM, n0 = blockIdx.y * BN;
  const int tid = threadIdx.x;
  const int arow = tid >> 1, ak = (tid & 1) * 16;   // A: 128 rows x 32k, 16 f/thread
  const int wrow = tid & 63, wk = (tid >> 6) * 8;   // W: 64 rows x 32k, 8 f/thread
  const int cx = tid & 15, ry = tid >> 4;
  float acc[8][4] = {};

  for (int p = 0; p < PAIRS; ++p) {
    const float* A = p ? A2 : A1;
    const float* W = p ? W2 : W1;
    const int la = p ? lda2 : lda, lw = p ? ldw2 : ldw, K = p ? K2 : K1;
    const int gm = m0 + arow, gn = n0 + wrow;
    const float* ap = A + (long)gm * la + ak;
    const float* wp = W + (long)gn * lw + wk;
    const bool aok = gm < M, wok = gn < N;
    float4 a[4], w[2];
    #pragma unroll
    for (int j = 0; j < 4; ++j)
      a[j] = aok ? *(const float4*)(ap + j * 4) : make_float4(0, 0, 0, 0);
    #pragma unroll
    for (int j = 0; j < 2; ++j)
      w[j] = wok ? *(const float4*)(wp + j * 4) : make_float4(0, 0, 0, 0);
    for (int kb = 0; kb < K; kb += BK) {
      __syncthreads();
      #pragma unroll
      for (int j = 0; j < 4; ++j) {
        As[ak + j * 4 + 0][arow] = a[j].x; As[ak + j * 4 + 1][arow] = a[j].y;
        As[ak + j * 4 + 2][arow] = a[j].z; As[ak + j * 4 + 3][arow] = a[j].w;
      }
      #pragma unroll
      for (int j = 0; j < 2; ++j) {
        Ws[wk + j * 4 + 0][wrow] = w[j].x; Ws[wk + j * 4 + 1][wrow] = w[j].y;
        Ws[wk + j * 4 + 2][wrow] = w[j].z; Ws[wk + j * 4 + 3][wrow] = w[j].w;
      }
      __syncthreads();
      if (kb + BK < K) {   // prefetch next tile into regs (overlaps compute)
        #pragma unroll
        for (int j = 0; j < 4; ++j)
          a[j] = aok ? *(const float4*)(ap + kb + BK + j * 4) : make_float4(0,0,0,0);
        #pragma unroll
        for (int j = 0; j < 2; ++j)
          w[j] = wok ? *(const float4*)(wp + kb + BK + j * 4) : make_float4(0,0,0,0);
      }
      #pragma unroll
      for (int k = 0; k < BK; ++k) {
        float4 av0 = *(const float4*)&As[k][ry * 8];
        float4 av1 = *(const float4*)&As[k][ry * 8 + 4];
        float4 bv  = *(const float4*)&Ws[k][cx * 4];
        float aa[8] = {av0.x, av0.y, av0.z, av0.w, av1.x, av1.y, av1.z, av1.w};
        float bb[4] = {bv.x, bv.y, bv.z, bv.w};
        #pragma unroll
        for (int i = 0; i < 8; ++i)
          #pragma unroll
          for (int j = 0; j < 4; ++j) acc[i][j] += aa[i] * bb[j];
      }
    }
  }

  const int gn = n0 + cx * 4;
  if (gn >= N) return;
  float bs[4] = {0, 0, 0, 0};
  if (b1) { for (int j = 0; j < 4; ++j) bs[j] += b1[gn + j]; }
  if (PAIRS == 2 && b2) { for (int j = 0; j < 4; ++j) bs[j] += b2[gn + j]; }
  #pragma unroll
  for (int i = 0; i < 8; ++i) {
    int gm = m0 + ry * 8 + i;
    if (gm >= M) continue;
    float4 prev;
    if (ADDC) prev = *(const float4*)(C + (long)gm * ldc + gn);
    float ov[4];
    #pragma unroll
    for (int j = 0; j < 4; ++j) {
      float xv = acc[i][j] + bs[j];
      if (ACT == 1) xv = fmaxf(xv, 0.f);
      if (ACT == 2) xv = tanhf(xv);
      ov[j] = xv;
    }
    if (ADDC) { ov[0] += prev.x; ov[1] += prev.y; ov[2] += prev.z; ov[3] += prev.w; }
    *(float4*)(C + (long)gm * ldc + gn) = make_float4(ov[0], ov[1], ov[2], ov[3]);
  }
}

// ---------------------------------------------------------------------------
// f32 NN GEMM (out2 = S @ q3), batched via grid.z. (round-5, verified)
// ---------------------------------------------------------------------------
#define NBK 16
__global__ __launch_bounds__(256)
void sgemm_nn(const float* __restrict__ Abuf, const float* __restrict__ Bbuf,
              float* __restrict__ C,
              int M, int N, int K, int Kvalid, int lda, int ldb, int ldc,
              long sA, long sB, long sC)
{
  __shared__ float As[NBK][BM + 4];
  __shared__ float Bs[NBK][BN + 4];
  const int bz = blockIdx.z;
  const float* A = Abuf + (long)bz * sA;
  const float* B = Bbuf + (long)bz * sB;
  float* Cb = C + (long)bz * sC;
  const int m0 = blockIdx.x * BM, n0 = blockIdx.y * BN;
  const int tid = threadIdx.x;
  const int arow = tid >> 1, ak = (tid & 1) * 8;
  const int bk = tid >> 4, bn = (tid & 15) * 4;
  const int cx = tid & 15, ry = tid >> 4;
  float acc[8][4] = {};

  const int gm = m0 + arow;
  const float* ap = A + (long)gm * lda;
  const bool av_ok = gm < M;
  for (int kb = 0; kb < K; kb += NBK) {
    float4 a0 = make_float4(0,0,0,0), a1 = make_float4(0,0,0,0);
    float4 b0 = make_float4(0,0,0,0);
    if (av_ok) { a0 = *(const float4*)(ap + kb + ak);
                 a1 = *(const float4*)(ap + kb + ak + 4); }
    int w = kb + bk;
    if (w < Kvalid) b0 = *(const float4*)(B + (long)w * ldb + n0 + bn);
    __syncthreads();
    As[ak + 0][arow] = a0.x; As[ak + 1][arow] = a0.y;
    As[ak + 2][arow] = a0.z; As[ak + 3][arow] = a0.w;
    As[ak + 4][arow] = a1.x; As[ak + 5][arow] = a1.y;
    As[ak + 6][arow] = a1.z; As[ak + 7][arow] = a1.w;
    *(float4*)&Bs[bk][bn] = b0;
    __syncthreads();
    #pragma unroll
    for (int k = 0; k < NBK; ++k) {
      float4 av0 = *(const float4*)&As[k][ry * 8];
      float4 av1 = *(const float4*)&As[k][ry * 8 + 4];
      float4 bv  = *(const float4*)&Bs[k][cx * 4];
      float aa[8] = {av0.x, av0.y, av0.z, av0.w, av1.x, av1.y, av1.z, av1.w};
      float bb[4] = {bv.x, bv.y, bv.z, bv.w};
      #pragma unroll
      for (int i = 0; i < 8; ++i)
        #pragma unroll
        for (int j = 0; j < 4; ++j) acc[i][j] += aa[i] * bb[j];
    }
  }
  const int gn = n0 + cx * 4;
  #pragma unroll
  for (int i = 0; i < 8; ++i) {
    int g = m0 + ry * 8 + i;
    if (g < M)
      *(float4*)(Cb + (long)g * ldc + gn) =
          make_float4(acc[i][0], acc[i][1], acc[i][2], acc[i][3]);
  }
}

// ---------------------------------------------------------------------------
// Transpose l: Ltr[b][n][c] = l[b][c][n].  One block per b, coalesced reads.
// ---------------------------------------------------------------------------
__global__ __launch_bounds__(256)
void transpose_l(const float* __restrict__ l, float* __restrict__ Ltr)
{
  const int b = blockIdx.x;
  const float* lb = l + (long)b * LIN_ * NL_;
  float* ob = Ltr + (long)b * NL_ * LIN_;
  for (int i = threadIdx.x; i < LIN_ * NL_; i += 256) {
    int c = i / NL_, n = i % NL_;
    ob[(long)n * LIN_ + c] = lb[i];
  }
}

// ---------------------------------------------------------------------------
// Fused language attention over NL=20 tokens (f32).  (round-5, verified)
// ---------------------------------------------------------------------------
__global__ __launch_bounds__(256)
void attn_kernel(const float* __restrict__ Q, const float* __restrict__ Lt,
                 const float* __restrict__ lmask, float* __restrict__ O,
                 int bbase)
{
  __shared__ float lt[NL_ * DIM_];
  __shared__ float smask[NL_];
  const int bg = blockIdx.y, b = bbase + bg;
  const int tid = threadIdx.x;
  const float* Lb = Lt + (long)b * NL_ * DIM_;
  for (int i = tid; i < NL_ * DIM_ / 4; i += 256)
    *(float4*)&lt[i * 4] = *(const float4*)&Lb[i * 4];
  if (tid < NL_) smask[tid] = 10000.f * lmask[b * NL_ + tid] - 10000.f;
  __syncthreads();
  const int wid = tid >> 6, lane = tid & 63;
  for (int rr = 0; rr < 2; ++rr) {
    int h = blockIdx.x * 8 + wid * 2 + rr;
    if (h >= HW_) continue;
    long grow = ((long)bg * HW_ + h) * DIM_;
    float4 q0 = *(const float4*)&Q[grow + lane * 8];
    float4 q1 = *(const float4*)&Q[grow + lane * 8 + 4];
    float sim[NL_];
    for (int n = 0; n < NL_; ++n) {
      const float* lv = &lt[n * DIM_ + lane * 8];
      float4 l0 = *(const float4*)lv, l1 = *(const float4*)(lv + 4);
      float d = q0.x * l0.x + q0.y * l0.y + q0.z * l0.z + q0.w * l0.w
              + q1.x * l1.x + q1.y * l1.y + q1.z * l1.z + q1.w * l1.w;
      #pragma unroll
      for (int m = 32; m >= 1; m >>= 1) d += __shfl_xor(d, m, 64);
      sim[n] = d + smask[n];
    }
    float mx = sim[0];
    #pragma unroll
    for (int n = 1; n < NL_; ++n) mx = fmaxf(mx, sim[n]);
    float s = 0.f;
    #pragma unroll
    for (int n = 0; n < NL_; ++n) { sim[n] = expf(sim[n] - mx); s += sim[n]; }
    float inv = 1.f / s;
    float o[8] = {0, 0, 0, 0, 0, 0, 0, 0};
    for (int n = 0; n < NL_; ++n) {
      float pn = sim[n] * inv;
      const float* lv = &lt[n * DIM_ + lane * 8];
      float4 l0 = *(const float4*)lv, l1 = *(const float4*)(lv + 4);
      o[0] += pn * l0.x; o[1] += pn * l0.y; o[2] += pn * l0.z; o[3] += pn * l0.w;
      o[4] += pn * l1.x; o[5] += pn * l1.y; o[6] += pn * l1.z; o[7] += pn * l1.w;
    }
    *(float4*)&O[grow + lane * 8] = make_float4(o[0], o[1], o[2], o[3]);
    *(float4*)&O[grow + lane * 8 + 4] = make_float4(o[4], o[5], o[6], o[7]);
  }
}

// ---------------------------------------------------------------------------
// Row softmax over 900 cols (stride SPAD); zeroes pad cols. One block/row.
// ---------------------------------------------------------------------------
__global__ __launch_bounds__(256)
void softmax_rows(float* __restrict__ S)
{
  __shared__ float red[4];
  float* p = S + (long)blockIdx.x * SPAD;
  const int tid = threadIdx.x, lane = tid & 63, wid = tid >> 6;
  float vals[4];
  float mx = -1e30f;
  #pragma unroll
  for (int i = 0; i < 4; ++i) {
    int idx = tid + i * 256;
    vals[i] = (idx < HW_) ? p[idx] : -1e30f;
    mx = fmaxf(mx, vals[i]);
  }
  #pragma unroll
  for (int m = 32; m >= 1; m >>= 1) mx = fmaxf(mx, __shfl_xor(mx, m, 64));
  if (lane == 0) red[wid] = mx;
  __syncthreads();
  mx = fmaxf(fmaxf(red[0], red[1]), fmaxf(red[2], red[3]));
  __syncthreads();
  float s = 0.f;
  #pragma unroll
  for (int i = 0; i < 4; ++i) {
    int idx = tid + i * 256;
    if (idx < HW_) { vals[i] = expf(vals[i] - mx); s += vals[i]; }
  }
  #pragma unroll
  for (int m = 32; m >= 1; m >>= 1) s += __shfl_xor(s, m, 64);
  if (lane == 0) red[wid] = s;
  __syncthreads();
  float inv = 1.f / (red[0] + red[1] + red[2] + red[3]);
  #pragma unroll
  for (int i = 0; i < 4; ++i) {
    int idx = tid + i * 256;
    if (idx < HW_) p[idx] = vals[i] * inv;
  }
  if (tid < SPAD - HW_) p[HW_ + tid] = 0.f;
}

// ---------------------------------------------------------------------------
__global__ void diag_kernel(float* out, long n, float ws_mb)
{
  long i = (long)blockIdx.x * 256 + threadIdx.x;
  if (i < n) out[i] = 0.f;
  if (i == 0) out[0] = ws_mb;
}

// ---------------------------------------------------------------------------
static size_t ws_need(int NB) {
  return (2 * (size_t)NB * HW_ * DIM_              // O + Ap
          + (size_t)(NB / 2) * HW_ * SPAD          // S (half-chunk)
          + (size_t)BATCH * NL_ * DIM_             // Lt
          + (size_t)BATCH * NL_ * LIN_) * 4;       // Ltr
}

extern "C" void kernel_launch(void* const* d_in, const int* in_sizes, int n_in,
                              void* d_out, int out_size, void* d_ws, size_t ws_size,
                              hipStream_t stream) {
  const float* x      = (const float*)d_in[0];
  const float* l      = (const float*)d_in[1];
  const float* lmask  = (const float*)d_in[2];
  const float* W_lang = (const float*)d_in[3];
  const float* b_lang = (const float*)d_in[4];
  const float* W_v1   = (const float*)d_in[5];  const float* b_v1   = (const float*)d_in[6];
  const float* W_v2   = (const float*)d_in[7];  const float* b_v2   = (const float*)d_in[8];
  const float* W_v3   = (const float*)d_in[9];  const float* b_v3   = (const float*)d_in[10];
  const float* W_v4   = (const float*)d_in[11]; const float* b_v4   = (const float*)d_in[12];
  const float* W_out1 = (const float*)d_in[13]; const float* b_out1 = (const float*)d_in[14];
  const float* W_v22  = (const float*)d_in[15]; const float* b_v22  = (const float*)d_in[16];
  const float* W_a    = (const float*)d_in[17]; const float* b_a    = (const float*)d_in[18];
  const float* W_o3   = (const float*)d_in[19]; const float* b_o3   = (const float*)d_in[20];
  float* out = (float*)d_out;

  // Tier selection by workspace size (constant per process -> graph-safe).
  int NB;
  if      (ws_size >= ws_need(32)) NB = 32;   // 173.9 MB
  else if (ws_size >= ws_need(16)) NB = 16;   //  88.8 MB
  else if (ws_size >= ws_need(8))  NB = 8;    //  46.3 MB (proven safe)
  else {
    long n = (long)out_size;
    diag_kernel<<<dim3((unsigned)((n + 255) / 256)), dim3(256), 0, stream>>>(
        out, n, (float)(ws_size >> 20));
    return;
  }

  const int nChunk = BATCH / NB;
  const int MC = NB * HW_;            // rows per chunk
  const int MHc = (NB / 2) * HW_;     // rows per S half-chunk
  const size_t nC = (size_t)MC * DIM_;          // floats per chunk buffer
  const size_t nS = (size_t)MHc * SPAD;

  float* ws = (float*)d_ws;
  float* O   = ws;
  float* Ap  = O + nC;
  float* S   = Ap + nC;
  float* Lt  = S + nS;
  float* Ltr = Lt + (size_t)BATCH * NL_ * DIM_;

  dim3 blk(256);
  dim3 gq((MC + BM - 1) / BM, DIM_ / BN);
  dim3 gs((MHc + BM - 1) / BM, (HW_ + BN - 1) / BN);
  dim3 go((HW_ + BM - 1) / BM, DIM_ / BN, NB / 2);

  // lt = l^T @ W_lang^T + b_lang  (transpose, then GEMM: M=640, K=768, N=512)
  transpose_l<<<dim3(BATCH), blk, 0, stream>>>(l, Ltr);
  sgemm_tn<0,1,0><<<dim3((BATCH * NL_ + BM - 1) / BM, DIM_ / BN), blk, 0, stream>>>(
      Ltr, W_lang, nullptr, nullptr, b_lang, nullptr, Lt,
      BATCH * NL_, DIM_, LIN_, LIN_, LIN_, 0, 0, 0, DIM_);

  for (int g = 0; g < nChunk; ++g) {
    const float* xg = x + (size_t)g * nC;
    float* outg = out + (size_t)g * nC;
    // q1 = relu(x W_v1^T + b) -> d_out chunk rows
    sgemm_tn<1,1,0><<<gq, blk, 0, stream>>>(
        xg, W_v1, nullptr, nullptr, b_v1, nullptr, outg,
        MC, DIM_, DIM_, DIM_, DIM_, 0, 0, 0, DIM_);
    // attention -> O
    attn_kernel<<<dim3(113, NB), blk, 0, stream>>>(outg, Lt, lmask, O, g * NB);
    // q2 -> d_out
    sgemm_tn<1,1,0><<<gq, blk, 0, stream>>>(
        xg, W_v2, nullptr, nullptr, b_v2, nullptr, outg,
        MC, DIM_, DIM_, DIM_, DIM_, 0, 0, 0, DIM_);
    // Apre = tanh(O W_out1^T + q2 W_v22^T + b + b) -> Ap
    sgemm_tn<2,2,0><<<gq, blk, 0, stream>>>(
        O, W_out1, outg, W_v22, b_out1, b_v22, Ap,
        MC, DIM_, DIM_, DIM_, DIM_, DIM_, DIM_, DIM_, DIM_);
    // q3 = relu(x W_v3^T + b) -> d_out
    sgemm_tn<1,1,0><<<gq, blk, 0, stream>>>(
        xg, W_v3, nullptr, nullptr, b_v3, nullptr, outg,
        MC, DIM_, DIM_, DIM_, DIM_, 0, 0, 0, DIM_);
    // rel_map + out2 per half-chunk (out2 overwrites Ap rows in place)
    for (int h = 0; h < 2; ++h) {
      float* Aph = Ap + (size_t)h * MHc * DIM_;
      const float* Q3h = outg + (size_t)h * MHc * DIM_;
      sgemm_tn<0,1,0><<<gs, blk, 0, stream>>>(
          Aph, W_a, nullptr, nullptr, b_a, nullptr, S,
          MHc, HW_, DIM_, DIM_, DIM_, 0, 0, 0, SPAD);
      softmax_rows<<<dim3(MHc), blk, 0, stream>>>(S);
      sgemm_nn<<<go, blk, 0, stream>>>(
          S, Q3h, Aph, HW_, DIM_, SPAD, HW_, SPAD, DIM_, DIM_,
          (long)HW_ * SPAD, (long)HW_ * DIM_, (long)HW_ * DIM_);
    }
    // q4 = relu(x W_v4^T + b_v4) -> d_out
    sgemm_tn<1,1,0><<<gq, blk, 0, stream>>>(
        xg, W_v4, nullptr, nullptr, b_v4, nullptr, outg,
        MC, DIM_, DIM_, DIM_, DIM_, 0, 0, 0, DIM_);
    // out += relu(out2 Wo3a + O Wo3b + b_o3)  (single accumulator, no spill)
    sgemm_tn<1,2,1><<<gq, blk, 0, stream>>>(
        Ap, W_o3, O, W_o3 + DIM_, b_o3, nullptr, outg,
        MC, DIM_, DIM_, DIM_, 2 * DIM_, DIM_, DIM_, 2 * DIM_, DIM_);
  }
}

// Round 2
// 1222.638 us; speedup vs baseline: 2.8376x; 2.4452x over previous
//
#include <hip/hip_runtime.h>

#define BATCH 32
#define HW_ 900
#define NL_ 20
#define DIM_ 512
#define LIN_ 768
#define SPAD 912        // S row stride (zero-padded cols 900..911)

#define BM 128
#define BN 64

typedef _Float16 half8 __attribute__((ext_vector_type(8)));
typedef _Float16 half4v __attribute__((ext_vector_type(4)));
typedef float f32x4 __attribute__((ext_vector_type(4)));

// ---------------------------------------------------------------------------
// async global->LDS, 16B per lane. LDS dest must be wave-uniform base;
// HW writes base + lane*16. Casts via integer (flat LDS addr low 32 bits are
// the LDS offset; flat global addr == AS1 addr).
// ---------------------------------------------------------------------------
__device__ __forceinline__ void gload16(const void* g, void* l) {
  __builtin_amdgcn_global_load_lds(
      (const __attribute__((address_space(1))) void*)(unsigned long long)g,
      (__attribute__((address_space(3))) void*)(unsigned int)(unsigned long long)l,
      16, 0, 0);
}

// Stage one 128xBK(=32) A-tile + BNTx32 W-tile (f16) into LDS, linear layout
// [rows][32]. Per wave r-round: 16 rows = 1KB contiguous; lane ln ->
// row 16*(w+4r)+(ln>>2), kchunk (ln&3)*8 halfs; LDS lands at base+ln*16B
// which equals the same (row,k) slot. M/N overflow rows read in-bounds-of-ws
// garbage; guarded at the C write.
template<int BNT>
__device__ __forceinline__ void stage_tile(
    const _Float16* __restrict__ A, const _Float16* __restrict__ W,
    _Float16* As, _Float16* Ws, int m0, int n0, int lda, int ldw, int kt,
    int w, int lane)
{
  #pragma unroll
  for (int r = 0; r < 2; ++r) {
    int row = 16 * (w + 4 * r) + (lane >> 2);
    const _Float16* gp = A + (long)(m0 + row) * lda + kt * 32 + (lane & 3) * 8;
    gload16(gp, As + (w + 4 * r) * 512);
  }
  #pragma unroll
  for (int r = 0; r < BNT / 64; ++r) {
    int row = 16 * (w + 4 * r) + (lane >> 2);
    const _Float16* gp = W + (long)(n0 + row) * ldw + kt * 32 + (lane & 3) * 8;
    gload16(gp, Ws + (w + 4 * r) * 512);
  }
}

// One BK=32 step: FRx4 fragments, mfma 16x16x32 f16.
// A-frag: lane -> row (l&15), k 8*(l>>4)+i  (contiguous 16B per lane,
// 16-row slab = contiguous 1KB -> conflict-free ds_read_b128).
template<int FR>
__device__ __forceinline__ void comp_tile(
    const _Float16* As, const _Float16* Ws, int wr0, int wc0, int lane,
    f32x4 (&acc)[FR][4])
{
  half8 af[FR], wf[4];
  const int lo = (lane & 15) * 32 + (lane >> 4) * 8;
  #pragma unroll
  for (int i = 0; i < FR; ++i)
    af[i] = *(const half8*)&As[(wr0 + 16 * i) * 32 + lo];
  #pragma unroll
  for (int j = 0; j < 4; ++j)
    wf[j] = *(const half8*)&Ws[(wc0 + 16 * j) * 32 + lo];
  #pragma unroll
  for (int i = 0; i < FR; ++i)
    #pragma unroll
    for (int j = 0; j < 4; ++j)
      acc[i][j] = __builtin_amdgcn_mfma_f32_16x16x32_f16(af[i], wf[j], acc[i][j], 0, 0, 0);
}

// ---------------------------------------------------------------------------
// f16-in / f32-acc TN GEMM: C = act( sum_p A_p * W_p^T + b1 [+ b2] )
// SPLITQ (final): passes 0,1 -> accM; pass 2 -> accQ;
//                 C = relu(accM+b1) + relu(accQ+b2), f32 out.
// BNT=128: 4 waves as 2x2, each 64x64 (FR=4). BNT=64: 4 waves stacked rows,
// each 32x64 (FR=2). BK=32, double-buffered LDS, global_load_lds staging.
// C/D layout (verified m89/m91): col = lane&15, row = (lane>>4)*4 + reg.
// ---------------------------------------------------------------------------
template<int ACT, int NPASS, int SPLITQ, int OUTF16, int BNT>
__global__ __launch_bounds__(256)
void mfma_tn(const _Float16* __restrict__ A1, const _Float16* __restrict__ W1,
             const _Float16* __restrict__ A2, const _Float16* __restrict__ W2,
             const _Float16* __restrict__ A3, const _Float16* __restrict__ W3,
             const float* __restrict__ b1, const float* __restrict__ b2,
             void* __restrict__ Cv,
             int M, int N, int K1, int lda1, int ldw1,
             int K2, int lda2, int ldw2, int K3, int lda3, int ldw3, int ldc)
{
  constexpr int FR = (BNT == 128) ? 4 : 2;
  __shared__ _Float16 AsB[2][128 * 32];
  __shared__ _Float16 WsB[2][BNT * 32];
  const int tid = threadIdx.x, w = tid >> 6, lane = tid & 63;
  const int m0 = blockIdx.x * 128, n0 = blockIdx.y * BNT;
  const int wr0 = (BNT == 128) ? (w >> 1) * 64 : w * 32;
  const int wc0 = (BNT == 128) ? (w & 1) * 64 : 0;
  f32x4 acc[FR][4] = {};
  f32x4 acc2[FR][4] = {};
  int cur = 0;

  #pragma unroll
  for (int p = 0; p < NPASS; ++p) {
    const _Float16* A = (p == 0) ? A1 : (p == 1) ? A2 : A3;
    const _Float16* W = (p == 0) ? W1 : (p == 1) ? W2 : W3;
    const int K   = (p == 0) ? K1   : (p == 1) ? K2   : K3;
    const int lda = (p == 0) ? lda1 : (p == 1) ? lda2 : lda3;
    const int ldw = (p == 0) ? ldw1 : (p == 1) ? ldw2 : ldw3;
    const int NT = K / 32;
    stage_tile<BNT>(A, W, AsB[cur], WsB[cur], m0, n0, lda, ldw, 0, w, lane);
    for (int kt = 0; kt < NT; ++kt) {
      __syncthreads();  // drains vmcnt -> buf[cur] loaded; lgkm -> prior reads done
      if (kt + 1 < NT)
        stage_tile<BNT>(A, W, AsB[cur ^ 1], WsB[cur ^ 1], m0, n0, lda, ldw, kt + 1, w, lane);
      if (SPLITQ && p == 2) comp_tile<FR>(AsB[cur], WsB[cur], wr0, wc0, lane, acc2);
      else                  comp_tile<FR>(AsB[cur], WsB[cur], wr0, wc0, lane, acc);
      cur ^= 1;
    }
  }

  const int cb = n0 + wc0 + (lane & 15);
  const int r0 = m0 + wr0 + (lane >> 4) * 4;
  #pragma unroll
  for (int j = 0; j < 4; ++j) {
    int col = cb + j * 16;
    if (col >= N) continue;
    float bv1 = b1 ? b1[col] : 0.f;
    float bv2 = (NPASS == 2 && b2) ? b2[col] : 0.f;
    float bq  = (SPLITQ && b2) ? b2[col] : 0.f;
    #pragma unroll
    for (int i = 0; i < FR; ++i) {
      #pragma unroll
      for (int jj = 0; jj < 4; ++jj) {
        int row = r0 + i * 16 + jj;
        if (row >= M) continue;
        float v = acc[i][j][jj] + bv1 + bv2;
        if (SPLITQ) v = fmaxf(v, 0.f) + fmaxf(acc2[i][j][jj] + bq, 0.f);
        else if (ACT == 1) v = fmaxf(v, 0.f);
        else if (ACT == 2) v = tanhf(v);
        if (OUTF16) ((_Float16*)Cv)[(long)row * ldc + col] = (_Float16)v;
        else        ((float*)Cv)[(long)row * ldc + col] = v;
      }
    }
  }
}

// ---------------------------------------------------------------------------
// f32 NN GEMM (out2 = S @ q3), batched via grid.z; f16 output (feeds MFMA).
// ---------------------------------------------------------------------------
#define NBK 16
__global__ __launch_bounds__(256)
void sgemm_nn(const float* __restrict__ Abuf, const float* __restrict__ Bbuf,
              _Float16* __restrict__ C,
              int M, int N, int K, int Kvalid, int lda, int ldb, int ldc,
              long sA, long sB, long sC)
{
  __shared__ float As[NBK][BM + 4];
  __shared__ float Bs[NBK][BN + 4];
  const int bz = blockIdx.z;
  const float* A = Abuf + (long)bz * sA;
  const float* B = Bbuf + (long)bz * sB;
  _Float16* Cb = C + (long)bz * sC;
  const int m0 = blockIdx.x * BM, n0 = blockIdx.y * BN;
  const int tid = threadIdx.x;
  const int arow = tid >> 1, ak = (tid & 1) * 8;
  const int bk = tid >> 4, bn = (tid & 15) * 4;
  const int cx = tid & 15, ry = tid >> 4;
  float acc[8][4] = {};

  const int gm = m0 + arow;
  const float* ap = A + (long)gm * lda;
  const bool av_ok = gm < M;
  for (int kb = 0; kb < K; kb += NBK) {
    float4 a0 = make_float4(0,0,0,0), a1 = make_float4(0,0,0,0);
    float4 b0 = make_float4(0,0,0,0);
    if (av_ok) { a0 = *(const float4*)(ap + kb + ak);
                 a1 = *(const float4*)(ap + kb + ak + 4); }
    int ww = kb + bk;
    if (ww < Kvalid) b0 = *(const float4*)(B + (long)ww * ldb + n0 + bn);
    __syncthreads();
    As[ak + 0][arow] = a0.x; As[ak + 1][arow] = a0.y;
    As[ak + 2][arow] = a0.z; As[ak + 3][arow] = a0.w;
    As[ak + 4][arow] = a1.x; As[ak + 5][arow] = a1.y;
    As[ak + 6][arow] = a1.z; As[ak + 7][arow] = a1.w;
    *(float4*)&Bs[bk][bn] = b0;
    __syncthreads();
    #pragma unroll
    for (int k = 0; k < NBK; ++k) {
      float4 av0 = *(const float4*)&As[k][ry * 8];
      float4 av1 = *(const float4*)&As[k][ry * 8 + 4];
      float4 bv  = *(const float4*)&Bs[k][cx * 4];
      float aa[8] = {av0.x, av0.y, av0.z, av0.w, av1.x, av1.y, av1.z, av1.w};
      float bb[4] = {bv.x, bv.y, bv.z, bv.w};
      #pragma unroll
      for (int i = 0; i < 8; ++i)
        #pragma unroll
        for (int j = 0; j < 4; ++j) acc[i][j] += aa[i] * bb[j];
    }
  }
  const int gn = n0 + cx * 4;
  #pragma unroll
  for (int i = 0; i < 8; ++i) {
    int g = m0 + ry * 8 + i;
    if (g < M) {
      half4v hv;
      hv[0] = (_Float16)acc[i][0]; hv[1] = (_Float16)acc[i][1];
      hv[2] = (_Float16)acc[i][2]; hv[3] = (_Float16)acc[i][3];
      *(half4v*)(Cb + (long)g * ldc + gn) = hv;
    }
  }
}

// ---------------------------------------------------------------------------
// Transpose l -> f16: Ltr[b][n][c] = (f16) l[b][c][n].
// ---------------------------------------------------------------------------
__global__ __launch_bounds__(256)
void transpose_l(const float* __restrict__ l, _Float16* __restrict__ Ltr)
{
  const int b = blockIdx.x;
  const float* lb = l + (long)b * LIN_ * NL_;
  _Float16* ob = Ltr + (long)b * NL_ * LIN_;
  for (int i = threadIdx.x; i < LIN_ * NL_; i += 256) {
    int c = i / NL_, n = i % NL_;
    ob[(long)n * LIN_ + c] = (_Float16)lb[i];
  }
}

// ---------------------------------------------------------------------------
// Fused language attention over NL=20 tokens; Q,Lt f32 in, O f16 out.
// ---------------------------------------------------------------------------
__global__ __launch_bounds__(256)
void attn_kernel(const float* __restrict__ Q, const float* __restrict__ Lt,
                 const float* __restrict__ lmask, _Float16* __restrict__ O,
                 int bbase)
{
  __shared__ float lt[NL_ * DIM_];
  __shared__ float smask[NL_];
  const int bg = blockIdx.y, b = bbase + bg;
  const int tid = threadIdx.x;
  const float* Lb = Lt + (long)b * NL_ * DIM_;
  for (int i = tid; i < NL_ * DIM_ / 4; i += 256)
    *(float4*)&lt[i * 4] = *(const float4*)&Lb[i * 4];
  if (tid < NL_) smask[tid] = 10000.f * lmask[b * NL_ + tid] - 10000.f;
  __syncthreads();
  const int wid = tid >> 6, lane = tid & 63;
  for (int rr = 0; rr < 2; ++rr) {
    int h = blockIdx.x * 8 + wid * 2 + rr;
    if (h >= HW_) continue;
    long grow = ((long)bg * HW_ + h) * DIM_;
    float4 q0 = *(const float4*)&Q[grow + lane * 8];
    float4 q1 = *(const float4*)&Q[grow + lane * 8 + 4];
    float sim[NL_];
    for (int n = 0; n < NL_; ++n) {
      const float* lv = &lt[n * DIM_ + lane * 8];
      float4 l0 = *(const float4*)lv, l1 = *(const float4*)(lv + 4);
      float d = q0.x * l0.x + q0.y * l0.y + q0.z * l0.z + q0.w * l0.w
              + q1.x * l1.x + q1.y * l1.y + q1.z * l1.z + q1.w * l1.w;
      #pragma unroll
      for (int m = 32; m >= 1; m >>= 1) d += __shfl_xor(d, m, 64);
      sim[n] = d + smask[n];
    }
    float mx = sim[0];
    #pragma unroll
    for (int n = 1; n < NL_; ++n) mx = fmaxf(mx, sim[n]);
    float s = 0.f;
    #pragma unroll
    for (int n = 0; n < NL_; ++n) { sim[n] = expf(sim[n] - mx); s += sim[n]; }
    float inv = 1.f / s;
    float o[8] = {0, 0, 0, 0, 0, 0, 0, 0};
    for (int n = 0; n < NL_; ++n) {
      float pn = sim[n] * inv;
      const float* lv = &lt[n * DIM_ + lane * 8];
      float4 l0 = *(const float4*)lv, l1 = *(const float4*)(lv + 4);
      o[0] += pn * l0.x; o[1] += pn * l0.y; o[2] += pn * l0.z; o[3] += pn * l0.w;
      o[4] += pn * l1.x; o[5] += pn * l1.y; o[6] += pn * l1.z; o[7] += pn * l1.w;
    }
    half8 hv;
    #pragma unroll
    for (int k = 0; k < 8; ++k) hv[k] = (_Float16)o[k];
    *(half8*)&O[grow + lane * 8] = hv;
  }
}

// ---------------------------------------------------------------------------
// Row softmax over 900 cols (stride SPAD); zeroes pad cols. One block/row.
// ---------------------------------------------------------------------------
__global__ __launch_bounds__(256)
void softmax_rows(float* __restrict__ S)
{
  __shared__ float red[4];
  float* p = S + (long)blockIdx.x * SPAD;
  const int tid = threadIdx.x, lane = tid & 63, wid = tid >> 6;
  float vals[4];
  float mx = -1e30f;
  #pragma unroll
  for (int i = 0; i < 4; ++i) {
    int idx = tid + i * 256;
    vals[i] = (idx < HW_) ? p[idx] : -1e30f;
    mx = fmaxf(mx, vals[i]);
  }
  #pragma unroll
  for (int m = 32; m >= 1; m >>= 1) mx = fmaxf(mx, __shfl_xor(mx, m, 64));
  if (lane == 0) red[wid] = mx;
  __syncthreads();
  mx = fmaxf(fmaxf(red[0], red[1]), fmaxf(red[2], red[3]));
  __syncthreads();
  float s = 0.f;
  #pragma unroll
  for (int i = 0; i < 4; ++i) {
    int idx = tid + i * 256;
    if (idx < HW_) { vals[i] = expf(vals[i] - mx); s += vals[i]; }
  }
  #pragma unroll
  for (int m = 32; m >= 1; m >>= 1) s += __shfl_xor(s, m, 64);
  if (lane == 0) red[wid] = s;
  __syncthreads();
  float inv = 1.f / (red[0] + red[1] + red[2] + red[3]);
  #pragma unroll
  for (int i = 0; i < 4; ++i) {
    int idx = tid + i * 256;
    if (idx < HW_) p[idx] = vals[i] * inv;
  }
  if (tid < SPAD - HW_) p[HW_ + tid] = 0.f;
}

// ---------------------------------------------------------------------------
// f32 -> f16 converters.
// ---------------------------------------------------------------------------
__global__ __launch_bounds__(256)
void cvt_x(const float* __restrict__ src, _Float16* __restrict__ dst, long n8)
{
  const float4* s4 = (const float4*)src;
  half8* d = (half8*)dst;
  for (long i = (long)blockIdx.x * 256 + threadIdx.x; i < n8;
       i += (long)gridDim.x * 256) {
    float4 u = s4[2 * i], v = s4[2 * i + 1];
    half8 h;
    h[0] = (_Float16)u.x; h[1] = (_Float16)u.y; h[2] = (_Float16)u.z; h[3] = (_Float16)u.w;
    h[4] = (_Float16)v.x; h[5] = (_Float16)v.y; h[6] = (_Float16)v.z; h[7] = (_Float16)v.w;
    d[i] = h;
  }
}

__global__ __launch_bounds__(256)
void cvt_w(const float* s0, const float* s1, const float* s2, const float* s3,
           const float* s4, const float* s5, const float* s6, const float* s7,
           const float* s8, _Float16* __restrict__ dst)
{
  const long off[10] = {0, 262144, 524288, 786432, 1048576, 1310720,
                        1572864, 1966080, 2426880, 2951168};
  const int t = blockIdx.y;
  const float* src;
  switch (t) {
    case 0: src = s0; break; case 1: src = s1; break; case 2: src = s2; break;
    case 3: src = s3; break; case 4: src = s4; break; case 5: src = s5; break;
    case 6: src = s6; break; case 7: src = s7; break; default: src = s8; break;
  }
  long n8 = (off[t + 1] - off[t]) >> 3;
  const float4* s4p = (const float4*)src;
  half8* d = (half8*)(dst + off[t]);
  for (long i = (long)blockIdx.x * 256 + threadIdx.x; i < n8;
       i += (long)gridDim.x * 256) {
    float4 u = s4p[2 * i], v = s4p[2 * i + 1];
    half8 h;
    h[0] = (_Float16)u.x; h[1] = (_Float16)u.y; h[2] = (_Float16)u.z; h[3] = (_Float16)u.w;
    h[4] = (_Float16)v.x; h[5] = (_Float16)v.y; h[6] = (_Float16)v.z; h[7] = (_Float16)v.w;
    d[i] = h;
  }
}

// ---------------------------------------------------------------------------
__global__ void diag_kernel(float* out, long n, float ws_mb)
{
  long i = (long)blockIdx.x * 256 + threadIdx.x;
  if (i < n) out[i] = 0.f;
  if (i == 0) out[0] = ws_mb;
}

// ---------------------------------------------------------------------------
extern "C" void kernel_launch(void* const* d_in, const int* in_sizes, int n_in,
                              void* d_out, int out_size, void* d_ws, size_t ws_size,
                              hipStream_t stream) {
  const float* x      = (const float*)d_in[0];
  const float* l      = (const float*)d_in[1];
  const float* lmask  = (const float*)d_in[2];
  const float* W_lang = (const float*)d_in[3];
  const float* b_lang = (const float*)d_in[4];
  const float* W_v1   = (const float*)d_in[5];  const float* b_v1   = (const float*)d_in[6];
  const float* W_v2   = (const float*)d_in[7];  const float* b_v2   = (const float*)d_in[8];
  const float* W_v3   = (const float*)d_in[9];  const float* b_v3   = (const float*)d_in[10];
  const float* W_v4   = (const float*)d_in[11]; const float* b_v4   = (const float*)d_in[12];
  const float* W_out1 = (const float*)d_in[13]; const float* b_out1 = (const float*)d_in[14];
  const float* W_v22  = (const float*)d_in[15]; const float* b_v22  = (const float*)d_in[16];
  const float* W_a    = (const float*)d_in[17]; const float* b_a    = (const float*)d_in[18];
  const float* W_o3   = (const float*)d_in[19]; const float* b_o3   = (const float*)d_in[20];
  float* out = (float*)d_out;

  // ws layout (f16 activations + f32 S/Lt + f16 weights).  152,426,496 B,
  // fits the granted >= 173.8 MB (tier-32 proven in prior rounds).
  const long NROW = 28800;                    // 32*900
  const long NC16 = NROW * 512;               // halfs per activation buffer
  const size_t need =
      4 * (size_t)NC16 * 2                    // x16,O16,q2h,Ap16
      + (size_t)7200 * SPAD * 4               // S (quarter-chunk, f32)
      + (size_t)640 * 512 * 4                 // Lt f32
      + (size_t)BATCH * NL_ * LIN_ * 2        // Ltr16
      + (size_t)2951168 * 2;                  // weights f16
  if (ws_size < need) {
    long n = (long)out_size;
    diag_kernel<<<dim3((unsigned)((n + 255) / 256)), dim3(256), 0, stream>>>(
        out, n, (float)(ws_size >> 20));
    return;
  }

  _Float16* x16  = (_Float16*)d_ws;
  _Float16* O16  = x16 + NC16;
  _Float16* q2h  = O16 + NC16;
  _Float16* Ap16 = q2h + NC16;
  float* S       = (float*)(Ap16 + NC16);
  float* Lt      = S + 7200L * SPAD;
  _Float16* Ltr16 = (_Float16*)(Lt + 640L * 512);
  _Float16* Wh   = Ltr16 + (long)BATCH * NL_ * LIN_;
  _Float16 *Wv1h = Wh,            *Wv2h = Wh + 262144,  *Wv3h = Wh + 524288,
           *Wv4h = Wh + 786432,   *Wout1h = Wh + 1048576, *Wv22h = Wh + 1310720,
           *Wlangh = Wh + 1572864, *Wah = Wh + 1966080,  *Wo3h = Wh + 2426880;

  dim3 blk(256);

  // conversions
  cvt_x<<<dim3(2048), blk, 0, stream>>>(x, x16, NC16 / 8);
  cvt_w<<<dim3(64, 9), blk, 0, stream>>>(W_v1, W_v2, W_v3, W_v4, W_out1, W_v22,
                                         W_lang, W_a, W_o3, Wh);
  transpose_l<<<dim3(BATCH), blk, 0, stream>>>(l, Ltr16);

  // Lt = Ltr @ W_lang^T + b_lang   (M=640, N=512, K=768) -> f32
  mfma_tn<0,1,0,0,128><<<dim3(5, 4), blk, 0, stream>>>(
      Ltr16, Wlangh, nullptr, nullptr, nullptr, nullptr, b_lang, nullptr, Lt,
      640, 512, 768, 768, 768, 0, 0, 0, 0, 0, 0, 512);

  // q1 = relu(x W_v1^T + b) -> f32 (attn consumes it)
  mfma_tn<1,1,0,0,128><<<dim3(225, 4), blk, 0, stream>>>(
      x16, Wv1h, nullptr, nullptr, nullptr, nullptr, b_v1, nullptr, out,
      28800, 512, 512, 512, 512, 0, 0, 0, 0, 0, 0, 512);

  attn_kernel<<<dim3(113, BATCH), blk, 0, stream>>>(out, Lt, lmask, O16, 0);

  // q2 = relu(x W_v2^T + b) -> f16
  mfma_tn<1,1,0,1,128><<<dim3(225, 4), blk, 0, stream>>>(
      x16, Wv2h, nullptr, nullptr, nullptr, nullptr, b_v2, nullptr, q2h,
      28800, 512, 512, 512, 512, 0, 0, 0, 0, 0, 0, 512);

  // Apre = tanh(O W_out1^T + q2 W_v22^T + b + b) -> f16
  mfma_tn<2,2,0,1,128><<<dim3(225, 4), blk, 0, stream>>>(
      O16, Wout1h, q2h, Wv22h, nullptr, nullptr, b_out1, b_v22, Ap16,
      28800, 512, 512, 512, 512, 512, 512, 512, 0, 0, 0, 512);

  // q3 = relu(x W_v3^T + b) -> f32 (NN consumes it)
  mfma_tn<1,1,0,0,128><<<dim3(225, 4), blk, 0, stream>>>(
      x16, Wv3h, nullptr, nullptr, nullptr, nullptr, b_v3, nullptr, out,
      28800, 512, 512, 512, 512, 0, 0, 0, 0, 0, 0, 512);

  // rel_map + out2 per quarter-chunk (out2 overwrites Ap16 rows, f16)
  for (int qt = 0; qt < 4; ++qt) {
    _Float16* Aph = Ap16 + (long)qt * 7200 * 512;
    const float* Q3h = out + (long)qt * 7200 * 512;
    mfma_tn<0,1,0,0,128><<<dim3(57, 8), blk, 0, stream>>>(
        Aph, Wah, nullptr, nullptr, nullptr, nullptr, b_a, nullptr, S,
        7200, 900, 512, 512, 512, 0, 0, 0, 0, 0, 0, SPAD);
    softmax_rows<<<dim3(7200), blk, 0, stream>>>(S);
    sgemm_nn<<<dim3(8, 8, 8), blk, 0, stream>>>(
        S, Q3h, Aph, 900, 512, SPAD, 900, SPAD, 512, 512,
        (long)900 * SPAD, (long)900 * 512, (long)900 * 512);
  }

  // out = relu(out2 Wo3a + O Wo3b + b_o3) + relu(x Wv4 + b_v4) -> f32
  mfma_tn<0,3,1,0,64><<<dim3(225, 8), blk, 0, stream>>>(
      Ap16, Wo3h, O16, Wo3h + 512, x16, Wv4h, b_o3, b_v4, out,
      28800, 512, 512, 512, 1024, 512, 512, 1024, 512, 512, 512, 512);
}

// Round 3
// 852.376 us; speedup vs baseline: 4.0703x; 1.4344x over previous
//
#include <hip/hip_runtime.h>

#define BATCH 32
#define HW_ 900
#define NL_ 20
#define DIM_ 512
#define LIN_ 768
#define SPAD 928        // S row stride, K-padded to 29*32 (cols 900..927 zero)

typedef _Float16 half8 __attribute__((ext_vector_type(8)));
typedef _Float16 half4v __attribute__((ext_vector_type(4)));
typedef float f32x4 __attribute__((ext_vector_type(4)));

// ---------------------------------------------------------------------------
// async global->LDS, 16B per lane. LDS dest is wave-uniform base; HW writes
// base + lane*16.
// ---------------------------------------------------------------------------
__device__ __forceinline__ void gload16(const void* g, void* l) {
  __builtin_amdgcn_global_load_lds(
      (const __attribute__((address_space(1))) void*)(unsigned long long)g,
      (__attribute__((address_space(3))) void*)(unsigned int)(unsigned long long)l,
      16, 0, 0);
}

// Stage one 128x32 A-tile + BNTx32 W-tile (f16) into LDS, linear [row][32].
template<int BNT>
__device__ __forceinline__ void stage_tile(
    const _Float16* __restrict__ A, const _Float16* __restrict__ W,
    _Float16* As, _Float16* Ws, int m0, int n0, int lda, int ldw, int kt,
    int w, int lane)
{
  #pragma unroll
  for (int r = 0; r < 2; ++r) {
    int row = 16 * (w + 4 * r) + (lane >> 2);
    const _Float16* gp = A + (long)(m0 + row) * lda + kt * 32 + (lane & 3) * 8;
    gload16(gp, As + (w + 4 * r) * 512);
  }
  #pragma unroll
  for (int r = 0; r < BNT / 64; ++r) {
    int row = 16 * (w + 4 * r) + (lane >> 2);
    const _Float16* gp = W + (long)(n0 + row) * ldw + kt * 32 + (lane & 3) * 8;
    gload16(gp, Ws + (w + 4 * r) * 512);
  }
}

// One BK=32 step: FRx4 fragments, mfma 16x16x32 f16.
template<int FR>
__device__ __forceinline__ void comp_tile(
    const _Float16* As, const _Float16* Ws, int wr0, int wc0, int lane,
    f32x4 (&acc)[FR][4])
{
  half8 af[FR], wf[4];
  const int lo = (lane & 15) * 32 + (lane >> 4) * 8;
  #pragma unroll
  for (int i = 0; i < FR; ++i)
    af[i] = *(const half8*)&As[(wr0 + 16 * i) * 32 + lo];
  #pragma unroll
  for (int j = 0; j < 4; ++j)
    wf[j] = *(const half8*)&Ws[(wc0 + 16 * j) * 32 + lo];
  #pragma unroll
  for (int i = 0; i < FR; ++i)
    #pragma unroll
    for (int j = 0; j < 4; ++j)
      acc[i][j] = __builtin_amdgcn_mfma_f32_16x16x32_f16(af[i], wf[j], acc[i][j], 0, 0, 0);
}

// ---------------------------------------------------------------------------
// f16-in / f32-acc TN GEMM: C = act( sum_p A_p * W_p^T + b1 [+ b2] )
// SPLITQ: passes 0,1 -> accM; pass 2 -> accQ; C = relu(accM+b1)+relu(accQ+b2).
// OUTMODE: 0 = f32, 1 = f16, 2 = f16 transposed-batched (q3T):
//   row -> (b = row/900, h = row%900); dst[(b*512 + col)*928 + h] (relu'd).
// C/D layout (verified m89/m91): col = lane&15, row = (lane>>4)*4 + reg.
// ---------------------------------------------------------------------------
template<int ACT, int NPASS, int SPLITQ, int OUTMODE, int BNT>
__global__ __launch_bounds__(256)
void mfma_tn(const _Float16* __restrict__ A1, const _Float16* __restrict__ W1,
             const _Float16* __restrict__ A2, const _Float16* __restrict__ W2,
             const _Float16* __restrict__ A3, const _Float16* __restrict__ W3,
             const float* __restrict__ b1, const float* __restrict__ b2,
             void* __restrict__ Cv,
             int M, int N, int K1, int lda1, int ldw1,
             int K2, int lda2, int ldw2, int K3, int lda3, int ldw3, int ldc)
{
  constexpr int FR = (BNT == 128) ? 4 : 2;
  __shared__ _Float16 AsB[2][128 * 32];
  __shared__ _Float16 WsB[2][BNT * 32];
  const int tid = threadIdx.x, w = tid >> 6, lane = tid & 63;
  const int m0 = blockIdx.x * 128, n0 = blockIdx.y * BNT;
  const int wr0 = (BNT == 128) ? (w >> 1) * 64 : w * 32;
  const int wc0 = (BNT == 128) ? (w & 1) * 64 : 0;
  f32x4 acc[FR][4] = {};
  f32x4 acc2[FR][4] = {};
  int cur = 0;

  #pragma unroll
  for (int p = 0; p < NPASS; ++p) {
    const _Float16* A = (p == 0) ? A1 : (p == 1) ? A2 : A3;
    const _Float16* W = (p == 0) ? W1 : (p == 1) ? W2 : W3;
    const int K   = (p == 0) ? K1   : (p == 1) ? K2   : K3;
    const int lda = (p == 0) ? lda1 : (p == 1) ? lda2 : lda3;
    const int ldw = (p == 0) ? ldw1 : (p == 1) ? ldw2 : ldw3;
    const int NT = K / 32;
    stage_tile<BNT>(A, W, AsB[cur], WsB[cur], m0, n0, lda, ldw, 0, w, lane);
    for (int kt = 0; kt < NT; ++kt) {
      __syncthreads();
      if (kt + 1 < NT)
        stage_tile<BNT>(A, W, AsB[cur ^ 1], WsB[cur ^ 1], m0, n0, lda, ldw, kt + 1, w, lane);
      if (SPLITQ && p == 2) comp_tile<FR>(AsB[cur], WsB[cur], wr0, wc0, lane, acc2);
      else                  comp_tile<FR>(AsB[cur], WsB[cur], wr0, wc0, lane, acc);
      cur ^= 1;
    }
  }

  const int cb = n0 + wc0 + (lane & 15);
  const int r0 = m0 + wr0 + (lane >> 4) * 4;
  #pragma unroll
  for (int j = 0; j < 4; ++j) {
    int col = cb + j * 16;
    if (col >= N) continue;
    float bv1 = b1 ? b1[col] : 0.f;
    float bv2 = (NPASS == 2 && b2) ? b2[col] : 0.f;
    float bq  = (SPLITQ && b2) ? b2[col] : 0.f;
    #pragma unroll
    for (int i = 0; i < FR; ++i) {
      #pragma unroll
      for (int jj = 0; jj < 4; ++jj) {
        int row = r0 + i * 16 + jj;
        if (row >= M) continue;
        float v = acc[i][j][jj] + bv1 + bv2;
        if (SPLITQ) v = fmaxf(v, 0.f) + fmaxf(acc2[i][j][jj] + bq, 0.f);
        else if (ACT == 1) v = fmaxf(v, 0.f);
        else if (ACT == 2) v = tanhf(v);
        if (OUTMODE == 0)      ((float*)Cv)[(long)row * ldc + col] = v;
        else if (OUTMODE == 1) ((_Float16*)Cv)[(long)row * ldc + col] = (_Float16)v;
        else {
          int bb = row / 900, hh = row - bb * 900;
          ((_Float16*)Cv)[((long)bb * 512 + col) * 928 + hh] = (_Float16)v;
        }
      }
    }
  }
}

// ---------------------------------------------------------------------------
// out2 = Sh @ q3  via MFMA, batched over grid.z (8 batches per quarter).
// A = Sh[z] (900x928 f16, rows 900.. pad-read guarded by C-write),
// W = q3T[bq0+z] (512x928 f16, cols 900..927 zeroed), C = f16 900x512.
// ---------------------------------------------------------------------------
__global__ __launch_bounds__(256)
void mfma_out2(const _Float16* __restrict__ Sh, const _Float16* __restrict__ q3T,
               _Float16* __restrict__ C, int bq0)
{
  __shared__ _Float16 AsB[2][128 * 32];
  __shared__ _Float16 WsB[2][128 * 32];
  const int tid = threadIdx.x, w = tid >> 6, lane = tid & 63;
  const int z = blockIdx.z;
  const _Float16* A = Sh + (long)z * 900 * SPAD;
  const _Float16* W = q3T + ((long)(bq0 + z) * 512) * SPAD;
  _Float16* Cz = C + (long)z * 900 * 512;
  const int m0 = blockIdx.x * 128, n0 = blockIdx.y * 128;
  const int wr0 = (w >> 1) * 64, wc0 = (w & 1) * 64;
  f32x4 acc[4][4] = {};
  int cur = 0;
  stage_tile<128>(A, W, AsB[0], WsB[0], m0, n0, SPAD, SPAD, 0, w, lane);
  for (int kt = 0; kt < SPAD / 32; ++kt) {
    __syncthreads();
    if (kt + 1 < SPAD / 32)
      stage_tile<128>(A, W, AsB[cur ^ 1], WsB[cur ^ 1], m0, n0, SPAD, SPAD, kt + 1, w, lane);
    comp_tile<4>(AsB[cur], WsB[cur], wr0, wc0, lane, acc);
    cur ^= 1;
  }
  const int cb = n0 + wc0 + (lane & 15);
  const int r0 = m0 + wr0 + (lane >> 4) * 4;
  #pragma unroll
  for (int j = 0; j < 4; ++j) {
    int col = cb + j * 16;
    #pragma unroll
    for (int i = 0; i < 4; ++i)
      #pragma unroll
      for (int jj = 0; jj < 4; ++jj) {
        int row = r0 + i * 16 + jj;
        if (row < 900)
          Cz[(long)row * 512 + col] = (_Float16)acc[i][j][jj];
      }
  }
}

// ---------------------------------------------------------------------------
// Zero q3T pad cols 900..927 for all (b,d). 16384 rows x 7 half4v.
// ---------------------------------------------------------------------------
__global__ __launch_bounds__(256)
void q3t_pad(_Float16* __restrict__ q3T)
{
  int i = blockIdx.x * 256 + threadIdx.x;      // 0 .. 114688
  int pair = i / 7, c = i - pair * 7;
  if (pair < 32 * 512) {
    half4v z = {};
    *(half4v*)&q3T[(long)pair * SPAD + 900 + c * 4] = z;
  }
}

// ---------------------------------------------------------------------------
// Transpose l -> f16: Ltr[b][n][c] = (f16) l[b][c][n].
// ---------------------------------------------------------------------------
__global__ __launch_bounds__(256)
void transpose_l(const float* __restrict__ l, _Float16* __restrict__ Ltr)
{
  const int b = blockIdx.x;
  const float* lb = l + (long)b * LIN_ * NL_;
  _Float16* ob = Ltr + (long)b * NL_ * LIN_;
  for (int i = threadIdx.x; i < LIN_ * NL_; i += 256) {
    int c = i / NL_, n = i % NL_;
    ob[(long)n * LIN_ + c] = (_Float16)lb[i];
  }
}

// ---------------------------------------------------------------------------
// Fused language attention over NL=20 tokens. Q f16, lt staged f16 in LDS.
// Lane owns dims {lane*4..+3} and {256+lane*4..+3}: consecutive lanes ->
// consecutive 16B/8B -> conflict-free LDS reads (was 4-way, 4.8e7 conflicts).
// ---------------------------------------------------------------------------
__global__ __launch_bounds__(256)
void attn_kernel(const _Float16* __restrict__ Q, const float* __restrict__ Lt,
                 const float* __restrict__ lmask, _Float16* __restrict__ O,
                 int bbase)
{
  __shared__ _Float16 lt[NL_ * DIM_];
  __shared__ float smask[NL_];
  const int bg = blockIdx.y, b = bbase + bg;
  const int tid = threadIdx.x;
  const float* Lb = Lt + (long)b * NL_ * DIM_;
  for (int i = tid; i < NL_ * DIM_ / 8; i += 256) {
    float4 u = *(const float4*)&Lb[i * 8];
    float4 v = *(const float4*)&Lb[i * 8 + 4];
    half8 hh;
    hh[0] = (_Float16)u.x; hh[1] = (_Float16)u.y; hh[2] = (_Float16)u.z; hh[3] = (_Float16)u.w;
    hh[4] = (_Float16)v.x; hh[5] = (_Float16)v.y; hh[6] = (_Float16)v.z; hh[7] = (_Float16)v.w;
    *(half8*)&lt[i * 8] = hh;
  }
  if (tid < NL_) smask[tid] = 10000.f * lmask[b * NL_ + tid] - 10000.f;
  __syncthreads();
  const int wid = tid >> 6, lane = tid & 63;
  const int d0 = lane * 4, d1 = 256 + lane * 4;
  for (int rr = 0; rr < 2; ++rr) {
    int h = blockIdx.x * 8 + wid * 2 + rr;
    if (h >= HW_) continue;
    long grow = ((long)bg * HW_ + h) * DIM_;
    half4v qh0 = *(const half4v*)&Q[grow + d0];
    half4v qh1 = *(const half4v*)&Q[grow + d1];
    float q0[4], q1[4];
    #pragma unroll
    for (int k = 0; k < 4; ++k) { q0[k] = (float)qh0[k]; q1[k] = (float)qh1[k]; }
    float sim[NL_];
    for (int n = 0; n < NL_; ++n) {
      half4v l0 = *(const half4v*)&lt[n * DIM_ + d0];
      half4v l1 = *(const half4v*)&lt[n * DIM_ + d1];
      float d = q0[0] * (float)l0[0] + q0[1] * (float)l0[1]
              + q0[2] * (float)l0[2] + q0[3] * (float)l0[3]
              + q1[0] * (float)l1[0] + q1[1] * (float)l1[1]
              + q1[2] * (float)l1[2] + q1[3] * (float)l1[3];
      #pragma unroll
      for (int m = 32; m >= 1; m >>= 1) d += __shfl_xor(d, m, 64);
      sim[n] = d + smask[n];
    }
    float mx = sim[0];
    #pragma unroll
    for (int n = 1; n < NL_; ++n) mx = fmaxf(mx, sim[n]);
    float s = 0.f;
    #pragma unroll
    for (int n = 0; n < NL_; ++n) { sim[n] = expf(sim[n] - mx); s += sim[n]; }
    float inv = 1.f / s;
    float o0[4] = {0, 0, 0, 0}, o1[4] = {0, 0, 0, 0};
    for (int n = 0; n < NL_; ++n) {
      float pn = sim[n] * inv;
      half4v l0 = *(const half4v*)&lt[n * DIM_ + d0];
      half4v l1 = *(const half4v*)&lt[n * DIM_ + d1];
      #pragma unroll
      for (int k = 0; k < 4; ++k) {
        o0[k] += pn * (float)l0[k];
        o1[k] += pn * (float)l1[k];
      }
    }
    half4v ov0, ov1;
    #pragma unroll
    for (int k = 0; k < 4; ++k) { ov0[k] = (_Float16)o0[k]; ov1[k] = (_Float16)o1[k]; }
    *(half4v*)&O[grow + d0] = ov0;
    *(half4v*)&O[grow + d1] = ov1;
  }
}

// ---------------------------------------------------------------------------
// Row softmax over 900 cols; f32 in (stride SPAD), f16 out + zeroed pad.
// ---------------------------------------------------------------------------
__global__ __launch_bounds__(256)
void softmax_rows(const float* __restrict__ S, _Float16* __restrict__ Sh)
{
  __shared__ float red[4];
  const float* p = S + (long)blockIdx.x * SPAD;
  _Float16* ph = Sh + (long)blockIdx.x * SPAD;
  const int tid = threadIdx.x, lane = tid & 63, wid = tid >> 6;
  float vals[4];
  float mx = -1e30f;
  #pragma unroll
  for (int i = 0; i < 4; ++i) {
    int idx = tid + i * 256;
    vals[i] = (idx < HW_) ? p[idx] : -1e30f;
    mx = fmaxf(mx, vals[i]);
  }
  #pragma unroll
  for (int m = 32; m >= 1; m >>= 1) mx = fmaxf(mx, __shfl_xor(mx, m, 64));
  if (lane == 0) red[wid] = mx;
  __syncthreads();
  mx = fmaxf(fmaxf(red[0], red[1]), fmaxf(red[2], red[3]));
  __syncthreads();
  float s = 0.f;
  #pragma unroll
  for (int i = 0; i < 4; ++i) {
    int idx = tid + i * 256;
    if (idx < HW_) { vals[i] = expf(vals[i] - mx); s += vals[i]; }
  }
  #pragma unroll
  for (int m = 32; m >= 1; m >>= 1) s += __shfl_xor(s, m, 64);
  if (lane == 0) red[wid] = s;
  __syncthreads();
  float inv = 1.f / (red[0] + red[1] + red[2] + red[3]);
  #pragma unroll
  for (int i = 0; i < 4; ++i) {
    int idx = tid + i * 256;
    if (idx < HW_) ph[idx] = (_Float16)(vals[i] * inv);
  }
  if (tid < SPAD - HW_) ph[HW_ + tid] = (_Float16)0.f;
}

// ---------------------------------------------------------------------------
// f32 -> f16 converters.
// ---------------------------------------------------------------------------
__global__ __launch_bounds__(256)
void cvt_x(const float* __restrict__ src, _Float16* __restrict__ dst, long n8)
{
  const float4* s4 = (const float4*)src;
  half8* d = (half8*)dst;
  for (long i = (long)blockIdx.x * 256 + threadIdx.x; i < n8;
       i += (long)gridDim.x * 256) {
    float4 u = s4[2 * i], v = s4[2 * i + 1];
    half8 h;
    h[0] = (_Float16)u.x; h[1] = (_Float16)u.y; h[2] = (_Float16)u.z; h[3] = (_Float16)u.w;
    h[4] = (_Float16)v.x; h[5] = (_Float16)v.y; h[6] = (_Float16)v.z; h[7] = (_Float16)v.w;
    d[i] = h;
  }
}

__global__ __launch_bounds__(256)
void cvt_w(const float* s0, const float* s1, const float* s2, const float* s3,
           const float* s4, const float* s5, const float* s6, const float* s7,
           const float* s8, _Float16* __restrict__ dst)
{
  const long off[10] = {0, 262144, 524288, 786432, 1048576, 1310720,
                        1572864, 1966080, 2426880, 2951168};
  const int t = blockIdx.y;
  const float* src;
  switch (t) {
    case 0: src = s0; break; case 1: src = s1; break; case 2: src = s2; break;
    case 3: src = s3; break; case 4: src = s4; break; case 5: src = s5; break;
    case 6: src = s6; break; case 7: src = s7; break; default: src = s8; break;
  }
  long n8 = (off[t + 1] - off[t]) >> 3;
  const float4* s4p = (const float4*)src;
  half8* d = (half8*)(dst + off[t]);
  for (long i = (long)blockIdx.x * 256 + threadIdx.x; i < n8;
       i += (long)gridDim.x * 256) {
    float4 u = s4p[2 * i], v = s4p[2 * i + 1];
    half8 h;
    h[0] = (_Float16)u.x; h[1] = (_Float16)u.y; h[2] = (_Float16)u.z; h[3] = (_Float16)u.w;
    h[4] = (_Float16)v.x; h[5] = (_Float16)v.y; h[6] = (_Float16)v.z; h[7] = (_Float16)v.w;
    d[i] = h;
  }
}

// ---------------------------------------------------------------------------
__global__ void diag_kernel(float* out, long n, float ws_mb)
{
  long i = (long)blockIdx.x * 256 + threadIdx.x;
  if (i < n) out[i] = 0.f;
  if (i == 0) out[0] = ws_mb;
}

// ---------------------------------------------------------------------------
extern "C" void kernel_launch(void* const* d_in, const int* in_sizes, int n_in,
                              void* d_out, int out_size, void* d_ws, size_t ws_size,
                              hipStream_t stream) {
  const float* x      = (const float*)d_in[0];
  const float* l      = (const float*)d_in[1];
  const float* lmask  = (const float*)d_in[2];
  const float* W_lang = (const float*)d_in[3];
  const float* b_lang = (const float*)d_in[4];
  const float* W_v1   = (const float*)d_in[5];  const float* b_v1   = (const float*)d_in[6];
  const float* W_v2   = (const float*)d_in[7];  const float* b_v2   = (const float*)d_in[8];
  const float* W_v3   = (const float*)d_in[9];  const float* b_v3   = (const float*)d_in[10];
  const float* W_v4   = (const float*)d_in[11]; const float* b_v4   = (const float*)d_in[12];
  const float* W_out1 = (const float*)d_in[13]; const float* b_out1 = (const float*)d_in[14];
  const float* W_v22  = (const float*)d_in[15]; const float* b_v22  = (const float*)d_in[16];
  const float* W_a    = (const float*)d_in[17]; const float* b_a    = (const float*)d_in[18];
  const float* W_o3   = (const float*)d_in[19]; const float* b_o3   = (const float*)d_in[20];
  float* out = (float*)d_out;

  // ws layout, 169,932,800 B total (< proven 173.77 MB grant):
  //   x16, O16, q2h, Ap16 (f16 28800x512 each), q3T (32x512x928 f16),
  //   Lt (f32 640x512), Ltr16, Sh (f16 7200x928), Wh (f16 weights).
  // f32 S scratch (7200x928, 26.7 MB) lives in d_out (free until final GEMM).
  const long NC16 = 28800L * 512;
  const size_t need =
      4 * (size_t)NC16 * 2
      + (size_t)32 * 512 * SPAD * 2
      + (size_t)640 * 512 * 4
      + (size_t)BATCH * NL_ * LIN_ * 2
      + (size_t)7200 * SPAD * 2
      + (size_t)2951168 * 2;
  if (ws_size < need) {
    long n = (long)out_size;
    diag_kernel<<<dim3((unsigned)((n + 255) / 256)), dim3(256), 0, stream>>>(
        out, n, (float)(ws_size >> 20));
    return;
  }

  _Float16* x16  = (_Float16*)d_ws;
  _Float16* O16  = x16 + NC16;
  _Float16* q2h  = O16 + NC16;
  _Float16* Ap16 = q2h + NC16;
  _Float16* q3T  = Ap16 + NC16;
  float* Lt      = (float*)(q3T + 32L * 512 * SPAD);
  _Float16* Ltr16 = (_Float16*)(Lt + 640L * 512);
  _Float16* Sh   = Ltr16 + (long)BATCH * NL_ * LIN_;
  _Float16* Wh   = Sh + 7200L * SPAD;
  _Float16 *Wv1h = Wh,            *Wv2h = Wh + 262144,  *Wv3h = Wh + 524288,
           *Wv4h = Wh + 786432,   *Wout1h = Wh + 1048576, *Wv22h = Wh + 1310720,
           *Wlangh = Wh + 1572864, *Wah = Wh + 1966080,  *Wo3h = Wh + 2426880;
  float* S32 = out;   // d_out as f32 scratch for pre-softmax scores

  dim3 blk(256);

  // conversions + pads
  cvt_x<<<dim3(2048), blk, 0, stream>>>(x, x16, NC16 / 8);
  cvt_w<<<dim3(64, 9), blk, 0, stream>>>(W_v1, W_v2, W_v3, W_v4, W_out1, W_v22,
                                         W_lang, W_a, W_o3, Wh);
  transpose_l<<<dim3(BATCH), blk, 0, stream>>>(l, Ltr16);
  q3t_pad<<<dim3(448), blk, 0, stream>>>(q3T);

  // Lt = Ltr @ W_lang^T + b_lang   (M=640, N=512, K=768) -> f32
  mfma_tn<0,1,0,0,128><<<dim3(5, 4), blk, 0, stream>>>(
      Ltr16, Wlangh, nullptr, nullptr, nullptr, nullptr, b_lang, nullptr, Lt,
      640, 512, 768, 768, 768, 0, 0, 0, 0, 0, 0, 512);

  // q1 = relu(x W_v1^T + b) -> f16 into Ap16 (free until Apre)
  mfma_tn<1,1,0,1,128><<<dim3(225, 4), blk, 0, stream>>>(
      x16, Wv1h, nullptr, nullptr, nullptr, nullptr, b_v1, nullptr, Ap16,
      28800, 512, 512, 512, 512, 0, 0, 0, 0, 0, 0, 512);

  attn_kernel<<<dim3(113, BATCH), blk, 0, stream>>>(Ap16, Lt, lmask, O16, 0);

  // q2 = relu(x W_v2^T + b) -> f16
  mfma_tn<1,1,0,1,128><<<dim3(225, 4), blk, 0, stream>>>(
      x16, Wv2h, nullptr, nullptr, nullptr, nullptr, b_v2, nullptr, q2h,
      28800, 512, 512, 512, 512, 0, 0, 0, 0, 0, 0, 512);

  // Apre = tanh(O W_out1^T + q2 W_v22^T + b + b) -> f16 (overwrites q1)
  mfma_tn<2,2,0,1,128><<<dim3(225, 4), blk, 0, stream>>>(
      O16, Wout1h, q2h, Wv22h, nullptr, nullptr, b_out1, b_v22, Ap16,
      28800, 512, 512, 512, 512, 512, 512, 512, 0, 0, 0, 512);

  // q3T[b][d][w] = relu(x W_v3^T + b)^T  (transposed epilogue, f16)
  mfma_tn<1,1,0,2,128><<<dim3(225, 4), blk, 0, stream>>>(
      x16, Wv3h, nullptr, nullptr, nullptr, nullptr, b_v3, nullptr, q3T,
      28800, 512, 512, 512, 512, 0, 0, 0, 0, 0, 0, 512);

  // rel_map + out2 per quarter (out2 overwrites Ap16 rows, f16)
  for (int qt = 0; qt < 4; ++qt) {
    _Float16* Aph = Ap16 + (long)qt * 7200 * 512;
    mfma_tn<0,1,0,0,128><<<dim3(57, 8), blk, 0, stream>>>(
        Aph, Wah, nullptr, nullptr, nullptr, nullptr, b_a, nullptr, S32,
        7200, 900, 512, 512, 512, 0, 0, 0, 0, 0, 0, SPAD);
    softmax_rows<<<dim3(7200), blk, 0, stream>>>(S32, Sh);
    mfma_out2<<<dim3(8, 4, 8), blk, 0, stream>>>(Sh, q3T, Aph, qt * 8);
  }

  // out = relu(out2 Wo3a + O Wo3b + b_o3) + relu(x Wv4 + b_v4) -> f32
  mfma_tn<0,3,1,0,64><<<dim3(225, 8), blk, 0, stream>>>(
      Ap16, Wo3h, O16, Wo3h + 512, x16, Wv4h, b_o3, b_v4, out,
      28800, 512, 512, 512, 1024, 512, 512, 1024, 512, 512, 512, 512);
}

// Round 4
// 790.590 us; speedup vs baseline: 4.3884x; 1.0782x over previous
//
#include <hip/hip_runtime.h>

#define BATCH 32
#define HW_ 900
#define NL_ 20
#define DIM_ 512
#define LIN_ 768
#define SPAD 928        // S row stride, K-padded to 29*32 (cols 900..927 zero)

typedef _Float16 half8 __attribute__((ext_vector_type(8)));
typedef _Float16 half4v __attribute__((ext_vector_type(4)));
typedef float f32x4 __attribute__((ext_vector_type(4)));

// ---------------------------------------------------------------------------
// XCD-bijective block swizzle (m204 variant): XCD k (= bid%8 under round-robin
// dispatch) gets a CONTIGUOUS range of work-ids; decompose with n fastest so
// each XCD sweeps all n-tiles of one m-panel before moving on -> A-panel stays
// in that XCD's private L2.
// ---------------------------------------------------------------------------
__device__ __forceinline__ void swz2(int& mt, int& nt) {
  const int nm = gridDim.x, nn = gridDim.y;
  const int total = nm * nn;
  const int bid = blockIdx.x + nm * blockIdx.y;
  const int q = total >> 3, r = total & 7;
  const int xcd = bid & 7, idx = bid >> 3;
  const int wg = (xcd < r ? xcd * (q + 1) : r * (q + 1) + (xcd - r) * q) + idx;
  mt = wg / nn; nt = wg - mt * nn;
}

// ---------------------------------------------------------------------------
// async global->LDS, 16B per lane. LDS dest is wave-uniform base; HW writes
// base + lane*16.
// ---------------------------------------------------------------------------
__device__ __forceinline__ void gload16(const void* g, void* l) {
  __builtin_amdgcn_global_load_lds(
      (const __attribute__((address_space(1))) void*)(unsigned long long)g,
      (__attribute__((address_space(3))) void*)(unsigned int)(unsigned long long)l,
      16, 0, 0);
}

// Stage one 128x32 A-tile + BNTx32 W-tile (f16) into LDS, linear [row][32].
template<int BNT>
__device__ __forceinline__ void stage_tile(
    const _Float16* __restrict__ A, const _Float16* __restrict__ W,
    _Float16* As, _Float16* Ws, int m0, int n0, int lda, int ldw, int kt,
    int w, int lane)
{
  #pragma unroll
  for (int r = 0; r < 2; ++r) {
    int row = 16 * (w + 4 * r) + (lane >> 2);
    const _Float16* gp = A + (long)(m0 + row) * lda + kt * 32 + (lane & 3) * 8;
    gload16(gp, As + (w + 4 * r) * 512);
  }
  #pragma unroll
  for (int r = 0; r < BNT / 64; ++r) {
    int row = 16 * (w + 4 * r) + (lane >> 2);
    const _Float16* gp = W + (long)(n0 + row) * ldw + kt * 32 + (lane & 3) * 8;
    gload16(gp, Ws + (w + 4 * r) * 512);
  }
}

// One BK=32 step: FRx4 fragments, mfma 16x16x32 f16.
template<int FR>
__device__ __forceinline__ void comp_tile(
    const _Float16* As, const _Float16* Ws, int wr0, int wc0, int lane,
    f32x4 (&acc)[FR][4])
{
  half8 af[FR], wf[4];
  const int lo = (lane & 15) * 32 + (lane >> 4) * 8;
  #pragma unroll
  for (int i = 0; i < FR; ++i)
    af[i] = *(const half8*)&As[(wr0 + 16 * i) * 32 + lo];
  #pragma unroll
  for (int j = 0; j < 4; ++j)
    wf[j] = *(const half8*)&Ws[(wc0 + 16 * j) * 32 + lo];
  #pragma unroll
  for (int i = 0; i < FR; ++i)
    #pragma unroll
    for (int j = 0; j < 4; ++j)
      acc[i][j] = __builtin_amdgcn_mfma_f32_16x16x32_f16(af[i], wf[j], acc[i][j], 0, 0, 0);
}

// ---------------------------------------------------------------------------
// f16-in / f32-acc TN GEMM: C = act( sum_p A_p * W_p^T + b1 [+ b2] )
// SPLITQ: passes 0,1 -> accM; pass 2 -> accQ; C = relu(accM+b1)+relu(accQ+b2).
// OUTMODE: 0 = f32, 1 = f16.
// C/D layout (verified m89/m91): col = lane&15, row = (lane>>4)*4 + reg.
// ---------------------------------------------------------------------------
template<int ACT, int NPASS, int SPLITQ, int OUTMODE, int BNT>
__global__ __launch_bounds__(256)
void mfma_tn(const _Float16* __restrict__ A1, const _Float16* __restrict__ W1,
             const _Float16* __restrict__ A2, const _Float16* __restrict__ W2,
             const _Float16* __restrict__ A3, const _Float16* __restrict__ W3,
             const float* __restrict__ b1, const float* __restrict__ b2,
             void* __restrict__ Cv,
             int M, int N, int K1, int lda1, int ldw1,
             int K2, int lda2, int ldw2, int K3, int lda3, int ldw3, int ldc)
{
  constexpr int FR = (BNT == 128) ? 4 : 2;
  __shared__ _Float16 AsB[2][128 * 32];
  __shared__ _Float16 WsB[2][BNT * 32];
  const int tid = threadIdx.x, w = tid >> 6, lane = tid & 63;
  int mt, nt;
  swz2(mt, nt);
  const int m0 = mt * 128, n0 = nt * BNT;
  const int wr0 = (BNT == 128) ? (w >> 1) * 64 : w * 32;
  const int wc0 = (BNT == 128) ? (w & 1) * 64 : 0;
  f32x4 acc[FR][4] = {};
  f32x4 acc2[FR][4] = {};
  int cur = 0;

  #pragma unroll
  for (int p = 0; p < NPASS; ++p) {
    const _Float16* A = (p == 0) ? A1 : (p == 1) ? A2 : A3;
    const _Float16* W = (p == 0) ? W1 : (p == 1) ? W2 : W3;
    const int K   = (p == 0) ? K1   : (p == 1) ? K2   : K3;
    const int lda = (p == 0) ? lda1 : (p == 1) ? lda2 : lda3;
    const int ldw = (p == 0) ? ldw1 : (p == 1) ? ldw2 : ldw3;
    const int NT = K / 32;
    stage_tile<BNT>(A, W, AsB[cur], WsB[cur], m0, n0, lda, ldw, 0, w, lane);
    for (int kt = 0; kt < NT; ++kt) {
      __syncthreads();
      if (kt + 1 < NT)
        stage_tile<BNT>(A, W, AsB[cur ^ 1], WsB[cur ^ 1], m0, n0, lda, ldw, kt + 1, w, lane);
      if (SPLITQ && p == 2) comp_tile<FR>(AsB[cur], WsB[cur], wr0, wc0, lane, acc2);
      else                  comp_tile<FR>(AsB[cur], WsB[cur], wr0, wc0, lane, acc);
      cur ^= 1;
    }
  }

  const int cb = n0 + wc0 + (lane & 15);
  const int r0 = m0 + wr0 + (lane >> 4) * 4;
  #pragma unroll
  for (int j = 0; j < 4; ++j) {
    int col = cb + j * 16;
    if (col >= N) continue;
    float bv1 = b1 ? b1[col] : 0.f;
    float bv2 = (NPASS == 2 && b2) ? b2[col] : 0.f;
    float bq  = (SPLITQ && b2) ? b2[col] : 0.f;
    #pragma unroll
    for (int i = 0; i < FR; ++i) {
      #pragma unroll
      for (int jj = 0; jj < 4; ++jj) {
        int row = r0 + i * 16 + jj;
        if (row >= M) continue;
        float v = acc[i][j][jj] + bv1 + bv2;
        if (SPLITQ) v = fmaxf(v, 0.f) + fmaxf(acc2[i][j][jj] + bq, 0.f);
        else if (ACT == 1) v = fmaxf(v, 0.f);
        else if (ACT == 2) v = tanhf(v);
        if (OUTMODE == 0)      ((float*)Cv)[(long)row * ldc + col] = v;
        else                   ((_Float16*)Cv)[(long)row * ldc + col] = (_Float16)v;
      }
    }
  }
}

// ---------------------------------------------------------------------------
// out2 = Sh @ q3  via MFMA, batched over grid.z (8 batches per quarter).
// A = Sh[z] (900x928 f16), W = q3T[bq0+z] (512x928 f16, pad cols zeroed by
// transpose_q3), C = f16 900x512.  Sh pad cols are zeroed by softmax, so the
// K-pad contributes exactly 0.
// ---------------------------------------------------------------------------
__global__ __launch_bounds__(256)
void mfma_out2(const _Float16* __restrict__ Sh, const _Float16* __restrict__ q3T,
               _Float16* __restrict__ C, int bq0)
{
  __shared__ _Float16 AsB[2][128 * 32];
  __shared__ _Float16 WsB[2][128 * 32];
  const int tid = threadIdx.x, w = tid >> 6, lane = tid & 63;
  const int z = blockIdx.z;
  const _Float16* A = Sh + (long)z * 900 * SPAD;
  const _Float16* W = q3T + ((long)(bq0 + z) * 512) * SPAD;
  _Float16* Cz = C + (long)z * 900 * 512;
  int mt, nt;
  swz2(mt, nt);
  const int m0 = mt * 128, n0 = nt * 128;
  const int wr0 = (w >> 1) * 64, wc0 = (w & 1) * 64;
  f32x4 acc[4][4] = {};
  int cur = 0;
  stage_tile<128>(A, W, AsB[0], WsB[0], m0, n0, SPAD, SPAD, 0, w, lane);
  for (int kt = 0; kt < SPAD / 32; ++kt) {
    __syncthreads();
    if (kt + 1 < SPAD / 32)
      stage_tile<128>(A, W, AsB[cur ^ 1], WsB[cur ^ 1], m0, n0, SPAD, SPAD, kt + 1, w, lane);
    comp_tile<4>(AsB[cur], WsB[cur], wr0, wc0, lane, acc);
    cur ^= 1;
  }
  const int cb = n0 + wc0 + (lane & 15);
  const int r0 = m0 + wr0 + (lane >> 4) * 4;
  #pragma unroll
  for (int j = 0; j < 4; ++j) {
    int col = cb + j * 16;
    #pragma unroll
    for (int i = 0; i < 4; ++i)
      #pragma unroll
      for (int jj = 0; jj < 4; ++jj) {
        int row = r0 + i * 16 + jj;
        if (row < 900)
          Cz[(long)row * 512 + col] = (_Float16)acc[i][j][jj];
      }
  }
}

// ---------------------------------------------------------------------------
// Batched 64x64 LDS-tiled transpose: q3T[b][d][h] = q3[b][h][d].
// Coalesced reads and 16B vector writes; fills h-pad 900..927 with zeros
// (keeps out2's K-pad NaN-free). grid (15, 8, 32).
// ---------------------------------------------------------------------------
__global__ __launch_bounds__(256)
void transpose_q3(const _Float16* __restrict__ q3, _Float16* __restrict__ q3T)
{
  __shared__ _Float16 t[64][72];        // stride 72 halfs = 144 B (16B-aligned)
  const int b = blockIdx.z;
  const int h0 = blockIdx.x * 64, d0 = blockIdx.y * 64;
  const int tid = threadIdx.x;
  const int r = tid >> 2, c0 = (tid & 3) * 16;
  half8 v0 = {}, v1 = {};
  if (h0 + r < 900) {
    const _Float16* src = q3 + ((long)b * 900 + h0 + r) * 512 + d0 + c0;
    v0 = *(const half8*)src;
    v1 = *(const half8*)(src + 8);
  }
  *(half8*)&t[r][c0] = v0;
  *(half8*)&t[r][c0 + 8] = v1;
  __syncthreads();
  const int dr = tid >> 2, hcb = (tid & 3) * 16;
  _Float16* dst = q3T + ((long)b * 512 + d0 + dr) * SPAD;
  #pragma unroll
  for (int s = 0; s < 2; ++s) {
    int hc = hcb + s * 8;
    if (h0 + hc + 8 <= SPAD) {         // never cross the 928 row boundary
      half8 v;
      #pragma unroll
      for (int k = 0; k < 8; ++k) {
        int h = h0 + hc + k;
        v[k] = (h < 900) ? t[hc + k][dr] : (_Float16)0.f;
      }
      *(half8*)&dst[h0 + hc] = v;
    }
  }
}

// ---------------------------------------------------------------------------
// Transpose l -> f16: Ltr[b][n][c] = (f16) l[b][c][n].
// ---------------------------------------------------------------------------
__global__ __launch_bounds__(256)
void transpose_l(const float* __restrict__ l, _Float16* __restrict__ Ltr)
{
  const int b = blockIdx.x;
  const float* lb = l + (long)b * LIN_ * NL_;
  _Float16* ob = Ltr + (long)b * NL_ * LIN_;
  for (int i = threadIdx.x; i < LIN_ * NL_; i += 256) {
    int c = i / NL_, n = i % NL_;
    ob[(long)n * LIN_ + c] = (_Float16)lb[i];
  }
}

// ---------------------------------------------------------------------------
// Fused language attention over NL=20 tokens. Q f16, lt staged f16 in LDS.
// Lane owns dims {lane*4..+3} and {256+lane*4..+3}: conflict-free LDS reads.
// ---------------------------------------------------------------------------
__global__ __launch_bounds__(256)
void attn_kernel(const _Float16* __restrict__ Q, const float* __restrict__ Lt,
                 const float* __restrict__ lmask, _Float16* __restrict__ O,
                 int bbase)
{
  __shared__ _Float16 lt[NL_ * DIM_];
  __shared__ float smask[NL_];
  const int bg = blockIdx.y, b = bbase + bg;
  const int tid = threadIdx.x;
  const float* Lb = Lt + (long)b * NL_ * DIM_;
  for (int i = tid; i < NL_ * DIM_ / 8; i += 256) {
    float4 u = *(const float4*)&Lb[i * 8];
    float4 v = *(const float4*)&Lb[i * 8 + 4];
    half8 hh;
    hh[0] = (_Float16)u.x; hh[1] = (_Float16)u.y; hh[2] = (_Float16)u.z; hh[3] = (_Float16)u.w;
    hh[4] = (_Float16)v.x; hh[5] = (_Float16)v.y; hh[6] = (_Float16)v.z; hh[7] = (_Float16)v.w;
    *(half8*)&lt[i * 8] = hh;
  }
  if (tid < NL_) smask[tid] = 10000.f * lmask[b * NL_ + tid] - 10000.f;
  __syncthreads();
  const int wid = tid >> 6, lane = tid & 63;
  const int d0 = lane * 4, d1 = 256 + lane * 4;
  for (int rr = 0; rr < 2; ++rr) {
    int h = blockIdx.x * 8 + wid * 2 + rr;
    if (h >= HW_) continue;
    long grow = ((long)bg * HW_ + h) * DIM_;
    half4v qh0 = *(const half4v*)&Q[grow + d0];
    half4v qh1 = *(const half4v*)&Q[grow + d1];
    float q0[4], q1[4];
    #pragma unroll
    for (int k = 0; k < 4; ++k) { q0[k] = (float)qh0[k]; q1[k] = (float)qh1[k]; }
    float sim[NL_];
    for (int n = 0; n < NL_; ++n) {
      half4v l0 = *(const half4v*)&lt[n * DIM_ + d0];
      half4v l1 = *(const half4v*)&lt[n * DIM_ + d1];
      float d = q0[0] * (float)l0[0] + q0[1] * (float)l0[1]
              + q0[2] * (float)l0[2] + q0[3] * (float)l0[3]
              + q1[0] * (float)l1[0] + q1[1] * (float)l1[1]
              + q1[2] * (float)l1[2] + q1[3] * (float)l1[3];
      #pragma unroll
      for (int m = 32; m >= 1; m >>= 1) d += __shfl_xor(d, m, 64);
      sim[n] = d + smask[n];
    }
    float mx = sim[0];
    #pragma unroll
    for (int n = 1; n < NL_; ++n) mx = fmaxf(mx, sim[n]);
    float s = 0.f;
    #pragma unroll
    for (int n = 0; n < NL_; ++n) { sim[n] = expf(sim[n] - mx); s += sim[n]; }
    float inv = 1.f / s;
    float o0[4] = {0, 0, 0, 0}, o1[4] = {0, 0, 0, 0};
    for (int n = 0; n < NL_; ++n) {
      float pn = sim[n] * inv;
      half4v l0 = *(const half4v*)&lt[n * DIM_ + d0];
      half4v l1 = *(const half4v*)&lt[n * DIM_ + d1];
      #pragma unroll
      for (int k = 0; k < 4; ++k) {
        o0[k] += pn * (float)l0[k];
        o1[k] += pn * (float)l1[k];
      }
    }
    half4v ov0, ov1;
    #pragma unroll
    for (int k = 0; k < 4; ++k) { ov0[k] = (_Float16)o0[k]; ov1[k] = (_Float16)o1[k]; }
    *(half4v*)&O[grow + d0] = ov0;
    *(half4v*)&O[grow + d1] = ov1;
  }
}

// ---------------------------------------------------------------------------
// Row softmax over 900 cols; f32 in (stride SPAD), f16 out + zeroed pad.
// ---------------------------------------------------------------------------
__global__ __launch_bounds__(256)
void softmax_rows(const float* __restrict__ S, _Float16* __restrict__ Sh)
{
  __shared__ float red[4];
  const float* p = S + (long)blockIdx.x * SPAD;
  _Float16* ph = Sh + (long)blockIdx.x * SPAD;
  const int tid = threadIdx.x, lane = tid & 63, wid = tid >> 6;
  float vals[4];
  float mx = -1e30f;
  #pragma unroll
  for (int i = 0; i < 4; ++i) {
    int idx = tid + i * 256;
    vals[i] = (idx < HW_) ? p[idx] : -1e30f;
    mx = fmaxf(mx, vals[i]);
  }
  #pragma unroll
  for (int m = 32; m >= 1; m >>= 1) mx = fmaxf(mx, __shfl_xor(mx, m, 64));
  if (lane == 0) red[wid] = mx;
  __syncthreads();
  mx = fmaxf(fmaxf(red[0], red[1]), fmaxf(red[2], red[3]));
  __syncthreads();
  float s = 0.f;
  #pragma unroll
  for (int i = 0; i < 4; ++i) {
    int idx = tid + i * 256;
    if (idx < HW_) { vals[i] = expf(vals[i] - mx); s += vals[i]; }
  }
  #pragma unroll
  for (int m = 32; m >= 1; m >>= 1) s += __shfl_xor(s, m, 64);
  if (lane == 0) red[wid] = s;
  __syncthreads();
  float inv = 1.f / (red[0] + red[1] + red[2] + red[3]);
  #pragma unroll
  for (int i = 0; i < 4; ++i) {
    int idx = tid + i * 256;
    if (idx < HW_) ph[idx] = (_Float16)(vals[i] * inv);
  }
  if (tid < SPAD - HW_) ph[HW_ + tid] = (_Float16)0.f;
}

// ---------------------------------------------------------------------------
// f32 -> f16 converters.
// ---------------------------------------------------------------------------
__global__ __launch_bounds__(256)
void cvt_x(const float* __restrict__ src, _Float16* __restrict__ dst, long n8)
{
  const float4* s4 = (const float4*)src;
  half8* d = (half8*)dst;
  for (long i = (long)blockIdx.x * 256 + threadIdx.x; i < n8;
       i += (long)gridDim.x * 256) {
    float4 u = s4[2 * i], v = s4[2 * i + 1];
    half8 h;
    h[0] = (_Float16)u.x; h[1] = (_Float16)u.y; h[2] = (_Float16)u.z; h[3] = (_Float16)u.w;
    h[4] = (_Float16)v.x; h[5] = (_Float16)v.y; h[6] = (_Float16)v.z; h[7] = (_Float16)v.w;
    d[i] = h;
  }
}

__global__ __launch_bounds__(256)
void cvt_w(const float* s0, const float* s1, const float* s2, const float* s3,
           const float* s4, const float* s5, const float* s6, const float* s7,
           const float* s8, _Float16* __restrict__ dst)
{
  const long off[10] = {0, 262144, 524288, 786432, 1048576, 1310720,
                        1572864, 1966080, 2426880, 2951168};
  const int t = blockIdx.y;
  const float* src;
  switch (t) {
    case 0: src = s0; break; case 1: src = s1; break; case 2: src = s2; break;
    case 3: src = s3; break; case 4: src = s4; break; case 5: src = s5; break;
    case 6: src = s6; break; case 7: src = s7; break; default: src = s8; break;
  }
  long n8 = (off[t + 1] - off[t]) >> 3;
  const float4* s4p = (const float4*)src;
  half8* d = (half8*)(dst + off[t]);
  for (long i = (long)blockIdx.x * 256 + threadIdx.x; i < n8;
       i += (long)gridDim.x * 256) {
    float4 u = s4p[2 * i], v = s4p[2 * i + 1];
    half8 h;
    h[0] = (_Float16)u.x; h[1] = (_Float16)u.y; h[2] = (_Float16)u.z; h[3] = (_Float16)u.w;
    h[4] = (_Float16)v.x; h[5] = (_Float16)v.y; h[6] = (_Float16)v.z; h[7] = (_Float16)v.w;
    d[i] = h;
  }
}

// ---------------------------------------------------------------------------
__global__ void diag_kernel(float* out, long n, float ws_mb)
{
  long i = (long)blockIdx.x * 256 + threadIdx.x;
  if (i < n) out[i] = 0.f;
  if (i == 0) out[0] = ws_mb;
}

// ---------------------------------------------------------------------------
extern "C" void kernel_launch(void* const* d_in, const int* in_sizes, int n_in,
                              void* d_out, int out_size, void* d_ws, size_t ws_size,
                              hipStream_t stream) {
  const float* x      = (const float*)d_in[0];
  const float* l      = (const float*)d_in[1];
  const float* lmask  = (const float*)d_in[2];
  const float* W_lang = (const float*)d_in[3];
  const float* b_lang = (const float*)d_in[4];
  const float* W_v1   = (const float*)d_in[5];  const float* b_v1   = (const float*)d_in[6];
  const float* W_v2   = (const float*)d_in[7];  const float* b_v2   = (const float*)d_in[8];
  const float* W_v3   = (const float*)d_in[9];  const float* b_v3   = (const float*)d_in[10];
  const float* W_v4   = (const float*)d_in[11]; const float* b_v4   = (const float*)d_in[12];
  const float* W_out1 = (const float*)d_in[13]; const float* b_out1 = (const float*)d_in[14];
  const float* W_v22  = (const float*)d_in[15]; const float* b_v22  = (const float*)d_in[16];
  const float* W_a    = (const float*)d_in[17]; const float* b_a    = (const float*)d_in[18];
  const float* W_o3   = (const float*)d_in[19]; const float* b_o3   = (const float*)d_in[20];
  float* out = (float*)d_out;

  // ws layout, ~170 MB (< proven 173.77 MB grant):
  //   x16, O16, q2h, Ap16 (f16 28800x512), q3T (32x512x928 f16),
  //   Lt (f32 640x512), Ltr16, Sh (f16 7200x928), Wh (f16 weights).
  // f32 S scratch (7200x928) lives in d_out (free until final GEMM).
  const long NC16 = 28800L * 512;
  const size_t need =
      4 * (size_t)NC16 * 2
      + (size_t)32 * 512 * SPAD * 2
      + (size_t)640 * 512 * 4
      + (size_t)BATCH * NL_ * LIN_ * 2
      + (size_t)7200 * SPAD * 2
      + (size_t)2951168 * 2;
  if (ws_size < need) {
    long n = (long)out_size;
    diag_kernel<<<dim3((unsigned)((n + 255) / 256)), dim3(256), 0, stream>>>(
        out, n, (float)(ws_size >> 20));
    return;
  }

  _Float16* x16  = (_Float16*)d_ws;
  _Float16* O16  = x16 + NC16;
  _Float16* q2h  = O16 + NC16;
  _Float16* Ap16 = q2h + NC16;
  _Float16* q3T  = Ap16 + NC16;
  float* Lt      = (float*)(q3T + 32L * 512 * SPAD);
  _Float16* Ltr16 = (_Float16*)(Lt + 640L * 512);
  _Float16* Sh   = Ltr16 + (long)BATCH * NL_ * LIN_;
  _Float16* Wh   = Sh + 7200L * SPAD;
  _Float16 *Wv1h = Wh,            *Wv2h = Wh + 262144,  *Wv3h = Wh + 524288,
           *Wv4h = Wh + 786432,   *Wout1h = Wh + 1048576, *Wv22h = Wh + 1310720,
           *Wlangh = Wh + 1572864, *Wah = Wh + 1966080,  *Wo3h = Wh + 2426880;
  float* S32 = out;   // d_out as f32 scratch for pre-softmax scores

  dim3 blk(256);

  // conversions
  cvt_x<<<dim3(2048), blk, 0, stream>>>(x, x16, NC16 / 8);
  cvt_w<<<dim3(64, 9), blk, 0, stream>>>(W_v1, W_v2, W_v3, W_v4, W_out1, W_v22,
                                         W_lang, W_a, W_o3, Wh);
  transpose_l<<<dim3(BATCH), blk, 0, stream>>>(l, Ltr16);

  // Lt = Ltr @ W_lang^T + b_lang   (M=640, N=512, K=768) -> f32
  mfma_tn<0,1,0,0,128><<<dim3(5, 4), blk, 0, stream>>>(
      Ltr16, Wlangh, nullptr, nullptr, nullptr, nullptr, b_lang, nullptr, Lt,
      640, 512, 768, 768, 768, 0, 0, 0, 0, 0, 0, 512);

  // q1 = relu(x W_v1^T + b) -> f16 into Ap16 (free until Apre)
  mfma_tn<1,1,0,1,128><<<dim3(225, 4), blk, 0, stream>>>(
      x16, Wv1h, nullptr, nullptr, nullptr, nullptr, b_v1, nullptr, Ap16,
      28800, 512, 512, 512, 512, 0, 0, 0, 0, 0, 0, 512);

  attn_kernel<<<dim3(113, BATCH), blk, 0, stream>>>(Ap16, Lt, lmask, O16, 0);

  // q2 = relu(x W_v2^T + b) -> f16
  mfma_tn<1,1,0,1,128><<<dim3(225, 4), blk, 0, stream>>>(
      x16, Wv2h, nullptr, nullptr, nullptr, nullptr, b_v2, nullptr, q2h,
      28800, 512, 512, 512, 512, 0, 0, 0, 0, 0, 0, 512);

  // Apre = tanh(O W_out1^T + q2 W_v22^T + b + b) -> f16 (overwrites q1)
  mfma_tn<2,2,0,1,128><<<dim3(225, 4), blk, 0, stream>>>(
      O16, Wout1h, q2h, Wv22h, nullptr, nullptr, b_out1, b_v22, Ap16,
      28800, 512, 512, 512, 512, 512, 512, 512, 0, 0, 0, 512);

  // q3 = relu(x W_v3^T + b) -> f16 row-major into q2h (dead after Apre)
  mfma_tn<1,1,0,1,128><<<dim3(225, 4), blk, 0, stream>>>(
      x16, Wv3h, nullptr, nullptr, nullptr, nullptr, b_v3, nullptr, q2h,
      28800, 512, 512, 512, 512, 0, 0, 0, 0, 0, 0, 512);

  // q3T[b][d][h] = q3[b][h][d]  (tiled transpose, zero-fills h-pad 900..927)
  transpose_q3<<<dim3(15, 8, 32), blk, 0, stream>>>(q2h, q3T);

  // rel_map + out2 per quarter (out2 overwrites Ap16 rows, f16)
  for (int qt = 0; qt < 4; ++qt) {
    _Float16* Aph = Ap16 + (long)qt * 7200 * 512;
    mfma_tn<0,1,0,0,128><<<dim3(57, 8), blk, 0, stream>>>(
        Aph, Wah, nullptr, nullptr, nullptr, nullptr, b_a, nullptr, S32,
        7200, 900, 512, 512, 512, 0, 0, 0, 0, 0, 0, SPAD);
    softmax_rows<<<dim3(7200), blk, 0, stream>>>(S32, Sh);
    mfma_out2<<<dim3(8, 4, 8), blk, 0, stream>>>(Sh, q3T, Aph, qt * 8);
  }

  // out = relu(out2 Wo3a + O Wo3b + b_o3) + relu(x Wv4 + b_v4) -> f32
  mfma_tn<0,3,1,0,64><<<dim3(225, 8), blk, 0, stream>>>(
      Ap16, Wo3h, O16, Wo3h + 512, x16, Wv4h, b_o3, b_v4, out,
      28800, 512, 512, 512, 1024, 512, 512, 1024, 512, 512, 512, 512);
}

// Round 5
// 691.085 us; speedup vs baseline: 5.0202x; 1.1440x over previous
//
#include <hip/hip_runtime.h>

#define BATCH 32
#define HW_ 900
#define NL_ 20
#define DIM_ 512
#define LIN_ 768
#define SPAD 928        // S row stride, K-padded to 29*32 (cols 900..927 zero)

typedef _Float16 half8 __attribute__((ext_vector_type(8)));
typedef _Float16 half4v __attribute__((ext_vector_type(4)));
typedef float f32x4 __attribute__((ext_vector_type(4)));

// ---------------------------------------------------------------------------
// XCD-bijective block swizzle (m204): XCD k (= bid%8) gets a contiguous range
// of work-ids; n fastest so each XCD sweeps all n-tiles of one m-panel.
// ---------------------------------------------------------------------------
__device__ __forceinline__ void swz2(int& mt, int& nt) {
  const int nm = gridDim.x, nn = gridDim.y;
  const int total = nm * nn;
  const int bid = blockIdx.x + nm * blockIdx.y;
  const int q = total >> 3, r = total & 7;
  const int xcd = bid & 7, idx = bid >> 3;
  const int wg = (xcd < r ? xcd * (q + 1) : r * (q + 1) + (xcd - r) * q) + idx;
  mt = wg / nn; nt = wg - mt * nn;
}

// ---------------------------------------------------------------------------
// async global->LDS, 16B per lane. LDS dest is wave-uniform base; HW writes
// base + lane*16.
// ---------------------------------------------------------------------------
__device__ __forceinline__ void gload16(const void* g, void* l) {
  __builtin_amdgcn_global_load_lds(
      (const __attribute__((address_space(1))) void*)(unsigned long long)g,
      (__attribute__((address_space(3))) void*)(unsigned int)(unsigned long long)l,
      16, 0, 0);
}

// ---------------------------------------------------------------------------
// Staging with LDS bank-swizzle (rule 21: linear LDS dest + inverse-swizzled
// GLOBAL source + swizzled read).  Within each 16-row x 64B slab, physical
// 16B k-slot p holds logical slot p ^ ((row>>1)&3).  Spreads a 16-lane b128
// read group over 8 bank-quads (was 8-way conflict on banks 0-3/16-19).
// ---------------------------------------------------------------------------
template<int BNT>
__device__ __forceinline__ void stage_tile(
    const _Float16* __restrict__ A, const _Float16* __restrict__ W,
    _Float16* As, _Float16* Ws, int m0, int n0, int lda, int ldw, int kt,
    int w, int lane)
{
  const int rr = lane >> 2;                       // row within 16-row slab
  const int ks = (lane & 3) ^ ((rr >> 1) & 3);    // pre-swizzled k-slot
  #pragma unroll
  for (int t = 0; t < 2; ++t) {
    int row = 16 * (w + 4 * t) + rr;
    const _Float16* gp = A + (long)(m0 + row) * lda + kt * 32 + ks * 8;
    gload16(gp, As + (w + 4 * t) * 512);
  }
  #pragma unroll
  for (int t = 0; t < BNT / 64; ++t) {
    int row = 16 * (w + 4 * t) + rr;
    const _Float16* gp = W + (long)(n0 + row) * ldw + kt * 32 + ks * 8;
    gload16(gp, Ws + (w + 4 * t) * 512);
  }
}

// One BK=32 step: FRx4 fragments, mfma 16x16x32 f16.  Swizzled LDS read.
template<int FR>
__device__ __forceinline__ void comp_tile(
    const _Float16* As, const _Float16* Ws, int wr0, int wc0, int lane,
    f32x4 (&acc)[FR][4])
{
  half8 af[FR], wf[4];
  const int r = lane & 15;
  const int cs = (lane >> 4) ^ ((r >> 1) & 3);    // swizzled k-slot
  const int lo = r * 32 + cs * 8;
  #pragma unroll
  for (int i = 0; i < FR; ++i)
    af[i] = *(const half8*)&As[(wr0 + 16 * i) * 32 + lo];
  #pragma unroll
  for (int j = 0; j < 4; ++j)
    wf[j] = *(const half8*)&Ws[(wc0 + 16 * j) * 32 + lo];
  #pragma unroll
  for (int i = 0; i < FR; ++i)
    #pragma unroll
    for (int j = 0; j < 4; ++j)
      acc[i][j] = __builtin_amdgcn_mfma_f32_16x16x32_f16(af[i], wf[j], acc[i][j], 0, 0, 0);
}

// ---------------------------------------------------------------------------
// f16-in / f32-acc TN GEMM: C = act( sum_p A_p * W_p^T + b1 [+ b2] )
// SPLITQ: passes 0,1 -> accM; pass 2 -> accQ; C = relu(accM+b1)+relu(accQ+b2).
// OUTMODE: 0 = f32, 1 = f16.  launch_bounds(256,2): VGPR budget 256 so the
// dual-acc BNT=128 SPLITQ variant (~190 live VGPRs) does not spill.
// C/D layout (verified m89/m91): col = lane&15, row = (lane>>4)*4 + reg.
// ---------------------------------------------------------------------------
template<int ACT, int NPASS, int SPLITQ, int OUTMODE, int BNT>
__global__ __launch_bounds__(256, 2)
void mfma_tn(const _Float16* __restrict__ A1, const _Float16* __restrict__ W1,
             const _Float16* __restrict__ A2, const _Float16* __restrict__ W2,
             const _Float16* __restrict__ A3, const _Float16* __restrict__ W3,
             const float* __restrict__ b1, const float* __restrict__ b2,
             void* __restrict__ Cv,
             int M, int N, int K1, int lda1, int ldw1,
             int K2, int lda2, int ldw2, int K3, int lda3, int ldw3, int ldc)
{
  constexpr int FR = (BNT == 128) ? 4 : 2;
  __shared__ _Float16 AsB[2][128 * 32];
  __shared__ _Float16 WsB[2][BNT * 32];
  const int tid = threadIdx.x, w = tid >> 6, lane = tid & 63;
  int mt, nt;
  swz2(mt, nt);
  const int m0 = mt * 128, n0 = nt * BNT;
  const int wr0 = (BNT == 128) ? (w >> 1) * 64 : w * 32;
  const int wc0 = (BNT == 128) ? (w & 1) * 64 : 0;
  f32x4 acc[FR][4] = {};
  f32x4 acc2[FR][4] = {};
  int cur = 0;

  #pragma unroll
  for (int p = 0; p < NPASS; ++p) {
    const _Float16* A = (p == 0) ? A1 : (p == 1) ? A2 : A3;
    const _Float16* W = (p == 0) ? W1 : (p == 1) ? W2 : W3;
    const int K   = (p == 0) ? K1   : (p == 1) ? K2   : K3;
    const int lda = (p == 0) ? lda1 : (p == 1) ? lda2 : lda3;
    const int ldw = (p == 0) ? ldw1 : (p == 1) ? ldw2 : ldw3;
    const int NT = K / 32;
    stage_tile<BNT>(A, W, AsB[cur], WsB[cur], m0, n0, lda, ldw, 0, w, lane);
    for (int kt = 0; kt < NT; ++kt) {
      __syncthreads();
      if (kt + 1 < NT)
        stage_tile<BNT>(A, W, AsB[cur ^ 1], WsB[cur ^ 1], m0, n0, lda, ldw, kt + 1, w, lane);
      if (SPLITQ && p == 2) comp_tile<FR>(AsB[cur], WsB[cur], wr0, wc0, lane, acc2);
      else                  comp_tile<FR>(AsB[cur], WsB[cur], wr0, wc0, lane, acc);
      cur ^= 1;
    }
  }

  const int cb = n0 + wc0 + (lane & 15);
  const int r0 = m0 + wr0 + (lane >> 4) * 4;
  #pragma unroll
  for (int j = 0; j < 4; ++j) {
    int col = cb + j * 16;
    if (col >= N) continue;
    float bv1 = b1 ? b1[col] : 0.f;
    float bv2 = (NPASS == 2 && b2) ? b2[col] : 0.f;
    float bq  = (SPLITQ && b2) ? b2[col] : 0.f;
    #pragma unroll
    for (int i = 0; i < FR; ++i) {
      #pragma unroll
      for (int jj = 0; jj < 4; ++jj) {
        int row = r0 + i * 16 + jj;
        if (row >= M) continue;
        float v = acc[i][j][jj] + bv1 + bv2;
        if (SPLITQ) v = fmaxf(v, 0.f) + fmaxf(acc2[i][j][jj] + bq, 0.f);
        else if (ACT == 1) v = fmaxf(v, 0.f);
        else if (ACT == 2) v = tanhf(v);
        if (OUTMODE == 0)      ((float*)Cv)[(long)row * ldc + col] = v;
        else                   ((_Float16*)Cv)[(long)row * ldc + col] = (_Float16)v;
      }
    }
  }
}

// ---------------------------------------------------------------------------
// out2 = Sh @ q3  via MFMA, batched over grid.z = 32 (all batches).
// A = Sh[z] (900x928 f16, pad cols zeroed by softmax), W = q3T[z]
// (512x928 f16, pad cols zeroed by transpose_q3), C = f16 900x512.
// ---------------------------------------------------------------------------
__global__ __launch_bounds__(256, 2)
void mfma_out2(const _Float16* __restrict__ Sh, const _Float16* __restrict__ q3T,
               _Float16* __restrict__ C)
{
  __shared__ _Float16 AsB[2][128 * 32];
  __shared__ _Float16 WsB[2][128 * 32];
  const int tid = threadIdx.x, w = tid >> 6, lane = tid & 63;
  const int z = blockIdx.z;
  const _Float16* A = Sh + (long)z * 900 * SPAD;
  const _Float16* W = q3T + ((long)z * 512) * SPAD;
  _Float16* Cz = C + (long)z * 900 * 512;
  int mt, nt;
  swz2(mt, nt);
  const int m0 = mt * 128, n0 = nt * 128;
  const int wr0 = (w >> 1) * 64, wc0 = (w & 1) * 64;
  f32x4 acc[4][4] = {};
  int cur = 0;
  stage_tile<128>(A, W, AsB[0], WsB[0], m0, n0, SPAD, SPAD, 0, w, lane);
  for (int kt = 0; kt < SPAD / 32; ++kt) {
    __syncthreads();
    if (kt + 1 < SPAD / 32)
      stage_tile<128>(A, W, AsB[cur ^ 1], WsB[cur ^ 1], m0, n0, SPAD, SPAD, kt + 1, w, lane);
    comp_tile<4>(AsB[cur], WsB[cur], wr0, wc0, lane, acc);
    cur ^= 1;
  }
  const int cb = n0 + wc0 + (lane & 15);
  const int r0 = m0 + wr0 + (lane >> 4) * 4;
  #pragma unroll
  for (int j = 0; j < 4; ++j) {
    int col = cb + j * 16;
    #pragma unroll
    for (int i = 0; i < 4; ++i)
      #pragma unroll
      for (int jj = 0; jj < 4; ++jj) {
        int row = r0 + i * 16 + jj;
        if (row < 900)
          Cz[(long)row * 512 + col] = (_Float16)acc[i][j][jj];
      }
  }
}

// ---------------------------------------------------------------------------
// Batched 64x64 LDS-tiled transpose: q3T[b][d][h] = q3[b][h][d].
// Zero-fills h-pad 900..927.  grid (15, 8, 32).
// ---------------------------------------------------------------------------
__global__ __launch_bounds__(256)
void transpose_q3(const _Float16* __restrict__ q3, _Float16* __restrict__ q3T)
{
  __shared__ _Float16 t[64][72];        // stride 72 halfs = 144 B (16B-aligned)
  const int b = blockIdx.z;
  const int h0 = blockIdx.x * 64, d0 = blockIdx.y * 64;
  const int tid = threadIdx.x;
  const int r = tid >> 2, c0 = (tid & 3) * 16;
  half8 v0 = {}, v1 = {};
  if (h0 + r < 900) {
    const _Float16* src = q3 + ((long)b * 900 + h0 + r) * 512 + d0 + c0;
    v0 = *(const half8*)src;
    v1 = *(const half8*)(src + 8);
  }
  *(half8*)&t[r][c0] = v0;
  *(half8*)&t[r][c0 + 8] = v1;
  __syncthreads();
  const int dr = tid >> 2, hcb = (tid & 3) * 16;
  _Float16* dst = q3T + ((long)b * 512 + d0 + dr) * SPAD;
  #pragma unroll
  for (int s = 0; s < 2; ++s) {
    int hc = hcb + s * 8;
    if (h0 + hc + 8 <= SPAD) {         // never cross the 928 row boundary
      half8 v;
      #pragma unroll
      for (int k = 0; k < 8; ++k) {
        int h = h0 + hc + k;
        v[k] = (h < 900) ? t[hc + k][dr] : (_Float16)0.f;
      }
      *(half8*)&dst[h0 + hc] = v;
    }
  }
}

// ---------------------------------------------------------------------------
// Transpose l -> f16: Ltr[b][n][c] = (f16) l[b][c][n].
// ---------------------------------------------------------------------------
__global__ __launch_bounds__(256)
void transpose_l(const float* __restrict__ l, _Float16* __restrict__ Ltr)
{
  const int b = blockIdx.x;
  const float* lb = l + (long)b * LIN_ * NL_;
  _Float16* ob = Ltr + (long)b * NL_ * LIN_;
  for (int i = threadIdx.x; i < LIN_ * NL_; i += 256) {
    int c = i / NL_, n = i % NL_;
    ob[(long)n * LIN_ + c] = (_Float16)lb[i];
  }
}

// ---------------------------------------------------------------------------
// Fused language attention over NL=20 tokens. Q f16, lt staged f16 in LDS.
// Lane owns dims {lane*4..+3} and {256+lane*4..+3}: conflict-free LDS reads.
// ---------------------------------------------------------------------------
__global__ __launch_bounds__(256)
void attn_kernel(const _Float16* __restrict__ Q, const float* __restrict__ Lt,
                 const float* __restrict__ lmask, _Float16* __restrict__ O,
                 int bbase)
{
  __shared__ _Float16 lt[NL_ * DIM_];
  __shared__ float smask[NL_];
  const int bg = blockIdx.y, b = bbase + bg;
  const int tid = threadIdx.x;
  const float* Lb = Lt + (long)b * NL_ * DIM_;
  for (int i = tid; i < NL_ * DIM_ / 8; i += 256) {
    float4 u = *(const float4*)&Lb[i * 8];
    float4 v = *(const float4*)&Lb[i * 8 + 4];
    half8 hh;
    hh[0] = (_Float16)u.x; hh[1] = (_Float16)u.y; hh[2] = (_Float16)u.z; hh[3] = (_Float16)u.w;
    hh[4] = (_Float16)v.x; hh[5] = (_Float16)v.y; hh[6] = (_Float16)v.z; hh[7] = (_Float16)v.w;
    *(half8*)&lt[i * 8] = hh;
  }
  if (tid < NL_) smask[tid] = 10000.f * lmask[b * NL_ + tid] - 10000.f;
  __syncthreads();
  const int wid = tid >> 6, lane = tid & 63;
  const int d0 = lane * 4, d1 = 256 + lane * 4;
  for (int rr = 0; rr < 2; ++rr) {
    int h = blockIdx.x * 8 + wid * 2 + rr;
    if (h >= HW_) continue;
    long grow = ((long)bg * HW_ + h) * DIM_;
    half4v qh0 = *(const half4v*)&Q[grow + d0];
    half4v qh1 = *(const half4v*)&Q[grow + d1];
    float q0[4], q1[4];
    #pragma unroll
    for (int k = 0; k < 4; ++k) { q0[k] = (float)qh0[k]; q1[k] = (float)qh1[k]; }
    float sim[NL_];
    for (int n = 0; n < NL_; ++n) {
      half4v l0 = *(const half4v*)&lt[n * DIM_ + d0];
      half4v l1 = *(const half4v*)&lt[n * DIM_ + d1];
      float d = q0[0] * (float)l0[0] + q0[1] * (float)l0[1]
              + q0[2] * (float)l0[2] + q0[3] * (float)l0[3]
              + q1[0] * (float)l1[0] + q1[1] * (float)l1[1]
              + q1[2] * (float)l1[2] + q1[3] * (float)l1[3];
      #pragma unroll
      for (int m = 32; m >= 1; m >>= 1) d += __shfl_xor(d, m, 64);
      sim[n] = d + smask[n];
    }
    float mx = sim[0];
    #pragma unroll
    for (int n = 1; n < NL_; ++n) mx = fmaxf(mx, sim[n]);
    float s = 0.f;
    #pragma unroll
    for (int n = 0; n < NL_; ++n) { sim[n] = expf(sim[n] - mx); s += sim[n]; }
    float inv = 1.f / s;
    float o0[4] = {0, 0, 0, 0}, o1[4] = {0, 0, 0, 0};
    for (int n = 0; n < NL_; ++n) {
      float pn = sim[n] * inv;
      half4v l0 = *(const half4v*)&lt[n * DIM_ + d0];
      half4v l1 = *(const half4v*)&lt[n * DIM_ + d1];
      #pragma unroll
      for (int k = 0; k < 4; ++k) {
        o0[k] += pn * (float)l0[k];
        o1[k] += pn * (float)l1[k];
      }
    }
    half4v ov0, ov1;
    #pragma unroll
    for (int k = 0; k < 4; ++k) { ov0[k] = (_Float16)o0[k]; ov1[k] = (_Float16)o1[k]; }
    *(half4v*)&O[grow + d0] = ov0;
    *(half4v*)&O[grow + d1] = ov1;
  }
}

// ---------------------------------------------------------------------------
// In-place f16 row softmax over 900 cols (stride SPAD); zero-fills pad.
// 900 = 225*4: thread t<225 owns one half4v; threads 225..231 zero the pad.
// ---------------------------------------------------------------------------
__global__ __launch_bounds__(256)
void softmax_rows16(_Float16* __restrict__ Sh)
{
  __shared__ float red[4];
  _Float16* ph = Sh + (long)blockIdx.x * SPAD;
  const int tid = threadIdx.x, lane = tid & 63, wid = tid >> 6;
  const bool act = tid < 225;
  half4v hv = {};
  if (act) hv = *(const half4v*)&ph[tid * 4];
  float v[4];
  float mx = -1e30f;
  #pragma unroll
  for (int i = 0; i < 4; ++i) {
    v[i] = act ? (float)hv[i] : -1e30f;
    mx = fmaxf(mx, v[i]);
  }
  #pragma unroll
  for (int m = 32; m >= 1; m >>= 1) mx = fmaxf(mx, __shfl_xor(mx, m, 64));
  if (lane == 0) red[wid] = mx;
  __syncthreads();
  mx = fmaxf(fmaxf(red[0], red[1]), fmaxf(red[2], red[3]));
  __syncthreads();
  float s = 0.f;
  #pragma unroll
  for (int i = 0; i < 4; ++i) {
    v[i] = act ? expf(v[i] - mx) : 0.f;
    s += v[i];
  }
  #pragma unroll
  for (int m = 32; m >= 1; m >>= 1) s += __shfl_xor(s, m, 64);
  if (lane == 0) red[wid] = s;
  __syncthreads();
  float inv = 1.f / (red[0] + red[1] + red[2] + red[3]);
  if (act) {
    half4v o;
    #pragma unroll
    for (int i = 0; i < 4; ++i) o[i] = (_Float16)(v[i] * inv);
    *(half4v*)&ph[tid * 4] = o;
  } else if (tid < 232) {
    half4v z = {};
    *(half4v*)&ph[900 + (tid - 225) * 4] = z;
  }
}

// ---------------------------------------------------------------------------
// f32 -> f16 converters.
// ---------------------------------------------------------------------------
__global__ __launch_bounds__(256)
void cvt_x(const float* __restrict__ src, _Float16* __restrict__ dst, long n8)
{
  const float4* s4 = (const float4*)src;
  half8* d = (half8*)dst;
  for (long i = (long)blockIdx.x * 256 + threadIdx.x; i < n8;
       i += (long)gridDim.x * 256) {
    float4 u = s4[2 * i], v = s4[2 * i + 1];
    half8 h;
    h[0] = (_Float16)u.x; h[1] = (_Float16)u.y; h[2] = (_Float16)u.z; h[3] = (_Float16)u.w;
    h[4] = (_Float16)v.x; h[5] = (_Float16)v.y; h[6] = (_Float16)v.z; h[7] = (_Float16)v.w;
    d[i] = h;
  }
}

__global__ __launch_bounds__(256)
void cvt_w(const float* s0, const float* s1, const float* s2, const float* s3,
           const float* s4, const float* s5, const float* s6, const float* s7,
           const float* s8, _Float16* __restrict__ dst)
{
  const long off[10] = {0, 262144, 524288, 786432, 1048576, 1310720,
                        1572864, 1966080, 2426880, 2951168};
  const int t = blockIdx.y;
  const float* src;
  switch (t) {
    case 0: src = s0; break; case 1: src = s1; break; case 2: src = s2; break;
    case 3: src = s3; break; case 4: src = s4; break; case 5: src = s5; break;
    case 6: src = s6; break; case 7: src = s7; break; default: src = s8; break;
  }
  long n8 = (off[t + 1] - off[t]) >> 3;
  const float4* s4p = (const float4*)src;
  half8* d = (half8*)(dst + off[t]);
  for (long i = (long)blockIdx.x * 256 + threadIdx.x; i < n8;
       i += (long)gridDim.x * 256) {
    float4 u = s4p[2 * i], v = s4p[2 * i + 1];
    half8 h;
    h[0] = (_Float16)u.x; h[1] = (_Float16)u.y; h[2] = (_Float16)u.z; h[3] = (_Float16)u.w;
    h[4] = (_Float16)v.x; h[5] = (_Float16)v.y; h[6] = (_Float16)v.z; h[7] = (_Float16)v.w;
    d[i] = h;
  }
}

// ---------------------------------------------------------------------------
__global__ void diag_kernel(float* out, long n, float ws_mb)
{
  long i = (long)blockIdx.x * 256 + threadIdx.x;
  if (i < n) out[i] = 0.f;
  if (i == 0) out[0] = ws_mb;
}

// ---------------------------------------------------------------------------
extern "C" void kernel_launch(void* const* d_in, const int* in_sizes, int n_in,
                              void* d_out, int out_size, void* d_ws, size_t ws_size,
                              hipStream_t stream) {
  const float* x      = (const float*)d_in[0];
  const float* l      = (const float*)d_in[1];
  const float* lmask  = (const float*)d_in[2];
  const float* W_lang = (const float*)d_in[3];
  const float* b_lang = (const float*)d_in[4];
  const float* W_v1   = (const float*)d_in[5];  const float* b_v1   = (const float*)d_in[6];
  const float* W_v2   = (const float*)d_in[7];  const float* b_v2   = (const float*)d_in[8];
  const float* W_v3   = (const float*)d_in[9];  const float* b_v3   = (const float*)d_in[10];
  const float* W_v4   = (const float*)d_in[11]; const float* b_v4   = (const float*)d_in[12];
  const float* W_out1 = (const float*)d_in[13]; const float* b_out1 = (const float*)d_in[14];
  const float* W_v22  = (const float*)d_in[15]; const float* b_v22  = (const float*)d_in[16];
  const float* W_a    = (const float*)d_in[17]; const float* b_a    = (const float*)d_in[18];
  const float* W_o3   = (const float*)d_in[19]; const float* b_o3   = (const float*)d_in[20];
  float* out = (float*)d_out;

  // ws layout (~170 MB, < proven 173.77 MB grant).  f16 scores Sh
  // (28800x928, 53.45 MB) live in d_out (58.98 MB), free until the final GEMM.
  const long NC16 = 28800L * 512;
  const size_t need =
      4 * (size_t)NC16 * 2
      + (size_t)32 * 512 * SPAD * 2
      + (size_t)640 * 512 * 4
      + (size_t)BATCH * NL_ * LIN_ * 2
      + (size_t)7200 * SPAD * 2
      + (size_t)2951168 * 2;
  if (ws_size < need) {
    long n = (long)out_size;
    diag_kernel<<<dim3((unsigned)((n + 255) / 256)), dim3(256), 0, stream>>>(
        out, n, (float)(ws_size >> 20));
    return;
  }

  _Float16* x16  = (_Float16*)d_ws;
  _Float16* O16  = x16 + NC16;
  _Float16* q2h  = O16 + NC16;
  _Float16* Ap16 = q2h + NC16;
  _Float16* q3T  = Ap16 + NC16;
  float* Lt      = (float*)(q3T + 32L * 512 * SPAD);
  _Float16* Ltr16 = (_Float16*)(Lt + 640L * 512);
  _Float16* Wh   = Ltr16 + (long)BATCH * NL_ * LIN_ + 7200L * SPAD;  // skip old Sh slot
  _Float16 *Wv1h = Wh,            *Wv2h = Wh + 262144,  *Wv3h = Wh + 524288,
           *Wv4h = Wh + 786432,   *Wout1h = Wh + 1048576, *Wv22h = Wh + 1310720,
           *Wlangh = Wh + 1572864, *Wah = Wh + 1966080,  *Wo3h = Wh + 2426880;
  _Float16* Sh = (_Float16*)out;   // d_out as f16 score buffer (28800 x 928)

  dim3 blk(256);

  // conversions
  cvt_x<<<dim3(2048), blk, 0, stream>>>(x, x16, NC16 / 8);
  cvt_w<<<dim3(64, 9), blk, 0, stream>>>(W_v1, W_v2, W_v3, W_v4, W_out1, W_v22,
                                         W_lang, W_a, W_o3, Wh);
  transpose_l<<<dim3(BATCH), blk, 0, stream>>>(l, Ltr16);

  // Lt = Ltr @ W_lang^T + b_lang   (M=640, N=512, K=768) -> f32
  mfma_tn<0,1,0,0,128><<<dim3(5, 4), blk, 0, stream>>>(
      Ltr16, Wlangh, nullptr, nullptr, nullptr, nullptr, b_lang, nullptr, Lt,
      640, 512, 768, 768, 768, 0, 0, 0, 0, 0, 0, 512);

  // q1 = relu(x W_v1^T + b) -> f16 into Ap16 (free until Apre)
  mfma_tn<1,1,0,1,128><<<dim3(225, 4), blk, 0, stream>>>(
      x16, Wv1h, nullptr, nullptr, nullptr, nullptr, b_v1, nullptr, Ap16,
      28800, 512, 512, 512, 512, 0, 0, 0, 0, 0, 0, 512);

  attn_kernel<<<dim3(113, BATCH), blk, 0, stream>>>(Ap16, Lt, lmask, O16, 0);

  // q2 = relu(x W_v2^T + b) -> f16
  mfma_tn<1,1,0,1,128><<<dim3(225, 4), blk, 0, stream>>>(
      x16, Wv2h, nullptr, nullptr, nullptr, nullptr, b_v2, nullptr, q2h,
      28800, 512, 512, 512, 512, 0, 0, 0, 0, 0, 0, 512);

  // Apre = tanh(O W_out1^T + q2 W_v22^T + b + b) -> f16 (overwrites q1)
  mfma_tn<2,2,0,1,128><<<dim3(225, 4), blk, 0, stream>>>(
      O16, Wout1h, q2h, Wv22h, nullptr, nullptr, b_out1, b_v22, Ap16,
      28800, 512, 512, 512, 512, 512, 512, 512, 0, 0, 0, 512);

  // q3 = relu(x W_v3^T + b) -> f16 row-major into q2h (dead after Apre)
  mfma_tn<1,1,0,1,128><<<dim3(225, 4), blk, 0, stream>>>(
      x16, Wv3h, nullptr, nullptr, nullptr, nullptr, b_v3, nullptr, q2h,
      28800, 512, 512, 512, 512, 0, 0, 0, 0, 0, 0, 512);

  // q3T[b][d][h] = q3[b][h][d]  (tiled transpose, zero-fills h-pad 900..927)
  transpose_q3<<<dim3(15, 8, 32), blk, 0, stream>>>(q2h, q3T);

  // S = Apre @ W_a^T + b_a for ALL batches -> f16 Sh (in d_out)
  mfma_tn<0,1,0,1,128><<<dim3(225, 8), blk, 0, stream>>>(
      Ap16, Wah, nullptr, nullptr, nullptr, nullptr, b_a, nullptr, Sh,
      28800, 900, 512, 512, 512, 0, 0, 0, 0, 0, 0, SPAD);

  // rel_map = softmax(S) in place (f16), zero pad cols
  softmax_rows16<<<dim3(28800), blk, 0, stream>>>(Sh);

  // out2 = rel_map @ q3 for all batches -> Ap16 (overwrites Apre)
  mfma_out2<<<dim3(8, 4, 32), blk, 0, stream>>>(Sh, q3T, Ap16);

  // out = relu(out2 Wo3a + O Wo3b + b_o3) + relu(x Wv4 + b_v4) -> f32
  mfma_tn<0,3,1,0,128><<<dim3(225, 4), blk, 0, stream>>>(
      Ap16, Wo3h, O16, Wo3h + 512, x16, Wv4h, b_o3, b_v4, out,
      28800, 512, 512, 512, 1024, 512, 512, 1024, 512, 512, 512, 512);
}

// Round 6
// 684.529 us; speedup vs baseline: 5.0683x; 1.0096x over previous
//
#include <hip/hip_runtime.h>

#define BATCH 32
#define HW_ 900
#define NL_ 20
#define DIM_ 512
#define LIN_ 768
#define SPAD 928        // S row stride, K-padded to 29*32 (cols 900..927 zero)

typedef _Float16 half8 __attribute__((ext_vector_type(8)));
typedef _Float16 half4v __attribute__((ext_vector_type(4)));
typedef float f32x4 __attribute__((ext_vector_type(4)));

// counted waitcnt (T4): literal must be a token, hence macro.
#define WAITV(N) asm volatile("s_waitcnt vmcnt(" #N ")" ::: "memory")

// ---------------------------------------------------------------------------
// XCD-bijective block swizzle (m204): XCD k (= bid%8) gets a contiguous range
// of work-ids; n fastest so each XCD sweeps all n-tiles of one m-panel.
// ---------------------------------------------------------------------------
__device__ __forceinline__ void swz2(int& mt, int& nt) {
  const int nm = gridDim.x, nn = gridDim.y;
  const int total = nm * nn;
  const int bid = blockIdx.x + nm * blockIdx.y;
  const int q = total >> 3, r = total & 7;
  const int xcd = bid & 7, idx = bid >> 3;
  const int wg = (xcd < r ? xcd * (q + 1) : r * (q + 1) + (xcd - r) * q) + idx;
  mt = wg / nn; nt = wg - mt * nn;
}

// ---------------------------------------------------------------------------
// async global->LDS, 16B per lane. LDS dest is wave-uniform base; HW writes
// base + lane*16.  Counts against vmcnt.
// ---------------------------------------------------------------------------
__device__ __forceinline__ void gload16(const void* g, void* l) {
  __builtin_amdgcn_global_load_lds(
      (const __attribute__((address_space(1))) void*)(unsigned long long)g,
      (__attribute__((address_space(3))) void*)(unsigned int)(unsigned long long)l,
      16, 0, 0);
}

// ---------------------------------------------------------------------------
// Staging with LDS bank-swizzle (rule 21: linear LDS dest + inverse-swizzled
// GLOBAL source + swizzled read).  Within each 16-row x 64B slab, physical
// 16B k-slot p holds logical slot p ^ ((row>>1)&3).
// Exactly 4 gload16 per wave per call at BNT=128 (vmcnt accounting relies
// on this).
// ---------------------------------------------------------------------------
template<int BNT>
__device__ __forceinline__ void stage_tile(
    const _Float16* __restrict__ A, const _Float16* __restrict__ W,
    _Float16* As, _Float16* Ws, int m0, int n0, int lda, int ldw, int kt,
    int w, int lane)
{
  const int rr = lane >> 2;                       // row within 16-row slab
  const int ks = (lane & 3) ^ ((rr >> 1) & 3);    // pre-swizzled k-slot
  #pragma unroll
  for (int t = 0; t < 2; ++t) {
    int row = 16 * (w + 4 * t) + rr;
    const _Float16* gp = A + (long)(m0 + row) * lda + kt * 32 + ks * 8;
    gload16(gp, As + (w + 4 * t) * 512);
  }
  #pragma unroll
  for (int t = 0; t < BNT / 64; ++t) {
    int row = 16 * (w + 4 * t) + rr;
    const _Float16* gp = W + (long)(n0 + row) * ldw + kt * 32 + ks * 8;
    gload16(gp, Ws + (w + 4 * t) * 512);
  }
}

// One BK=32 step: FRx4 fragments, mfma 16x16x32 f16.  Swizzled LDS read.
// T5: setprio(1) around the MFMA cluster (waves are role-split between
// staging and compute under the counted-vmcnt schedule).
template<int FR>
__device__ __forceinline__ void comp_tile(
    const _Float16* As, const _Float16* Ws, int wr0, int wc0, int lane,
    f32x4 (&acc)[FR][4])
{
  half8 af[FR], wf[4];
  const int r = lane & 15;
  const int cs = (lane >> 4) ^ ((r >> 1) & 3);    // swizzled k-slot
  const int lo = r * 32 + cs * 8;
  #pragma unroll
  for (int i = 0; i < FR; ++i)
    af[i] = *(const half8*)&As[(wr0 + 16 * i) * 32 + lo];
  #pragma unroll
  for (int j = 0; j < 4; ++j)
    wf[j] = *(const half8*)&Ws[(wc0 + 16 * j) * 32 + lo];
  __builtin_amdgcn_s_setprio(1);
  #pragma unroll
  for (int i = 0; i < FR; ++i)
    #pragma unroll
    for (int j = 0; j < 4; ++j)
      acc[i][j] = __builtin_amdgcn_mfma_f32_16x16x32_f16(af[i], wf[j], acc[i][j], 0, 0, 0);
  __builtin_amdgcn_s_setprio(0);
}

// ---------------------------------------------------------------------------
// f16-in / f32-acc TN GEMM with T3+T4 counted-vmcnt pipeline:
// 4-buffer LDS ring, prefetch depth 2, one s_barrier per K-step, vmcnt(8)
// steady state (2 stages in flight), drain 4 -> 0 at the tail.  Buffer-reuse
// distance 4 > max wave skew 1 (barrier-bounded), so no overwrite race.
// SPLITQ: passes 0,1 -> accM; pass 2 -> accQ; C = relu(accM+b1)+relu(accQ+b2).
// OUTMODE: 0 = f32, 1 = f16.
// C/D layout (verified m89/m91): col = lane&15, row = (lane>>4)*4 + reg.
// ---------------------------------------------------------------------------
template<int ACT, int NPASS, int SPLITQ, int OUTMODE, int BNT>
__global__ __launch_bounds__(256, 2)
void mfma_tn(const _Float16* __restrict__ A1, const _Float16* __restrict__ W1,
             const _Float16* __restrict__ A2, const _Float16* __restrict__ W2,
             const _Float16* __restrict__ A3, const _Float16* __restrict__ W3,
             const float* __restrict__ b1, const float* __restrict__ b2,
             void* __restrict__ Cv,
             int M, int N, int K1, int lda1, int ldw1,
             int K2, int lda2, int ldw2, int K3, int lda3, int ldw3, int ldc)
{
  constexpr int FR = (BNT == 128) ? 4 : 2;
  __shared__ _Float16 AsB[4][128 * 32];
  __shared__ _Float16 WsB[4][BNT * 32];
  const int tid = threadIdx.x, w = tid >> 6, lane = tid & 63;
  int mt, nt;
  swz2(mt, nt);
  const int m0 = mt * 128, n0 = nt * BNT;
  const int wr0 = (BNT == 128) ? (w >> 1) * 64 : w * 32;
  const int wc0 = (BNT == 128) ? (w & 1) * 64 : 0;
  f32x4 acc[FR][4] = {};
  f32x4 acc2[FR][4] = {};

  #pragma unroll
  for (int p = 0; p < NPASS; ++p) {
    const _Float16* A = (p == 0) ? A1 : (p == 1) ? A2 : A3;
    const _Float16* W = (p == 0) ? W1 : (p == 1) ? W2 : W3;
    const int K   = (p == 0) ? K1   : (p == 1) ? K2   : K3;
    const int lda = (p == 0) ? lda1 : (p == 1) ? lda2 : lda3;
    const int ldw = (p == 0) ? ldw1 : (p == 1) ? ldw2 : ldw3;
    const int NT = K / 32;
    // guard: all waves finished reading prev pass's buffers before restage
    __builtin_amdgcn_s_barrier();
    stage_tile<BNT>(A, W, AsB[0], WsB[0], m0, n0, lda, ldw, 0, w, lane);
    if (NT > 1)
      stage_tile<BNT>(A, W, AsB[1], WsB[1], m0, n0, lda, ldw, 1, w, lane);
    for (int kt = 0; kt < NT; ++kt) {
      if (kt + 2 < NT) {
        stage_tile<BNT>(A, W, AsB[(kt + 2) & 3], WsB[(kt + 2) & 3],
                        m0, n0, lda, ldw, kt + 2, w, lane);
        WAITV(8);             // stages kt+1, kt+2 stay in flight
      } else if (kt + 1 < NT) {
        WAITV(4);             // stage kt+1 stays in flight
      } else {
        WAITV(0);             // tail drain
      }
      __builtin_amdgcn_s_barrier();
      __builtin_amdgcn_sched_barrier(0);
      if (SPLITQ && p == 2)
        comp_tile<FR>(AsB[kt & 3], WsB[kt & 3], wr0, wc0, lane, acc2);
      else
        comp_tile<FR>(AsB[kt & 3], WsB[kt & 3], wr0, wc0, lane, acc);
    }
  }

  const int cb = n0 + wc0 + (lane & 15);
  const int r0 = m0 + wr0 + (lane >> 4) * 4;
  #pragma unroll
  for (int j = 0; j < 4; ++j) {
    int col = cb + j * 16;
    if (col >= N) continue;
    float bv1 = b1 ? b1[col] : 0.f;
    float bv2 = (NPASS == 2 && b2) ? b2[col] : 0.f;
    float bq  = (SPLITQ && b2) ? b2[col] : 0.f;
    #pragma unroll
    for (int i = 0; i < FR; ++i) {
      #pragma unroll
      for (int jj = 0; jj < 4; ++jj) {
        int row = r0 + i * 16 + jj;
        if (row >= M) continue;
        float v = acc[i][j][jj] + bv1 + bv2;
        if (SPLITQ) v = fmaxf(v, 0.f) + fmaxf(acc2[i][j][jj] + bq, 0.f);
        else if (ACT == 1) v = fmaxf(v, 0.f);
        else if (ACT == 2) v = tanhf(v);
        if (OUTMODE == 0)      ((float*)Cv)[(long)row * ldc + col] = v;
        else                   ((_Float16*)Cv)[(long)row * ldc + col] = (_Float16)v;
      }
    }
  }
}

// ---------------------------------------------------------------------------
// out2 = Sh @ q3  via MFMA, batched over grid.z = 32; same T3+T4 pipeline.
// A = Sh[z] (900x928 f16, pad cols zeroed by softmax), W = q3T[z]
// (512x928 f16, pad cols zeroed by transpose_q3), C = f16 900x512.
// ---------------------------------------------------------------------------
__global__ __launch_bounds__(256, 2)
void mfma_out2(const _Float16* __restrict__ Sh, const _Float16* __restrict__ q3T,
               _Float16* __restrict__ C)
{
  __shared__ _Float16 AsB[4][128 * 32];
  __shared__ _Float16 WsB[4][128 * 32];
  const int tid = threadIdx.x, w = tid >> 6, lane = tid & 63;
  const int z = blockIdx.z;
  const _Float16* A = Sh + (long)z * 900 * SPAD;
  const _Float16* W = q3T + ((long)z * 512) * SPAD;
  _Float16* Cz = C + (long)z * 900 * 512;
  int mt, nt;
  swz2(mt, nt);
  const int m0 = mt * 128, n0 = nt * 128;
  const int wr0 = (w >> 1) * 64, wc0 = (w & 1) * 64;
  f32x4 acc[4][4] = {};
  const int NT = SPAD / 32;   // 29
  stage_tile<128>(A, W, AsB[0], WsB[0], m0, n0, SPAD, SPAD, 0, w, lane);
  stage_tile<128>(A, W, AsB[1], WsB[1], m0, n0, SPAD, SPAD, 1, w, lane);
  for (int kt = 0; kt < NT; ++kt) {
    if (kt + 2 < NT) {
      stage_tile<128>(A, W, AsB[(kt + 2) & 3], WsB[(kt + 2) & 3],
                      m0, n0, SPAD, SPAD, kt + 2, w, lane);
      WAITV(8);
    } else if (kt + 1 < NT) {
      WAITV(4);
    } else {
      WAITV(0);
    }
    __builtin_amdgcn_s_barrier();
    __builtin_amdgcn_sched_barrier(0);
    comp_tile<4>(AsB[kt & 3], WsB[kt & 3], wr0, wc0, lane, acc);
  }
  const int cb = n0 + wc0 + (lane & 15);
  const int r0 = m0 + wr0 + (lane >> 4) * 4;
  #pragma unroll
  for (int j = 0; j < 4; ++j) {
    int col = cb + j * 16;
    #pragma unroll
    for (int i = 0; i < 4; ++i)
      #pragma unroll
      for (int jj = 0; jj < 4; ++jj) {
        int row = r0 + i * 16 + jj;
        if (row < 900)
          Cz[(long)row * 512 + col] = (_Float16)acc[i][j][jj];
      }
  }
}

// ---------------------------------------------------------------------------
// Batched 64x64 LDS-tiled transpose: q3T[b][d][h] = q3[b][h][d].
// Zero-fills h-pad 900..927.  grid (15, 8, 32).
// ---------------------------------------------------------------------------
__global__ __launch_bounds__(256)
void transpose_q3(const _Float16* __restrict__ q3, _Float16* __restrict__ q3T)
{
  __shared__ _Float16 t[64][72];        // stride 72 halfs = 144 B (16B-aligned)
  const int b = blockIdx.z;
  const int h0 = blockIdx.x * 64, d0 = blockIdx.y * 64;
  const int tid = threadIdx.x;
  const int r = tid >> 2, c0 = (tid & 3) * 16;
  half8 v0 = {}, v1 = {};
  if (h0 + r < 900) {
    const _Float16* src = q3 + ((long)b * 900 + h0 + r) * 512 + d0 + c0;
    v0 = *(const half8*)src;
    v1 = *(const half8*)(src + 8);
  }
  *(half8*)&t[r][c0] = v0;
  *(half8*)&t[r][c0 + 8] = v1;
  __syncthreads();
  const int dr = tid >> 2, hcb = (tid & 3) * 16;
  _Float16* dst = q3T + ((long)b * 512 + d0 + dr) * SPAD;
  #pragma unroll
  for (int s = 0; s < 2; ++s) {
    int hc = hcb + s * 8;
    if (h0 + hc + 8 <= SPAD) {         // never cross the 928 row boundary
      half8 v;
      #pragma unroll
      for (int k = 0; k < 8; ++k) {
        int h = h0 + hc + k;
        v[k] = (h < 900) ? t[hc + k][dr] : (_Float16)0.f;
      }
      *(half8*)&dst[h0 + hc] = v;
    }
  }
}

// ---------------------------------------------------------------------------
// Transpose l -> f16: Ltr[b][n][c] = (f16) l[b][c][n].
// ---------------------------------------------------------------------------
__global__ __launch_bounds__(256)
void transpose_l(const float* __restrict__ l, _Float16* __restrict__ Ltr)
{
  const int b = blockIdx.x;
  const float* lb = l + (long)b * LIN_ * NL_;
  _Float16* ob = Ltr + (long)b * NL_ * LIN_;
  for (int i = threadIdx.x; i < LIN_ * NL_; i += 256) {
    int c = i / NL_, n = i % NL_;
    ob[(long)n * LIN_ + c] = (_Float16)lb[i];
  }
}

// ---------------------------------------------------------------------------
// Fused language attention over NL=20 tokens. Q f16, lt staged f16 in LDS.
// Lane owns dims {lane*4..+3} and {256+lane*4..+3}: conflict-free LDS reads.
// ---------------------------------------------------------------------------
__global__ __launch_bounds__(256)
void attn_kernel(const _Float16* __restrict__ Q, const float* __restrict__ Lt,
                 const float* __restrict__ lmask, _Float16* __restrict__ O,
                 int bbase)
{
  __shared__ _Float16 lt[NL_ * DIM_];
  __shared__ float smask[NL_];
  const int bg = blockIdx.y, b = bbase + bg;
  const int tid = threadIdx.x;
  const float* Lb = Lt + (long)b * NL_ * DIM_;
  for (int i = tid; i < NL_ * DIM_ / 8; i += 256) {
    float4 u = *(const float4*)&Lb[i * 8];
    float4 v = *(const float4*)&Lb[i * 8 + 4];
    half8 hh;
    hh[0] = (_Float16)u.x; hh[1] = (_Float16)u.y; hh[2] = (_Float16)u.z; hh[3] = (_Float16)u.w;
    hh[4] = (_Float16)v.x; hh[5] = (_Float16)v.y; hh[6] = (_Float16)v.z; hh[7] = (_Float16)v.w;
    *(half8*)&lt[i * 8] = hh;
  }
  if (tid < NL_) smask[tid] = 10000.f * lmask[b * NL_ + tid] - 10000.f;
  __syncthreads();
  const int wid = tid >> 6, lane = tid & 63;
  const int d0 = lane * 4, d1 = 256 + lane * 4;
  for (int rr = 0; rr < 2; ++rr) {
    int h = blockIdx.x * 8 + wid * 2 + rr;
    if (h >= HW_) continue;
    long grow = ((long)bg * HW_ + h) * DIM_;
    half4v qh0 = *(const half4v*)&Q[grow + d0];
    half4v qh1 = *(const half4v*)&Q[grow + d1];
    float q0[4], q1[4];
    #pragma unroll
    for (int k = 0; k < 4; ++k) { q0[k] = (float)qh0[k]; q1[k] = (float)qh1[k]; }
    float sim[NL_];
    for (int n = 0; n < NL_; ++n) {
      half4v l0 = *(const half4v*)&lt[n * DIM_ + d0];
      half4v l1 = *(const half4v*)&lt[n * DIM_ + d1];
      float d = q0[0] * (float)l0[0] + q0[1] * (float)l0[1]
              + q0[2] * (float)l0[2] + q0[3] * (float)l0[3]
              + q1[0] * (float)l1[0] + q1[1] * (float)l1[1]
              + q1[2] * (float)l1[2] + q1[3] * (float)l1[3];
      #pragma unroll
      for (int m = 32; m >= 1; m >>= 1) d += __shfl_xor(d, m, 64);
      sim[n] = d + smask[n];
    }
    float mx = sim[0];
    #pragma unroll
    for (int n = 1; n < NL_; ++n) mx = fmaxf(mx, sim[n]);
    float s = 0.f;
    #pragma unroll
    for (int n = 0; n < NL_; ++n) { sim[n] = expf(sim[n] - mx); s += sim[n]; }
    float inv = 1.f / s;
    float o0[4] = {0, 0, 0, 0}, o1[4] = {0, 0, 0, 0};
    for (int n = 0; n < NL_; ++n) {
      float pn = sim[n] * inv;
      half4v l0 = *(const half4v*)&lt[n * DIM_ + d0];
      half4v l1 = *(const half4v*)&lt[n * DIM_ + d1];
      #pragma unroll
      for (int k = 0; k < 4; ++k) {
        o0[k] += pn * (float)l0[k];
        o1[k] += pn * (float)l1[k];
      }
    }
    half4v ov0, ov1;
    #pragma unroll
    for (int k = 0; k < 4; ++k) { ov0[k] = (_Float16)o0[k]; ov1[k] = (_Float16)o1[k]; }
    *(half4v*)&O[grow + d0] = ov0;
    *(half4v*)&O[grow + d1] = ov1;
  }
}

// ---------------------------------------------------------------------------
// In-place f16 row softmax over 900 cols (stride SPAD); zero-fills pad.
// 900 = 225*4: thread t<225 owns one half4v; threads 225..231 zero the pad.
// ---------------------------------------------------------------------------
__global__ __launch_bounds__(256)
void softmax_rows16(_Float16* __restrict__ Sh)
{
  __shared__ float red[4];
  _Float16* ph = Sh + (long)blockIdx.x * SPAD;
  const int tid = threadIdx.x, lane = tid & 63, wid = tid >> 6;
  const bool act = tid < 225;
  half4v hv = {};
  if (act) hv = *(const half4v*)&ph[tid * 4];
  float v[4];
  float mx = -1e30f;
  #pragma unroll
  for (int i = 0; i < 4; ++i) {
    v[i] = act ? (float)hv[i] : -1e30f;
    mx = fmaxf(mx, v[i]);
  }
  #pragma unroll
  for (int m = 32; m >= 1; m >>= 1) mx = fmaxf(mx, __shfl_xor(mx, m, 64));
  if (lane == 0) red[wid] = mx;
  __syncthreads();
  mx = fmaxf(fmaxf(red[0], red[1]), fmaxf(red[2], red[3]));
  __syncthreads();
  float s = 0.f;
  #pragma unroll
  for (int i = 0; i < 4; ++i) {
    v[i] = act ? expf(v[i] - mx) : 0.f;
    s += v[i];
  }
  #pragma unroll
  for (int m = 32; m >= 1; m >>= 1) s += __shfl_xor(s, m, 64);
  if (lane == 0) red[wid] = s;
  __syncthreads();
  float inv = 1.f / (red[0] + red[1] + red[2] + red[3]);
  if (act) {
    half4v o;
    #pragma unroll
    for (int i = 0; i < 4; ++i) o[i] = (_Float16)(v[i] * inv);
    *(half4v*)&ph[tid * 4] = o;
  } else if (tid < 232) {
    half4v z = {};
    *(half4v*)&ph[900 + (tid - 225) * 4] = z;
  }
}

// ---------------------------------------------------------------------------
// f32 -> f16 converters.
// ---------------------------------------------------------------------------
__global__ __launch_bounds__(256)
void cvt_x(const float* __restrict__ src, _Float16* __restrict__ dst, long n8)
{
  const float4* s4 = (const float4*)src;
  half8* d = (half8*)dst;
  for (long i = (long)blockIdx.x * 256 + threadIdx.x; i < n8;
       i += (long)gridDim.x * 256) {
    float4 u = s4[2 * i], v = s4[2 * i + 1];
    half8 h;
    h[0] = (_Float16)u.x; h[1] = (_Float16)u.y; h[2] = (_Float16)u.z; h[3] = (_Float16)u.w;
    h[4] = (_Float16)v.x; h[5] = (_Float16)v.y; h[6] = (_Float16)v.z; h[7] = (_Float16)v.w;
    d[i] = h;
  }
}

__global__ __launch_bounds__(256)
void cvt_w(const float* s0, const float* s1, const float* s2, const float* s3,
           const float* s4, const float* s5, const float* s6, const float* s7,
           const float* s8, _Float16* __restrict__ dst)
{
  const long off[10] = {0, 262144, 524288, 786432, 1048576, 1310720,
                        1572864, 1966080, 2426880, 2951168};
  const int t = blockIdx.y;
  const float* src;
  switch (t) {
    case 0: src = s0; break; case 1: src = s1; break; case 2: src = s2; break;
    case 3: src = s3; break; case 4: src = s4; break; case 5: src = s5; break;
    case 6: src = s6; break; case 7: src = s7; break; default: src = s8; break;
  }
  long n8 = (off[t + 1] - off[t]) >> 3;
  const float4* s4p = (const float4*)src;
  half8* d = (half8*)(dst + off[t]);
  for (long i = (long)blockIdx.x * 256 + threadIdx.x; i < n8;
       i += (long)gridDim.x * 256) {
    float4 u = s4p[2 * i], v = s4p[2 * i + 1];
    half8 h;
    h[0] = (_Float16)u.x; h[1] = (_Float16)u.y; h[2] = (_Float16)u.z; h[3] = (_Float16)u.w;
    h[4] = (_Float16)v.x; h[5] = (_Float16)v.y; h[6] = (_Float16)v.z; h[7] = (_Float16)v.w;
    d[i] = h;
  }
}

// ---------------------------------------------------------------------------
__global__ void diag_kernel(float* out, long n, float ws_mb)
{
  long i = (long)blockIdx.x * 256 + threadIdx.x;
  if (i < n) out[i] = 0.f;
  if (i == 0) out[0] = ws_mb;
}

// ---------------------------------------------------------------------------
extern "C" void kernel_launch(void* const* d_in, const int* in_sizes, int n_in,
                              void* d_out, int out_size, void* d_ws, size_t ws_size,
                              hipStream_t stream) {
  const float* x      = (const float*)d_in[0];
  const float* l      = (const float*)d_in[1];
  const float* lmask  = (const float*)d_in[2];
  const float* W_lang = (const float*)d_in[3];
  const float* b_lang = (const float*)d_in[4];
  const float* W_v1   = (const float*)d_in[5];  const float* b_v1   = (const float*)d_in[6];
  const float* W_v2   = (const float*)d_in[7];  const float* b_v2   = (const float*)d_in[8];
  const float* W_v3   = (const float*)d_in[9];  const float* b_v3   = (const float*)d_in[10];
  const float* W_v4   = (const float*)d_in[11]; const float* b_v4   = (const float*)d_in[12];
  const float* W_out1 = (const float*)d_in[13]; const float* b_out1 = (const float*)d_in[14];
  const float* W_v22  = (const float*)d_in[15]; const float* b_v22  = (const float*)d_in[16];
  const float* W_a    = (const float*)d_in[17]; const float* b_a    = (const float*)d_in[18];
  const float* W_o3   = (const float*)d_in[19]; const float* b_o3   = (const float*)d_in[20];
  float* out = (float*)d_out;

  // ws layout (~170 MB, < proven 173.77 MB grant).  f16 scores Sh
  // (28800x928, 53.45 MB) live in d_out (58.98 MB), free until the final GEMM.
  const long NC16 = 28800L * 512;
  const size_t need =
      4 * (size_t)NC16 * 2
      + (size_t)32 * 512 * SPAD * 2
      + (size_t)640 * 512 * 4
      + (size_t)BATCH * NL_ * LIN_ * 2
      + (size_t)7200 * SPAD * 2
      + (size_t)2951168 * 2;
  if (ws_size < need) {
    long n = (long)out_size;
    diag_kernel<<<dim3((unsigned)((n + 255) / 256)), dim3(256), 0, stream>>>(
        out, n, (float)(ws_size >> 20));
    return;
  }

  _Float16* x16  = (_Float16*)d_ws;
  _Float16* O16  = x16 + NC16;
  _Float16* q2h  = O16 + NC16;
  _Float16* Ap16 = q2h + NC16;
  _Float16* q3T  = Ap16 + NC16;
  float* Lt      = (float*)(q3T + 32L * 512 * SPAD);
  _Float16* Ltr16 = (_Float16*)(Lt + 640L * 512);
  _Float16* Wh   = Ltr16 + (long)BATCH * NL_ * LIN_ + 7200L * SPAD;  // skip old Sh slot
  _Float16 *Wv1h = Wh,            *Wv2h = Wh + 262144,  *Wv3h = Wh + 524288,
           *Wv4h = Wh + 786432,   *Wout1h = Wh + 1048576, *Wv22h = Wh + 1310720,
           *Wlangh = Wh + 1572864, *Wah = Wh + 1966080,  *Wo3h = Wh + 2426880;
  _Float16* Sh = (_Float16*)out;   // d_out as f16 score buffer (28800 x 928)

  dim3 blk(256);

  // conversions
  cvt_x<<<dim3(2048), blk, 0, stream>>>(x, x16, NC16 / 8);
  cvt_w<<<dim3(64, 9), blk, 0, stream>>>(W_v1, W_v2, W_v3, W_v4, W_out1, W_v22,
                                         W_lang, W_a, W_o3, Wh);
  transpose_l<<<dim3(BATCH), blk, 0, stream>>>(l, Ltr16);

  // Lt = Ltr @ W_lang^T + b_lang   (M=640, N=512, K=768) -> f32
  mfma_tn<0,1,0,0,128><<<dim3(5, 4), blk, 0, stream>>>(
      Ltr16, Wlangh, nullptr, nullptr, nullptr, nullptr, b_lang, nullptr, Lt,
      640, 512, 768, 768, 768, 0, 0, 0, 0, 0, 0, 512);

  // q1 = relu(x W_v1^T + b) -> f16 into Ap16 (free until Apre)
  mfma_tn<1,1,0,1,128><<<dim3(225, 4), blk, 0, stream>>>(
      x16, Wv1h, nullptr, nullptr, nullptr, nullptr, b_v1, nullptr, Ap16,
      28800, 512, 512, 512, 512, 0, 0, 0, 0, 0, 0, 512);

  attn_kernel<<<dim3(113, BATCH), blk, 0, stream>>>(Ap16, Lt, lmask, O16, 0);

  // q2 = relu(x W_v2^T + b) -> f16
  mfma_tn<1,1,0,1,128><<<dim3(225, 4), blk, 0, stream>>>(
      x16, Wv2h, nullptr, nullptr, nullptr, nullptr, b_v2, nullptr, q2h,
      28800, 512, 512, 512, 512, 0, 0, 0, 0, 0, 0, 512);

  // Apre = tanh(O W_out1^T + q2 W_v22^T + b + b) -> f16 (overwrites q1)
  mfma_tn<2,2,0,1,128><<<dim3(225, 4), blk, 0, stream>>>(
      O16, Wout1h, q2h, Wv22h, nullptr, nullptr, b_out1, b_v22, Ap16,
      28800, 512, 512, 512, 512, 512, 512, 512, 0, 0, 0, 512);

  // q3 = relu(x W_v3^T + b) -> f16 row-major into q2h (dead after Apre)
  mfma_tn<1,1,0,1,128><<<dim3(225, 4), blk, 0, stream>>>(
      x16, Wv3h, nullptr, nullptr, nullptr, nullptr, b_v3, nullptr, q2h,
      28800, 512, 512, 512, 512, 0, 0, 0, 0, 0, 0, 512);

  // q3T[b][d][h] = q3[b][h][d]  (tiled transpose, zero-fills h-pad 900..927)
  transpose_q3<<<dim3(15, 8, 32), blk, 0, stream>>>(q2h, q3T);

  // S = Apre @ W_a^T + b_a for ALL batches -> f16 Sh (in d_out)
  mfma_tn<0,1,0,1,128><<<dim3(225, 8), blk, 0, stream>>>(
      Ap16, Wah, nullptr, nullptr, nullptr, nullptr, b_a, nullptr, Sh,
      28800, 900, 512, 512, 512, 0, 0, 0, 0, 0, 0, SPAD);

  // rel_map = softmax(S) in place (f16), zero pad cols
  softmax_rows16<<<dim3(28800), blk, 0, stream>>>(Sh);

  // out2 = rel_map @ q3 for all batches -> Ap16 (overwrites Apre)
  mfma_out2<<<dim3(8, 4, 32), blk, 0, stream>>>(Sh, q3T, Ap16);

  // out = relu(out2 Wo3a + O Wo3b + b_o3) + relu(x Wv4 + b_v4) -> f32
  mfma_tn<0,3,1,0,128><<<dim3(225, 4), blk, 0, stream>>>(
      Ap16, Wo3h, O16, Wo3h + 512, x16, Wv4h, b_o3, b_v4, out,
      28800, 512, 512, 512, 1024, 512, 512, 1024, 512, 512, 512, 512);
}

// Round 7
// 622.344 us; speedup vs baseline: 5.5747x; 1.0999x over previous
//
#include <hip/hip_runtime.h>

#define BATCH 32
#define HW_ 900
#define NL_ 20
#define DIM_ 512
#define LIN_ 768
#define SPAD 928        // S row stride, K-padded to 29*32 (cols 900..927 zero)

typedef _Float16 half8 __attribute__((ext_vector_type(8)));
typedef _Float16 half4v __attribute__((ext_vector_type(4)));
typedef float f32x4 __attribute__((ext_vector_type(4)));

#define WAITV(N) asm volatile("s_waitcnt vmcnt(" #N ")" ::: "memory")
#define MFMA16(a, b, c) __builtin_amdgcn_mfma_f32_16x16x32_f16(a, b, c, 0, 0, 0)

// ---------------------------------------------------------------------------
// XCD-bijective block swizzle (m204): XCD k (= bid%8) gets a contiguous range
// of work-ids; n fastest so each XCD sweeps all n-tiles of one m-panel.
// ---------------------------------------------------------------------------
__device__ __forceinline__ void swz2(int& mt, int& nt) {
  const int nm = gridDim.x, nn = gridDim.y;
  const int total = nm * nn;
  const int bid = blockIdx.x + nm * blockIdx.y;
  const int q = total >> 3, r = total & 7;
  const int xcd = bid & 7, idx = bid >> 3;
  const int wg = (xcd < r ? xcd * (q + 1) : r * (q + 1) + (xcd - r) * q) + idx;
  mt = wg / nn; nt = wg - mt * nn;
}

// ---------------------------------------------------------------------------
// async global->LDS, 16B per lane. LDS dest is wave-uniform base; HW writes
// base + lane*16.  Counts against vmcnt.
// ---------------------------------------------------------------------------
__device__ __forceinline__ void gload16(const void* g, void* l) {
  __builtin_amdgcn_global_load_lds(
      (const __attribute__((address_space(1))) void*)(unsigned long long)g,
      (__attribute__((address_space(3))) void*)(unsigned int)(unsigned long long)l,
      16, 0, 0);
}

// ---------------------------------------------------------------------------
// Staging with LDS bank-swizzle (rule 21: linear LDS dest + inverse-swizzled
// GLOBAL source + swizzled read).  Within each 16-row x 64B slab, physical
// 16B k-slot p holds logical slot p ^ ((row>>1)&3).
// ---------------------------------------------------------------------------
template<int BNT>
__device__ __forceinline__ void stage_tile(
    const _Float16* __restrict__ A, const _Float16* __restrict__ W,
    _Float16* As, _Float16* Ws, int m0, int n0, int lda, int ldw, int kt,
    int w, int lane)
{
  const int rr = lane >> 2;
  const int ks = (lane & 3) ^ ((rr >> 1) & 3);
  #pragma unroll
  for (int t = 0; t < 2; ++t) {
    int row = 16 * (w + 4 * t) + rr;
    const _Float16* gp = A + (long)(m0 + row) * lda + kt * 32 + ks * 8;
    gload16(gp, As + (w + 4 * t) * 512);
  }
  #pragma unroll
  for (int t = 0; t < BNT / 64; ++t) {
    int row = 16 * (w + 4 * t) + rr;
    const _Float16* gp = W + (long)(n0 + row) * ldw + kt * 32 + ks * 8;
    gload16(gp, Ws + (w + 4 * t) * 512);
  }
}

// A-only staging (128 x 32 tile) for the attention Q slab. 2 gload16/wave.
__device__ __forceinline__ void stage_q(
    const _Float16* __restrict__ Q, long rowbase, _Float16* dst, int kt,
    int w, int lane)
{
  const int rr = lane >> 2;
  const int ks = (lane & 3) ^ ((rr >> 1) & 3);
  #pragma unroll
  for (int t = 0; t < 2; ++t) {
    int row = 16 * (w + 4 * t) + rr;
    const _Float16* gp = Q + (rowbase + row) * DIM_ + kt * 32 + ks * 8;
    gload16(gp, dst + (w + 4 * t) * 512);
  }
}

// One BK=32 step: FRx4 fragments, mfma 16x16x32 f16.  Swizzled LDS read.
template<int FR>
__device__ __forceinline__ void comp_tile(
    const _Float16* As, const _Float16* Ws, int wr0, int wc0, int lane,
    f32x4 (&acc)[FR][4])
{
  half8 af[FR], wf[4];
  const int r = lane & 15;
  const int cs = (lane >> 4) ^ ((r >> 1) & 3);
  const int lo = r * 32 + cs * 8;
  #pragma unroll
  for (int i = 0; i < FR; ++i)
    af[i] = *(const half8*)&As[(wr0 + 16 * i) * 32 + lo];
  #pragma unroll
  for (int j = 0; j < 4; ++j)
    wf[j] = *(const half8*)&Ws[(wc0 + 16 * j) * 32 + lo];
  __builtin_amdgcn_s_setprio(1);
  #pragma unroll
  for (int i = 0; i < FR; ++i)
    #pragma unroll
    for (int j = 0; j < 4; ++j)
      acc[i][j] = MFMA16(af[i], wf[j], acc[i][j]);
  __builtin_amdgcn_s_setprio(0);
}

// ---------------------------------------------------------------------------
// f16-in / f32-acc TN GEMM with counted-vmcnt pipeline (4-buffer ring).
// SPLITQ: passes 0,1 -> accM; pass 2 -> accQ; C = relu(accM+b1)+relu(accQ+b2).
// OUTMODE: 0 = f32, 1 = f16, 3 = f16 3-way column split (cols 0-511 -> Cv,
//   512-1023 -> A2 (dst carrier), 1024-1535 -> A3); bias b1 is concat'd 1536.
// C/D layout (verified m89/m91): col = lane&15, row = (lane>>4)*4 + reg.
// ---------------------------------------------------------------------------
template<int ACT, int NPASS, int SPLITQ, int OUTMODE, int BNT>
__global__ __launch_bounds__(256, 2)
void mfma_tn(const _Float16* __restrict__ A1, const _Float16* __restrict__ W1,
             const _Float16* __restrict__ A2, const _Float16* __restrict__ W2,
             const _Float16* __restrict__ A3, const _Float16* __restrict__ W3,
             const float* __restrict__ b1, const float* __restrict__ b2,
             void* __restrict__ Cv,
             int M, int N, int K1, int lda1, int ldw1,
             int K2, int lda2, int ldw2, int K3, int lda3, int ldw3, int ldc)
{
  constexpr int FR = (BNT == 128) ? 4 : 2;
  __shared__ _Float16 AsB[4][128 * 32];
  __shared__ _Float16 WsB[4][BNT * 32];
  const int tid = threadIdx.x, w = tid >> 6, lane = tid & 63;
  int mt, nt;
  swz2(mt, nt);
  const int m0 = mt * 128, n0 = nt * BNT;
  const int wr0 = (BNT == 128) ? (w >> 1) * 64 : w * 32;
  const int wc0 = (BNT == 128) ? (w & 1) * 64 : 0;
  f32x4 acc[FR][4] = {};
  f32x4 acc2[FR][4] = {};

  #pragma unroll
  for (int p = 0; p < NPASS; ++p) {
    const _Float16* A = (p == 0) ? A1 : (p == 1) ? A2 : A3;
    const _Float16* W = (p == 0) ? W1 : (p == 1) ? W2 : W3;
    const int K   = (p == 0) ? K1   : (p == 1) ? K2   : K3;
    const int lda = (p == 0) ? lda1 : (p == 1) ? lda2 : lda3;
    const int ldw = (p == 0) ? ldw1 : (p == 1) ? ldw2 : ldw3;
    const int NT = K / 32;
    __builtin_amdgcn_s_barrier();
    stage_tile<BNT>(A, W, AsB[0], WsB[0], m0, n0, lda, ldw, 0, w, lane);
    if (NT > 1)
      stage_tile<BNT>(A, W, AsB[1], WsB[1], m0, n0, lda, ldw, 1, w, lane);
    for (int kt = 0; kt < NT; ++kt) {
      if (kt + 2 < NT) {
        stage_tile<BNT>(A, W, AsB[(kt + 2) & 3], WsB[(kt + 2) & 3],
                        m0, n0, lda, ldw, kt + 2, w, lane);
        WAITV(8);
      } else if (kt + 1 < NT) {
        WAITV(4);
      } else {
        WAITV(0);
      }
      __builtin_amdgcn_s_barrier();
      __builtin_amdgcn_sched_barrier(0);
      if (SPLITQ && p == 2)
        comp_tile<FR>(AsB[kt & 3], WsB[kt & 3], wr0, wc0, lane, acc2);
      else
        comp_tile<FR>(AsB[kt & 3], WsB[kt & 3], wr0, wc0, lane, acc);
    }
  }

  const int cb = n0 + wc0 + (lane & 15);
  const int r0 = m0 + wr0 + (lane >> 4) * 4;
  #pragma unroll
  for (int j = 0; j < 4; ++j) {
    int col = cb + j * 16;
    if (col >= N) continue;
    float bv1 = b1 ? b1[col] : 0.f;
    float bv2 = (NPASS == 2 && b2) ? b2[col] : 0.f;
    float bq  = (SPLITQ && b2) ? b2[col] : 0.f;
    #pragma unroll
    for (int i = 0; i < FR; ++i) {
      #pragma unroll
      for (int jj = 0; jj < 4; ++jj) {
        int row = r0 + i * 16 + jj;
        if (row >= M) continue;
        float v = acc[i][j][jj] + bv1 + bv2;
        if (SPLITQ) v = fmaxf(v, 0.f) + fmaxf(acc2[i][j][jj] + bq, 0.f);
        else if (ACT == 1) v = fmaxf(v, 0.f);
        else if (ACT == 2) v = tanhf(v);
        if (OUTMODE == 0)      ((float*)Cv)[(long)row * ldc + col] = v;
        else if (OUTMODE == 1) ((_Float16*)Cv)[(long)row * ldc + col] = (_Float16)v;
        else {
          int which = col >> 9, c = col & 511;
          _Float16* dp = (which == 0) ? (_Float16*)Cv
                       : (which == 1) ? const_cast<_Float16*>(A2)
                                      : const_cast<_Float16*>(A3);
          dp[(long)row * 512 + c] = (_Float16)v;
        }
      }
    }
  }
}

// ---------------------------------------------------------------------------
// out2 = Sh @ q3  via MFMA, batched over grid.z = 32; counted-vmcnt pipeline.
// ---------------------------------------------------------------------------
__global__ __launch_bounds__(256, 2)
void mfma_out2(const _Float16* __restrict__ Sh, const _Float16* __restrict__ q3T,
               _Float16* __restrict__ C)
{
  __shared__ _Float16 AsB[4][128 * 32];
  __shared__ _Float16 WsB[4][128 * 32];
  const int tid = threadIdx.x, w = tid >> 6, lane = tid & 63;
  const int z = blockIdx.z;
  const _Float16* A = Sh + (long)z * 900 * SPAD;
  const _Float16* W = q3T + ((long)z * 512) * SPAD;
  _Float16* Cz = C + (long)z * 900 * 512;
  int mt, nt;
  swz2(mt, nt);
  const int m0 = mt * 128, n0 = nt * 128;
  const int wr0 = (w >> 1) * 64, wc0 = (w & 1) * 64;
  f32x4 acc[4][4] = {};
  const int NT = SPAD / 32;   // 29
  stage_tile<128>(A, W, AsB[0], WsB[0], m0, n0, SPAD, SPAD, 0, w, lane);
  stage_tile<128>(A, W, AsB[1], WsB[1], m0, n0, SPAD, SPAD, 1, w, lane);
  for (int kt = 0; kt < NT; ++kt) {
    if (kt + 2 < NT) {
      stage_tile<128>(A, W, AsB[(kt + 2) & 3], WsB[(kt + 2) & 3],
                      m0, n0, SPAD, SPAD, kt + 2, w, lane);
      WAITV(8);
    } else if (kt + 1 < NT) {
      WAITV(4);
    } else {
      WAITV(0);
    }
    __builtin_amdgcn_s_barrier();
    __builtin_amdgcn_sched_barrier(0);
    comp_tile<4>(AsB[kt & 3], WsB[kt & 3], wr0, wc0, lane, acc);
  }
  const int cb = n0 + wc0 + (lane & 15);
  const int r0 = m0 + wr0 + (lane >> 4) * 4;
  #pragma unroll
  for (int j = 0; j < 4; ++j) {
    int col = cb + j * 16;
    #pragma unroll
    for (int i = 0; i < 4; ++i)
      #pragma unroll
      for (int jj = 0; jj < 4; ++jj) {
        int row = r0 + i * 16 + jj;
        if (row < 900)
          Cz[(long)row * 512 + col] = (_Float16)acc[i][j][jj];
      }
  }
}

// ---------------------------------------------------------------------------
// MFMA fused attention.  One block per (batch z, 128-row tile).
// LDS: ltN[32][512] f16, slot-swizzled (phys 8-slot = logical ^ (tok&7)) —
// serves QK^T B-frags (one b128, <=2-way) AND PV B-frags (8 u16, 2-way).
// Q slabs double-buffered via swizzled global_load_lds; P (post-softmax,
// f16) overlays Qs[0] with the GEMM row-swizzle for its A-frag read.
// Softmax in-register on C-layout: 4-shuffle reduce over the 16-lane group.
// ---------------------------------------------------------------------------
__global__ __launch_bounds__(256, 2)
void attn_mfma(const _Float16* __restrict__ Q, const float* __restrict__ Lt,
               const float* __restrict__ lmask, _Float16* __restrict__ O)
{
  __shared__ _Float16 ltN[32 * 512];     // 32 KB
  __shared__ _Float16 Qs[2][128 * 32];   // 16 KB
  __shared__ float smask[32];
  _Float16* P = Qs[0];                   // reused after QK phase

  const int z = blockIdx.y;
  const int m0 = blockIdx.x * 128;
  const int tid = threadIdx.x, w = tid >> 6, lane = tid & 63;
  const int lo = lane & 15, hi = lane >> 4;
  const int wr0 = w * 32;
  const long rowbase = (long)z * HW_ + m0;

  // Lt (f32 20x512) -> ltN swizzled f16; pad tokens 20..31 zeroed.
  const float* Lb = Lt + (long)z * NL_ * DIM_;
  for (int i = tid; i < NL_ * 256; i += 256) {
    int n = i >> 8, d = (i & 255) * 2;
    float2 v2 = *(const float2*)&Lb[n * DIM_ + d];
    int c0 = (((d >> 3) ^ (n & 7)) << 3) + (d & 7);
    ltN[n * 512 + c0]     = (_Float16)v2.x;
    ltN[n * 512 + c0 + 1] = (_Float16)v2.y;
  }
  for (int i = tid; i < 12 * 512; i += 256)
    ltN[(20 + (i >> 9)) * 512 + (i & 511)] = (_Float16)0.f;
  if (tid < 32)
    smask[tid] = (tid < NL_) ? 10000.f * lmask[z * NL_ + tid] - 10000.f : -1e30f;

  // ---- QK^T: rows wr0+16i+(hi*4+jj), tokens 16j+lo; K=512 in 16 steps.
  f32x4 accS[2][2] = {};
  const int csA = hi ^ ((lo >> 1) & 3);
  stage_q(Q, rowbase, Qs[0], 0, w, lane);
  __syncthreads();
  for (int kt = 0; kt < 16; ++kt) {
    if (kt + 1 < 16) stage_q(Q, rowbase, Qs[(kt + 1) & 1], kt + 1, w, lane);
    const _Float16* Qc = Qs[kt & 1];
    half8 a0 = *(const half8*)&Qc[(wr0 + lo) * 32 + csA * 8];
    half8 a1 = *(const half8*)&Qc[(wr0 + 16 + lo) * 32 + csA * 8];
    int co = (((kt * 4 + hi) ^ (lo & 7)) << 3);
    half8 b0 = *(const half8*)&ltN[lo * 512 + co];
    half8 b1 = *(const half8*)&ltN[(16 + lo) * 512 + co];
    accS[0][0] = MFMA16(a0, b0, accS[0][0]);
    accS[0][1] = MFMA16(a0, b1, accS[0][1]);
    accS[1][0] = MFMA16(a1, b0, accS[1][0]);
    accS[1][1] = MFMA16(a1, b1, accS[1][1]);
    __syncthreads();   // drains stage (vmcnt) + all reads before buffer reuse
  }

  // ---- softmax per row (16-lane reduce) and P -> LDS (swizzled).
  #pragma unroll
  for (int i = 0; i < 2; ++i)
    #pragma unroll
    for (int jj = 0; jj < 4; ++jj) {
      float v0 = accS[i][0][jj] + smask[lo];
      float v1 = accS[i][1][jj] + smask[16 + lo];
      float mx = fmaxf(v0, v1);
      #pragma unroll
      for (int m = 1; m <= 8; m <<= 1) mx = fmaxf(mx, __shfl_xor(mx, m, 64));
      float e0 = expf(v0 - mx), e1 = expf(v1 - mx);
      float s = e0 + e1;
      #pragma unroll
      for (int m = 1; m <= 8; m <<= 1) s += __shfl_xor(s, m, 64);
      float iv = 1.f / s;
      int r = wr0 + 16 * i + 4 * hi + jj;
      int key = (r >> 1) & 3;
      P[r * 32 + ((((lo >> 3) ^ key) << 3) + (lo & 7))]       = (_Float16)(e0 * iv);
      P[r * 32 + ((((2 + (lo >> 3)) ^ key) << 3) + (lo & 7))] = (_Float16)(e1 * iv);
    }
  __syncthreads();

  // ---- PV: O[rows][512] = P(128x32) @ ltN(32x512), 4 dim-chunks of 128.
  half8 pa0 = *(const half8*)&P[(wr0 + lo) * 32 + csA * 8];
  half8 pa1 = *(const half8*)&P[(wr0 + 16 + lo) * 32 + csA * 8];
  for (int dc = 0; dc < 4; ++dc) {
    f32x4 accO[2][8] = {};
    #pragma unroll
    for (int cf = 0; cf < 8; ++cf) {
      int d = dc * 128 + cf * 16 + lo;
      int dsl = d >> 3, dw = d & 7;
      half8 bf;
      #pragma unroll
      for (int i2 = 0; i2 < 8; ++i2)
        bf[i2] = ltN[(8 * hi + i2) * 512 + (((dsl ^ i2) << 3) + dw)];
      accO[0][cf] = MFMA16(pa0, bf, accO[0][cf]);
      accO[1][cf] = MFMA16(pa1, bf, accO[1][cf]);
    }
    #pragma unroll
    for (int i = 0; i < 2; ++i)
      #pragma unroll
      for (int cf = 0; cf < 8; ++cf)
        #pragma unroll
        for (int jj = 0; jj < 4; ++jj) {
          int rloc = m0 + wr0 + 16 * i + 4 * hi + jj;
          if (rloc < HW_) {
            int d = dc * 128 + cf * 16 + lo;
            O[((long)z * HW_ + rloc) * 512 + d] = (_Float16)accO[i][cf][jj];
          }
        }
  }
}

// ---------------------------------------------------------------------------
// Batched 64x64 LDS-tiled transpose: q3T[b][d][h] = q3[b][h][d].
// Zero-fills h-pad 900..927.  grid (15, 8, 32).
// ---------------------------------------------------------------------------
__global__ __launch_bounds__(256)
void transpose_q3(const _Float16* __restrict__ q3, _Float16* __restrict__ q3T)
{
  __shared__ _Float16 t[64][72];
  const int b = blockIdx.z;
  const int h0 = blockIdx.x * 64, d0 = blockIdx.y * 64;
  const int tid = threadIdx.x;
  const int r = tid >> 2, c0 = (tid & 3) * 16;
  half8 v0 = {}, v1 = {};
  if (h0 + r < 900) {
    const _Float16* src = q3 + ((long)b * 900 + h0 + r) * 512 + d0 + c0;
    v0 = *(const half8*)src;
    v1 = *(const half8*)(src + 8);
  }
  *(half8*)&t[r][c0] = v0;
  *(half8*)&t[r][c0 + 8] = v1;
  __syncthreads();
  const int dr = tid >> 2, hcb = (tid & 3) * 16;
  _Float16* dst = q3T + ((long)b * 512 + d0 + dr) * SPAD;
  #pragma unroll
  for (int s = 0; s < 2; ++s) {
    int hc = hcb + s * 8;
    if (h0 + hc + 8 <= SPAD) {
      half8 v;
      #pragma unroll
      for (int k = 0; k < 8; ++k) {
        int h = h0 + hc + k;
        v[k] = (h < 900) ? t[hc + k][dr] : (_Float16)0.f;
      }
      *(half8*)&dst[h0 + hc] = v;
    }
  }
}

// ---------------------------------------------------------------------------
// Transpose l -> f16 + concat q-biases into bcat[1536] (f32).
// ---------------------------------------------------------------------------
__global__ __launch_bounds__(256)
void transpose_l(const float* __restrict__ l, _Float16* __restrict__ Ltr,
                 const float* __restrict__ bv1, const float* __restrict__ bv2,
                 const float* __restrict__ bv3, float* __restrict__ bcat)
{
  const int b = blockIdx.x;
  if (b < 6) {
    int i = b * 256 + threadIdx.x;
    if (i < 1536)
      bcat[i] = (i < 512) ? bv1[i] : (i < 1024) ? bv2[i - 512] : bv3[i - 1024];
  }
  const float* lb = l + (long)b * LIN_ * NL_;
  _Float16* ob = Ltr + (long)b * NL_ * LIN_;
  for (int i = threadIdx.x; i < LIN_ * NL_; i += 256) {
    int c = i / NL_, n = i % NL_;
    ob[(long)n * LIN_ + c] = (_Float16)lb[i];
  }
}

// ---------------------------------------------------------------------------
// In-place f16 row softmax over 900 cols (stride SPAD); zero-fills pad.
// ---------------------------------------------------------------------------
__global__ __launch_bounds__(256)
void softmax_rows16(_Float16* __restrict__ Sh)
{
  __shared__ float red[4];
  _Float16* ph = Sh + (long)blockIdx.x * SPAD;
  const int tid = threadIdx.x, lane = tid & 63, wid = tid >> 6;
  const bool act = tid < 225;
  half4v hv = {};
  if (act) hv = *(const half4v*)&ph[tid * 4];
  float v[4];
  float mx = -1e30f;
  #pragma unroll
  for (int i = 0; i < 4; ++i) {
    v[i] = act ? (float)hv[i] : -1e30f;
    mx = fmaxf(mx, v[i]);
  }
  #pragma unroll
  for (int m = 32; m >= 1; m >>= 1) mx = fmaxf(mx, __shfl_xor(mx, m, 64));
  if (lane == 0) red[wid] = mx;
  __syncthreads();
  mx = fmaxf(fmaxf(red[0], red[1]), fmaxf(red[2], red[3]));
  __syncthreads();
  float s = 0.f;
  #pragma unroll
  for (int i = 0; i < 4; ++i) {
    v[i] = act ? expf(v[i] - mx) : 0.f;
    s += v[i];
  }
  #pragma unroll
  for (int m = 32; m >= 1; m >>= 1) s += __shfl_xor(s, m, 64);
  if (lane == 0) red[wid] = s;
  __syncthreads();
  float inv = 1.f / (red[0] + red[1] + red[2] + red[3]);
  if (act) {
    half4v o;
    #pragma unroll
    for (int i = 0; i < 4; ++i) o[i] = (_Float16)(v[i] * inv);
    *(half4v*)&ph[tid * 4] = o;
  } else if (tid < 232) {
    half4v z = {};
    *(half4v*)&ph[900 + (tid - 225) * 4] = z;
  }
}

// ---------------------------------------------------------------------------
// f32 -> f16 converters.
// ---------------------------------------------------------------------------
__global__ __launch_bounds__(256)
void cvt_x(const float* __restrict__ src, _Float16* __restrict__ dst, long n8)
{
  const float4* s4 = (const float4*)src;
  half8* d = (half8*)dst;
  for (long i = (long)blockIdx.x * 256 + threadIdx.x; i < n8;
       i += (long)gridDim.x * 256) {
    float4 u = s4[2 * i], v = s4[2 * i + 1];
    half8 h;
    h[0] = (_Float16)u.x; h[1] = (_Float16)u.y; h[2] = (_Float16)u.z; h[3] = (_Float16)u.w;
    h[4] = (_Float16)v.x; h[5] = (_Float16)v.y; h[6] = (_Float16)v.z; h[7] = (_Float16)v.w;
    d[i] = h;
  }
}

__global__ __launch_bounds__(256)
void cvt_w(const float* s0, const float* s1, const float* s2, const float* s3,
           const float* s4, const float* s5, const float* s6, const float* s7,
           const float* s8, _Float16* __restrict__ dst)
{
  const long off[10] = {0, 262144, 524288, 786432, 1048576, 1310720,
                        1572864, 1966080, 2426880, 2951168};
  const int t = blockIdx.y;
  const float* src;
  switch (t) {
    case 0: src = s0; break; case 1: src = s1; break; case 2: src = s2; break;
    case 3: src = s3; break; case 4: src = s4; break; case 5: src = s5; break;
    case 6: src = s6; break; case 7: src = s7; break; default: src = s8; break;
  }
  long n8 = (off[t + 1] - off[t]) >> 3;
  const float4* s4p = (const float4*)src;
  half8* d = (half8*)(dst + off[t]);
  for (long i = (long)blockIdx.x * 256 + threadIdx.x; i < n8;
       i += (long)gridDim.x * 256) {
    float4 u = s4p[2 * i], v = s4p[2 * i + 1];
    half8 h;
    h[0] = (_Float16)u.x; h[1] = (_Float16)u.y; h[2] = (_Float16)u.z; h[3] = (_Float16)u.w;
    h[4] = (_Float16)v.x; h[5] = (_Float16)v.y; h[6] = (_Float16)v.z; h[7] = (_Float16)v.w;
    d[i] = h;
  }
}

// ---------------------------------------------------------------------------
__global__ void diag_kernel(float* out, long n, float ws_mb)
{
  long i = (long)blockIdx.x * 256 + threadIdx.x;
  if (i < n) out[i] = 0.f;
  if (i == 0) out[0] = ws_mb;
}

// ---------------------------------------------------------------------------
extern "C" void kernel_launch(void* const* d_in, const int* in_sizes, int n_in,
                              void* d_out, int out_size, void* d_ws, size_t ws_size,
                              hipStream_t stream) {
  const float* x      = (const float*)d_in[0];
  const float* l      = (const float*)d_in[1];
  const float* lmask  = (const float*)d_in[2];
  const float* W_lang = (const float*)d_in[3];
  const float* b_lang = (const float*)d_in[4];
  const float* W_v1   = (const float*)d_in[5];  const float* b_v1   = (const float*)d_in[6];
  const float* W_v2   = (const float*)d_in[7];  const float* b_v2   = (const float*)d_in[8];
  const float* W_v3   = (const float*)d_in[9];  const float* b_v3   = (const float*)d_in[10];
  const float* W_v4   = (const float*)d_in[11]; const float* b_v4   = (const float*)d_in[12];
  const float* W_out1 = (const float*)d_in[13]; const float* b_out1 = (const float*)d_in[14];
  const float* W_v22  = (const float*)d_in[15]; const float* b_v22  = (const float*)d_in[16];
  const float* W_a    = (const float*)d_in[17]; const float* b_a    = (const float*)d_in[18];
  const float* W_o3   = (const float*)d_in[19]; const float* b_o3   = (const float*)d_in[20];
  float* out = (float*)d_out;

  const long NC16 = 28800L * 512;
  const size_t need =
      4 * (size_t)NC16 * 2
      + (size_t)32 * 512 * SPAD * 2
      + (size_t)640 * 512 * 4
      + (size_t)BATCH * NL_ * LIN_ * 2
      + (size_t)7200 * SPAD * 2
      + (size_t)2951168 * 2
      + 6144;
  if (ws_size < need) {
    long n = (long)out_size;
    diag_kernel<<<dim3((unsigned)((n + 255) / 256)), dim3(256), 0, stream>>>(
        out, n, (float)(ws_size >> 20));
    return;
  }

  _Float16* x16  = (_Float16*)d_ws;
  _Float16* O16  = x16 + NC16;
  _Float16* q2h  = O16 + NC16;
  _Float16* Ap16 = q2h + NC16;
  _Float16* q3T  = Ap16 + NC16;
  float* Lt      = (float*)(q3T + 32L * 512 * SPAD);
  _Float16* Ltr16 = (_Float16*)(Lt + 640L * 512);
  _Float16* Wh   = Ltr16 + (long)BATCH * NL_ * LIN_ + 7200L * SPAD;
  _Float16 *Wv1h = Wh,            *Wv2h = Wh + 262144,  *Wv3h = Wh + 524288,
           *Wv4h = Wh + 786432,   *Wout1h = Wh + 1048576, *Wv22h = Wh + 1310720,
           *Wlangh = Wh + 1572864, *Wah = Wh + 1966080,  *Wo3h = Wh + 2426880;
  float* bcat = (float*)(Wh + 2951168);
  _Float16* Sh  = (_Float16*)out;   // d_out: q3h then Sh (both dead by final)
  _Float16* q3h = (_Float16*)out;

  dim3 blk(256);

  cvt_x<<<dim3(2048), blk, 0, stream>>>(x, x16, NC16 / 8);
  cvt_w<<<dim3(64, 9), blk, 0, stream>>>(W_v1, W_v2, W_v3, W_v4, W_out1, W_v22,
                                         W_lang, W_a, W_o3, Wh);
  transpose_l<<<dim3(BATCH), blk, 0, stream>>>(l, Ltr16, b_v1, b_v2, b_v3, bcat);

  // Lt = Ltr @ W_lang^T + b_lang   (M=640, N=512, K=768) -> f32
  mfma_tn<0,1,0,0,128><<<dim3(5, 4), blk, 0, stream>>>(
      Ltr16, Wlangh, nullptr, nullptr, nullptr, nullptr, b_lang, nullptr, Lt,
      640, 512, 768, 768, 768, 0, 0, 0, 0, 0, 0, 512);

  // mega-Q: relu(x @ [Wv1|Wv2|Wv3]^T + bcat); q1->Ap16, q2->q2h, q3->d_out
  mfma_tn<1,1,0,3,128><<<dim3(225, 12), blk, 0, stream>>>(
      x16, Wh, q2h, nullptr, q3h, nullptr, bcat, nullptr, Ap16,
      28800, 1536, 512, 512, 512, 0, 0, 0, 0, 0, 0, 512);

  // q3T[b][d][h] = q3[b][h][d]  (reads d_out, frees it for Sh)
  transpose_q3<<<dim3(15, 8, 32), blk, 0, stream>>>(q3h, q3T);

  // attention: O16 = softmax(q1 Lt^T + mask) Lt   (MFMA)
  attn_mfma<<<dim3(8, 32), blk, 0, stream>>>(Ap16, Lt, lmask, O16);

  // Apre = tanh(O W_out1^T + q2 W_v22^T + b + b) -> f16 (overwrites q1)
  mfma_tn<2,2,0,1,128><<<dim3(225, 4), blk, 0, stream>>>(
      O16, Wout1h, q2h, Wv22h, nullptr, nullptr, b_out1, b_v22, Ap16,
      28800, 512, 512, 512, 512, 512, 512, 512, 0, 0, 0, 512);

  // S = Apre @ W_a^T + b_a -> f16 Sh (in d_out)
  mfma_tn<0,1,0,1,128><<<dim3(225, 8), blk, 0, stream>>>(
      Ap16, Wah, nullptr, nullptr, nullptr, nullptr, b_a, nullptr, Sh,
      28800, 900, 512, 512, 512, 0, 0, 0, 0, 0, 0, SPAD);

  softmax_rows16<<<dim3(28800), blk, 0, stream>>>(Sh);

  // out2 = rel_map @ q3 -> Ap16 (overwrites Apre)
  mfma_out2<<<dim3(8, 4, 32), blk, 0, stream>>>(Sh, q3T, Ap16);

  // out = relu(out2 Wo3a + O Wo3b + b_o3) + relu(x Wv4 + b_v4) -> f32
  mfma_tn<0,3,1,0,128><<<dim3(225, 4), blk, 0, stream>>>(
      Ap16, Wo3h, O16, Wo3h + 512, x16, Wv4h, b_o3, b_v4, out,
      28800, 512, 512, 512, 1024, 512, 512, 1024, 512, 512, 512, 512);
}

// Round 8
// 539.888 us; speedup vs baseline: 6.4261x; 1.1527x over previous
//
#include <hip/hip_runtime.h>

#define BATCH 32
#define HW_ 900
#define NL_ 20
#define DIM_ 512
#define LIN_ 768
#define SPAD 928        // S row stride, K-padded to 29*32 (cols 900..927 zero)

typedef _Float16 half8 __attribute__((ext_vector_type(8)));
typedef _Float16 half4v __attribute__((ext_vector_type(4)));
typedef float f32x4 __attribute__((ext_vector_type(4)));

#define WAITV(N) asm volatile("s_waitcnt vmcnt(" #N ")" ::: "memory")
#define MFMA16(a, b, c) __builtin_amdgcn_mfma_f32_16x16x32_f16(a, b, c, 0, 0, 0)

// ---------------------------------------------------------------------------
// XCD-bijective block swizzle (m204).
// ---------------------------------------------------------------------------
__device__ __forceinline__ void swz2(int& mt, int& nt) {
  const int nm = gridDim.x, nn = gridDim.y;
  const int total = nm * nn;
  const int bid = blockIdx.x + nm * blockIdx.y;
  const int q = total >> 3, r = total & 7;
  const int xcd = bid & 7, idx = bid >> 3;
  const int wg = (xcd < r ? xcd * (q + 1) : r * (q + 1) + (xcd - r) * q) + idx;
  mt = wg / nn; nt = wg - mt * nn;
}

// ---------------------------------------------------------------------------
__device__ __forceinline__ void gload16(const void* g, void* l) {
  __builtin_amdgcn_global_load_lds(
      (const __attribute__((address_space(1))) void*)(unsigned long long)g,
      (__attribute__((address_space(3))) void*)(unsigned int)(unsigned long long)l,
      16, 0, 0);
}

// Stage 128x32 A-tile + BNTx32 W-tile; linear LDS dest + inverse-swizzled
// global source (rule 21).  4 gload16/wave at BNT=128 (vmcnt counting).
template<int BNT>
__device__ __forceinline__ void stage_tile(
    const _Float16* __restrict__ A, const _Float16* __restrict__ W,
    _Float16* As, _Float16* Ws, int m0, int n0, int lda, int ldw, int kt,
    int w, int lane)
{
  const int rr = lane >> 2;
  const int ks = (lane & 3) ^ ((rr >> 1) & 3);
  #pragma unroll
  for (int t = 0; t < 2; ++t) {
    int row = 16 * (w + 4 * t) + rr;
    const _Float16* gp = A + (long)(m0 + row) * lda + kt * 32 + ks * 8;
    gload16(gp, As + (w + 4 * t) * 512);
  }
  #pragma unroll
  for (int t = 0; t < BNT / 64; ++t) {
    int row = 16 * (w + 4 * t) + rr;
    const _Float16* gp = W + (long)(n0 + row) * ldw + kt * 32 + ks * 8;
    gload16(gp, Ws + (w + 4 * t) * 512);
  }
}

// A-only staging for attention Q slab.
__device__ __forceinline__ void stage_q(
    const _Float16* __restrict__ Q, long rowbase, _Float16* dst, int kt,
    int w, int lane)
{
  const int rr = lane >> 2;
  const int ks = (lane & 3) ^ ((rr >> 1) & 3);
  #pragma unroll
  for (int t = 0; t < 2; ++t) {
    int row = 16 * (w + 4 * t) + rr;
    const _Float16* gp = Q + (rowbase + row) * DIM_ + kt * 32 + ks * 8;
    gload16(gp, dst + (w + 4 * t) * 512);
  }
}

// One BK=32 step: FRx4 fragments, swizzled LDS read, setprio'd MFMA cluster.
template<int FR>
__device__ __forceinline__ void comp_tile(
    const _Float16* As, const _Float16* Ws, int wr0, int wc0, int lane,
    f32x4 (&acc)[FR][4])
{
  half8 af[FR], wf[4];
  const int r = lane & 15;
  const int cs = (lane >> 4) ^ ((r >> 1) & 3);
  const int lo = r * 32 + cs * 8;
  #pragma unroll
  for (int i = 0; i < FR; ++i)
    af[i] = *(const half8*)&As[(wr0 + 16 * i) * 32 + lo];
  #pragma unroll
  for (int j = 0; j < 4; ++j)
    wf[j] = *(const half8*)&Ws[(wc0 + 16 * j) * 32 + lo];
  __builtin_amdgcn_s_setprio(1);
  #pragma unroll
  for (int i = 0; i < FR; ++i)
    #pragma unroll
    for (int j = 0; j < 4; ++j)
      acc[i][j] = MFMA16(af[i], wf[j], acc[i][j]);
  __builtin_amdgcn_s_setprio(0);
}

// ---------------------------------------------------------------------------
// f16-in / f32-acc TN GEMM.  3-buffer LDS ring (48 KB -> 3 blocks/CU),
// depth-2 prefetch, counted vmcnt(4); stage issued AFTER the barrier so
// buffer-reuse distance 3 > wave skew 1 (race-free).
// OUTMODE: 0 = f32 scalar epilogue; 1 = f16 via LDS-repack half8 stores;
// 3 = f16 repack + 3-way column split (cols 0-511 -> Cv, 512-1023 -> A2,
//     1024-1535 -> A3).  nwr = writable col bound (928 for S: pad written,
//     softmax zeroes it; bias read still guarded by col < N).
// C/D layout (verified m89/m91): col = lane&15, row = (lane>>4)*4 + reg.
// ---------------------------------------------------------------------------
template<int ACT, int NPASS, int SPLITQ, int OUTMODE, int BNT>
__global__ __launch_bounds__(256, 2)
void mfma_tn(const _Float16* __restrict__ A1, const _Float16* __restrict__ W1,
             const _Float16* __restrict__ A2, const _Float16* __restrict__ W2,
             const _Float16* __restrict__ A3, const _Float16* __restrict__ W3,
             const float* __restrict__ b1, const float* __restrict__ b2,
             void* __restrict__ Cv,
             int M, int N, int K1, int lda1, int ldw1,
             int K2, int lda2, int ldw2, int K3, int lda3, int ldw3, int ldc,
             int nwr)
{
  constexpr int FR = (BNT == 128) ? 4 : 2;
  constexpr int ASZ = 128 * 32, WSZ = BNT * 32;
  __shared__ _Float16 lds[3 * ASZ + 3 * WSZ];
  const int tid = threadIdx.x, w = tid >> 6, lane = tid & 63;
  int mt, nt;
  swz2(mt, nt);
  const int m0 = mt * 128, n0 = nt * BNT;
  const int wr0 = (BNT == 128) ? (w >> 1) * 64 : w * 32;
  const int wc0 = (BNT == 128) ? (w & 1) * 64 : 0;
  f32x4 acc[FR][4] = {};
  f32x4 acc2[FR][4] = {};

  #pragma unroll
  for (int p = 0; p < NPASS; ++p) {
    const _Float16* A = (p == 0) ? A1 : (p == 1) ? A2 : A3;
    const _Float16* W = (p == 0) ? W1 : (p == 1) ? W2 : W3;
    const int K   = (p == 0) ? K1   : (p == 1) ? K2   : K3;
    const int lda = (p == 0) ? lda1 : (p == 1) ? lda2 : lda3;
    const int ldw = (p == 0) ? ldw1 : (p == 1) ? ldw2 : ldw3;
    const int NT = K / 32;
    __builtin_amdgcn_s_barrier();       // all waves done reading prev buffers
    stage_tile<BNT>(A, W, lds, lds + 3 * ASZ, m0, n0, lda, ldw, 0, w, lane);
    if (NT > 1)
      stage_tile<BNT>(A, W, lds + ASZ, lds + 3 * ASZ + WSZ, m0, n0, lda, ldw, 1, w, lane);
    for (int kt = 0; kt < NT; ++kt) {
      if (kt + 1 < NT) { WAITV(4); } else { WAITV(0); }
      __builtin_amdgcn_s_barrier();
      __builtin_amdgcn_sched_barrier(0);
      if (kt + 2 < NT) {
        int sb = (kt + 2) % 3;
        stage_tile<BNT>(A, W, lds + sb * ASZ, lds + 3 * ASZ + sb * WSZ,
                        m0, n0, lda, ldw, kt + 2, w, lane);
      }
      int cb_ = kt % 3;
      if (SPLITQ && p == 2)
        comp_tile<FR>(lds + cb_ * ASZ, lds + 3 * ASZ + cb_ * WSZ, wr0, wc0, lane, acc2);
      else
        comp_tile<FR>(lds + cb_ * ASZ, lds + 3 * ASZ + cb_ * WSZ, wr0, wc0, lane, acc);
    }
  }

  const int lo = lane & 15, hi = lane >> 4;
  if (OUTMODE == 0) {
    const int cb = n0 + wc0 + lo;
    const int r0 = m0 + wr0 + hi * 4;
    #pragma unroll
    for (int j = 0; j < 4; ++j) {
      int col = cb + j * 16;
      if (col >= N) continue;
      float bv1 = b1 ? b1[col] : 0.f;
      float bv2 = (NPASS == 2 && b2) ? b2[col] : 0.f;
      float bq  = (SPLITQ && b2) ? b2[col] : 0.f;
      #pragma unroll
      for (int i = 0; i < FR; ++i) {
        #pragma unroll
        for (int jj = 0; jj < 4; ++jj) {
          int row = r0 + i * 16 + jj;
          if (row >= M) continue;
          float v = acc[i][j][jj] + bv1 + bv2;
          if (SPLITQ) v = fmaxf(v, 0.f) + fmaxf(acc2[i][j][jj] + bq, 0.f);
          else if (ACT == 1) v = fmaxf(v, 0.f);
          else if (ACT == 2) v = tanhf(v);
          ((float*)Cv)[(long)row * ldc + col] = v;
        }
      }
    }
  } else {
    // f16 repack epilogue: acc -> per-wave LDS scratch -> half8 stores.
    __syncthreads();                      // ring reads all done; LDS reusable
    _Float16* scr = lds + w * 64 * 72;    // 64 rows x stride 72 (16B-aligned)
    #pragma unroll
    for (int j = 0; j < 4; ++j) {
      int col = n0 + wc0 + 16 * j + lo;
      float bv1 = (b1 && col < N) ? b1[col] : 0.f;
      float bv2 = (NPASS == 2 && b2 && col < N) ? b2[col] : 0.f;
      #pragma unroll
      for (int i = 0; i < FR; ++i) {
        #pragma unroll
        for (int jj = 0; jj < 4; ++jj) {
          float v = acc[i][j][jj] + bv1 + bv2;
          if (ACT == 1) v = fmaxf(v, 0.f);
          if (ACT == 2) v = tanhf(v);
          scr[(16 * i + 4 * hi + jj) * 72 + 16 * j + lo] = (_Float16)v;
        }
      }
    }
    const int rl = lane >> 3, cl = (lane & 7) * 8;
    #pragma unroll
    for (int it = 0; it < 8; ++it) {
      half8 hv = *(const half8*)&scr[(it * 8 + rl) * 72 + cl];
      int row = m0 + wr0 + it * 8 + rl;
      int col = n0 + wc0 + cl;
      if (row < M && col < nwr) {
        if (OUTMODE == 1) {
          *(half8*)&((_Float16*)Cv)[(long)row * ldc + col] = hv;
        } else {
          int which = col >> 9, c = col & 511;
          _Float16* dp = (which == 0) ? (_Float16*)Cv
                       : (which == 1) ? const_cast<_Float16*>(A2)
                                      : const_cast<_Float16*>(A3);
          *(half8*)&dp[(long)row * 512 + c] = hv;
        }
      }
    }
  }
}

// ---------------------------------------------------------------------------
// out2 = Sh @ q3, batched over grid.z = 32; 3-ring + repack epilogue.
// ---------------------------------------------------------------------------
__global__ __launch_bounds__(256, 2)
void mfma_out2(const _Float16* __restrict__ Sh, const _Float16* __restrict__ q3T,
               _Float16* __restrict__ C)
{
  constexpr int ASZ = 128 * 32;
  __shared__ _Float16 lds[6 * ASZ];
  const int tid = threadIdx.x, w = tid >> 6, lane = tid & 63;
  const int z = blockIdx.z;
  const _Float16* A = Sh + (long)z * 900 * SPAD;
  const _Float16* W = q3T + ((long)z * 512) * SPAD;
  _Float16* Cz = C + (long)z * 900 * 512;
  int mt, nt;
  swz2(mt, nt);
  const int m0 = mt * 128, n0 = nt * 128;
  const int wr0 = (w >> 1) * 64, wc0 = (w & 1) * 64;
  f32x4 acc[4][4] = {};
  const int NT = SPAD / 32;   // 29
  stage_tile<128>(A, W, lds, lds + 3 * ASZ, m0, n0, SPAD, SPAD, 0, w, lane);
  stage_tile<128>(A, W, lds + ASZ, lds + 4 * ASZ, m0, n0, SPAD, SPAD, 1, w, lane);
  for (int kt = 0; kt < NT; ++kt) {
    if (kt + 1 < NT) { WAITV(4); } else { WAITV(0); }
    __builtin_amdgcn_s_barrier();
    __builtin_amdgcn_sched_barrier(0);
    if (kt + 2 < NT) {
      int sb = (kt + 2) % 3;
      stage_tile<128>(A, W, lds + sb * ASZ, lds + (3 + sb) * ASZ,
                      m0, n0, SPAD, SPAD, kt + 2, w, lane);
    }
    int cb_ = kt % 3;
    comp_tile<4>(lds + cb_ * ASZ, lds + (3 + cb_) * ASZ, wr0, wc0, lane, acc);
  }
  __syncthreads();
  const int lo = lane & 15, hi = lane >> 4;
  _Float16* scr = lds + w * 64 * 72;
  #pragma unroll
  for (int j = 0; j < 4; ++j)
    #pragma unroll
    for (int i = 0; i < 4; ++i)
      #pragma unroll
      for (int jj = 0; jj < 4; ++jj)
        scr[(16 * i + 4 * hi + jj) * 72 + 16 * j + lo] = (_Float16)acc[i][j][jj];
  const int rl = lane >> 3, cl = (lane & 7) * 8;
  #pragma unroll
  for (int it = 0; it < 8; ++it) {
    half8 hv = *(const half8*)&scr[(it * 8 + rl) * 72 + cl];
    int row = m0 + wr0 + it * 8 + rl;
    if (row < 900)
      *(half8*)&Cz[(long)row * 512 + n0 + wc0 + cl] = hv;
  }
}

// ---------------------------------------------------------------------------
// MFMA fused attention (round-7, verified).  One block per (batch, 128 rows).
// ---------------------------------------------------------------------------
__global__ __launch_bounds__(256, 2)
void attn_mfma(const _Float16* __restrict__ Q, const float* __restrict__ Lt,
               const float* __restrict__ lmask, _Float16* __restrict__ O)
{
  __shared__ _Float16 ltN[32 * 512];     // 32 KB
  __shared__ _Float16 Qs[2][128 * 32];   // 16 KB
  __shared__ float smask[32];
  _Float16* P = Qs[0];

  const int z = blockIdx.y;
  const int m0 = blockIdx.x * 128;
  const int tid = threadIdx.x, w = tid >> 6, lane = tid & 63;
  const int lo = lane & 15, hi = lane >> 4;
  const int wr0 = w * 32;
  const long rowbase = (long)z * HW_ + m0;

  const float* Lb = Lt + (long)z * NL_ * DIM_;
  for (int i = tid; i < NL_ * 256; i += 256) {
    int n = i >> 8, d = (i & 255) * 2;
    float2 v2 = *(const float2*)&Lb[n * DIM_ + d];
    int c0 = (((d >> 3) ^ (n & 7)) << 3) + (d & 7);
    ltN[n * 512 + c0]     = (_Float16)v2.x;
    ltN[n * 512 + c0 + 1] = (_Float16)v2.y;
  }
  for (int i = tid; i < 12 * 512; i += 256)
    ltN[(20 + (i >> 9)) * 512 + (i & 511)] = (_Float16)0.f;
  if (tid < 32)
    smask[tid] = (tid < NL_) ? 10000.f * lmask[z * NL_ + tid] - 10000.f : -1e30f;

  f32x4 accS[2][2] = {};
  const int csA = hi ^ ((lo >> 1) & 3);
  stage_q(Q, rowbase, Qs[0], 0, w, lane);
  __syncthreads();
  for (int kt = 0; kt < 16; ++kt) {
    if (kt + 1 < 16) stage_q(Q, rowbase, Qs[(kt + 1) & 1], kt + 1, w, lane);
    const _Float16* Qc = Qs[kt & 1];
    half8 a0 = *(const half8*)&Qc[(wr0 + lo) * 32 + csA * 8];
    half8 a1 = *(const half8*)&Qc[(wr0 + 16 + lo) * 32 + csA * 8];
    int co = (((kt * 4 + hi) ^ (lo & 7)) << 3);
    half8 b0 = *(const half8*)&ltN[lo * 512 + co];
    half8 b1 = *(const half8*)&ltN[(16 + lo) * 512 + co];
    accS[0][0] = MFMA16(a0, b0, accS[0][0]);
    accS[0][1] = MFMA16(a0, b1, accS[0][1]);
    accS[1][0] = MFMA16(a1, b0, accS[1][0]);
    accS[1][1] = MFMA16(a1, b1, accS[1][1]);
    __syncthreads();
  }

  #pragma unroll
  for (int i = 0; i < 2; ++i)
    #pragma unroll
    for (int jj = 0; jj < 4; ++jj) {
      float v0 = accS[i][0][jj] + smask[lo];
      float v1 = accS[i][1][jj] + smask[16 + lo];
      float mx = fmaxf(v0, v1);
      #pragma unroll
      for (int m = 1; m <= 8; m <<= 1) mx = fmaxf(mx, __shfl_xor(mx, m, 64));
      float e0 = expf(v0 - mx), e1 = expf(v1 - mx);
      float s = e0 + e1;
      #pragma unroll
      for (int m = 1; m <= 8; m <<= 1) s += __shfl_xor(s, m, 64);
      float iv = 1.f / s;
      int r = wr0 + 16 * i + 4 * hi + jj;
      int key = (r >> 1) & 3;
      P[r * 32 + ((((lo >> 3) ^ key) << 3) + (lo & 7))]       = (_Float16)(e0 * iv);
      P[r * 32 + ((((2 + (lo >> 3)) ^ key) << 3) + (lo & 7))] = (_Float16)(e1 * iv);
    }
  __syncthreads();

  half8 pa0 = *(const half8*)&P[(wr0 + lo) * 32 + csA * 8];
  half8 pa1 = *(const half8*)&P[(wr0 + 16 + lo) * 32 + csA * 8];
  for (int dc = 0; dc < 4; ++dc) {
    f32x4 accO[2][8] = {};
    #pragma unroll
    for (int cf = 0; cf < 8; ++cf) {
      int d = dc * 128 + cf * 16 + lo;
      int dsl = d >> 3, dw = d & 7;
      half8 bf;
      #pragma unroll
      for (int i2 = 0; i2 < 8; ++i2)
        bf[i2] = ltN[(8 * hi + i2) * 512 + (((dsl ^ i2) << 3) + dw)];
      accO[0][cf] = MFMA16(pa0, bf, accO[0][cf]);
      accO[1][cf] = MFMA16(pa1, bf, accO[1][cf]);
    }
    #pragma unroll
    for (int i = 0; i < 2; ++i)
      #pragma unroll
      for (int cf = 0; cf < 8; ++cf)
        #pragma unroll
        for (int jj = 0; jj < 4; ++jj) {
          int rloc = m0 + wr0 + 16 * i + 4 * hi + jj;
          if (rloc < HW_) {
            int d = dc * 128 + cf * 16 + lo;
            O[((long)z * HW_ + rloc) * 512 + d] = (_Float16)accO[i][cf][jj];
          }
        }
  }
}

// ---------------------------------------------------------------------------
// Batched 64x64 LDS-tiled transpose: q3T[b][d][h] = q3[b][h][d].
// ---------------------------------------------------------------------------
__global__ __launch_bounds__(256)
void transpose_q3(const _Float16* __restrict__ q3, _Float16* __restrict__ q3T)
{
  __shared__ _Float16 t[64][72];
  const int b = blockIdx.z;
  const int h0 = blockIdx.x * 64, d0 = blockIdx.y * 64;
  const int tid = threadIdx.x;
  const int r = tid >> 2, c0 = (tid & 3) * 16;
  half8 v0 = {}, v1 = {};
  if (h0 + r < 900) {
    const _Float16* src = q3 + ((long)b * 900 + h0 + r) * 512 + d0 + c0;
    v0 = *(const half8*)src;
    v1 = *(const half8*)(src + 8);
  }
  *(half8*)&t[r][c0] = v0;
  *(half8*)&t[r][c0 + 8] = v1;
  __syncthreads();
  const int dr = tid >> 2, hcb = (tid & 3) * 16;
  _Float16* dst = q3T + ((long)b * 512 + d0 + dr) * SPAD;
  #pragma unroll
  for (int s = 0; s < 2; ++s) {
    int hc = hcb + s * 8;
    if (h0 + hc + 8 <= SPAD) {
      half8 v;
      #pragma unroll
      for (int k = 0; k < 8; ++k) {
        int h = h0 + hc + k;
        v[k] = (h < 900) ? t[hc + k][dr] : (_Float16)0.f;
      }
      *(half8*)&dst[h0 + hc] = v;
    }
  }
}

// ---------------------------------------------------------------------------
// Transpose l -> f16 + concat q-biases into bcat[1536] (f32).
// ---------------------------------------------------------------------------
__global__ __launch_bounds__(256)
void transpose_l(const float* __restrict__ l, _Float16* __restrict__ Ltr,
                 const float* __restrict__ bv1, const float* __restrict__ bv2,
                 const float* __restrict__ bv3, float* __restrict__ bcat)
{
  const int b = blockIdx.x;
  if (b < 6) {
    int i = b * 256 + threadIdx.x;
    if (i < 1536)
      bcat[i] = (i < 512) ? bv1[i] : (i < 1024) ? bv2[i - 512] : bv3[i - 1024];
  }
  const float* lb = l + (long)b * LIN_ * NL_;
  _Float16* ob = Ltr + (long)b * NL_ * LIN_;
  for (int i = threadIdx.x; i < LIN_ * NL_; i += 256) {
    int c = i / NL_, n = i % NL_;
    ob[(long)n * LIN_ + c] = (_Float16)lb[i];
  }
}

// ---------------------------------------------------------------------------
// In-place f16 row softmax over 900 cols (stride SPAD); zero-fills pad.
// ---------------------------------------------------------------------------
__global__ __launch_bounds__(256)
void softmax_rows16(_Float16* __restrict__ Sh)
{
  __shared__ float red[4];
  _Float16* ph = Sh + (long)blockIdx.x * SPAD;
  const int tid = threadIdx.x, lane = tid & 63, wid = tid >> 6;
  const bool act = tid < 225;
  half4v hv = {};
  if (act) hv = *(const half4v*)&ph[tid * 4];
  float v[4];
  float mx = -1e30f;
  #pragma unroll
  for (int i = 0; i < 4; ++i) {
    v[i] = act ? (float)hv[i] : -1e30f;
    mx = fmaxf(mx, v[i]);
  }
  #pragma unroll
  for (int m = 32; m >= 1; m >>= 1) mx = fmaxf(mx, __shfl_xor(mx, m, 64));
  if (lane == 0) red[wid] = mx;
  __syncthreads();
  mx = fmaxf(fmaxf(red[0], red[1]), fmaxf(red[2], red[3]));
  __syncthreads();
  float s = 0.f;
  #pragma unroll
  for (int i = 0; i < 4; ++i) {
    v[i] = act ? expf(v[i] - mx) : 0.f;
    s += v[i];
  }
  #pragma unroll
  for (int m = 32; m >= 1; m >>= 1) s += __shfl_xor(s, m, 64);
  if (lane == 0) red[wid] = s;
  __syncthreads();
  float inv = 1.f / (red[0] + red[1] + red[2] + red[3]);
  if (act) {
    half4v o;
    #pragma unroll
    for (int i = 0; i < 4; ++i) o[i] = (_Float16)(v[i] * inv);
    *(half4v*)&ph[tid * 4] = o;
  } else if (tid < 232) {
    half4v z = {};
    *(half4v*)&ph[900 + (tid - 225) * 4] = z;
  }
}

// ---------------------------------------------------------------------------
__global__ __launch_bounds__(256)
void cvt_x(const float* __restrict__ src, _Float16* __restrict__ dst, long n8)
{
  const float4* s4 = (const float4*)src;
  half8* d = (half8*)dst;
  for (long i = (long)blockIdx.x * 256 + threadIdx.x; i < n8;
       i += (long)gridDim.x * 256) {
    float4 u = s4[2 * i], v = s4[2 * i + 1];
    half8 h;
    h[0] = (_Float16)u.x; h[1] = (_Float16)u.y; h[2] = (_Float16)u.z; h[3] = (_Float16)u.w;
    h[4] = (_Float16)v.x; h[5] = (_Float16)v.y; h[6] = (_Float16)v.z; h[7] = (_Float16)v.w;
    d[i] = h;
  }
}

__global__ __launch_bounds__(256)
void cvt_w(const float* s0, const float* s1, const float* s2, const float* s3,
           const float* s4, const float* s5, const float* s6, const float* s7,
           const float* s8, _Float16* __restrict__ dst)
{
  const long off[10] = {0, 262144, 524288, 786432, 1048576, 1310720,
                        1572864, 1966080, 2426880, 2951168};
  const int t = blockIdx.y;
  const float* src;
  switch (t) {
    case 0: src = s0; break; case 1: src = s1; break; case 2: src = s2; break;
    case 3: src = s3; break; case 4: src = s4; break; case 5: src = s5; break;
    case 6: src = s6; break; case 7: src = s7; break; default: src = s8; break;
  }
  long n8 = (off[t + 1] - off[t]) >> 3;
  const float4* s4p = (const float4*)src;
  half8* d = (half8*)(dst + off[t]);
  for (long i = (long)blockIdx.x * 256 + threadIdx.x; i < n8;
       i += (long)gridDim.x * 256) {
    float4 u = s4p[2 * i], v = s4p[2 * i + 1];
    half8 h;
    h[0] = (_Float16)u.x; h[1] = (_Float16)u.y; h[2] = (_Float16)u.z; h[3] = (_Float16)u.w;
    h[4] = (_Float16)v.x; h[5] = (_Float16)v.y; h[6] = (_Float16)v.z; h[7] = (_Float16)v.w;
    d[i] = h;
  }
}

// ---------------------------------------------------------------------------
__global__ void diag_kernel(float* out, long n, float ws_mb)
{
  long i = (long)blockIdx.x * 256 + threadIdx.x;
  if (i < n) out[i] = 0.f;
  if (i == 0) out[0] = ws_mb;
}

// ---------------------------------------------------------------------------
extern "C" void kernel_launch(void* const* d_in, const int* in_sizes, int n_in,
                              void* d_out, int out_size, void* d_ws, size_t ws_size,
                              hipStream_t stream) {
  const float* x      = (const float*)d_in[0];
  const float* l      = (const float*)d_in[1];
  const float* lmask  = (const float*)d_in[2];
  const float* W_lang = (const float*)d_in[3];
  const float* b_lang = (const float*)d_in[4];
  const float* W_v1   = (const float*)d_in[5];  const float* b_v1   = (const float*)d_in[6];
  const float* W_v2   = (const float*)d_in[7];  const float* b_v2   = (const float*)d_in[8];
  const float* W_v3   = (const float*)d_in[9];  const float* b_v3   = (const float*)d_in[10];
  const float* W_v4   = (const float*)d_in[11]; const float* b_v4   = (const float*)d_in[12];
  const float* W_out1 = (const float*)d_in[13]; const float* b_out1 = (const float*)d_in[14];
  const float* W_v22  = (const float*)d_in[15]; const float* b_v22  = (const float*)d_in[16];
  const float* W_a    = (const float*)d_in[17]; const float* b_a    = (const float*)d_in[18];
  const float* W_o3   = (const float*)d_in[19]; const float* b_o3   = (const float*)d_in[20];
  float* out = (float*)d_out;

  const long NC16 = 28800L * 512;
  const size_t need =
      4 * (size_t)NC16 * 2
      + (size_t)32 * 512 * SPAD * 2
      + (size_t)640 * 512 * 4
      + (size_t)BATCH * NL_ * LIN_ * 2
      + (size_t)7200 * SPAD * 2
      + (size_t)2951168 * 2
      + 6144;
  if (ws_size < need) {
    long n = (long)out_size;
    diag_kernel<<<dim3((unsigned)((n + 255) / 256)), dim3(256), 0, stream>>>(
        out, n, (float)(ws_size >> 20));
    return;
  }

  _Float16* x16  = (_Float16*)d_ws;
  _Float16* O16  = x16 + NC16;
  _Float16* q2h  = O16 + NC16;
  _Float16* Ap16 = q2h + NC16;
  _Float16* q3T  = Ap16 + NC16;
  float* Lt      = (float*)(q3T + 32L * 512 * SPAD);
  _Float16* Ltr16 = (_Float16*)(Lt + 640L * 512);
  _Float16* Wh   = Ltr16 + (long)BATCH * NL_ * LIN_ + 7200L * SPAD;
  _Float16 *Wv1h = Wh,            *Wv2h = Wh + 262144,  *Wv3h = Wh + 524288,
           *Wv4h = Wh + 786432,   *Wout1h = Wh + 1048576, *Wv22h = Wh + 1310720,
           *Wlangh = Wh + 1572864, *Wah = Wh + 1966080,  *Wo3h = Wh + 2426880;
  float* bcat = (float*)(Wh + 2951168);
  _Float16* Sh  = (_Float16*)out;
  _Float16* q3h = (_Float16*)out;

  dim3 blk(256);

  cvt_x<<<dim3(2048), blk, 0, stream>>>(x, x16, NC16 / 8);
  cvt_w<<<dim3(64, 9), blk, 0, stream>>>(W_v1, W_v2, W_v3, W_v4, W_out1, W_v22,
                                         W_lang, W_a, W_o3, Wh);
  transpose_l<<<dim3(BATCH), blk, 0, stream>>>(l, Ltr16, b_v1, b_v2, b_v3, bcat);

  // Lt = Ltr @ W_lang^T + b_lang  -> f32
  mfma_tn<0,1,0,0,128><<<dim3(5, 4), blk, 0, stream>>>(
      Ltr16, Wlangh, nullptr, nullptr, nullptr, nullptr, b_lang, nullptr, Lt,
      640, 512, 768, 768, 768, 0, 0, 0, 0, 0, 0, 512, 512);

  // mega-Q: relu(x @ [Wv1|Wv2|Wv3]^T + bcat); q1->Ap16, q2->q2h, q3->d_out
  mfma_tn<1,1,0,3,128><<<dim3(225, 12), blk, 0, stream>>>(
      x16, Wh, q2h, nullptr, q3h, nullptr, bcat, nullptr, Ap16,
      28800, 1536, 512, 512, 512, 0, 0, 0, 0, 0, 0, 512, 1536);

  // q3T[b][d][h] = q3[b][h][d]
  transpose_q3<<<dim3(15, 8, 32), blk, 0, stream>>>(q3h, q3T);

  // attention: O16 = softmax(q1 Lt^T + mask) Lt
  attn_mfma<<<dim3(8, 32), blk, 0, stream>>>(Ap16, Lt, lmask, O16);

  // Apre = tanh(O W_out1^T + q2 W_v22^T + b + b) -> f16 (overwrites q1)
  mfma_tn<2,2,0,1,128><<<dim3(225, 4), blk, 0, stream>>>(
      O16, Wout1h, q2h, Wv22h, nullptr, nullptr, b_out1, b_v22, Ap16,
      28800, 512, 512, 512, 512, 512, 512, 512, 0, 0, 0, 512, 512);

  // S = Apre @ W_a^T + b_a -> f16 Sh (in d_out); pad cols writable to 928
  mfma_tn<0,1,0,1,128><<<dim3(225, 8), blk, 0, stream>>>(
      Ap16, Wah, nullptr, nullptr, nullptr, nullptr, b_a, nullptr, Sh,
      28800, 900, 512, 512, 512, 0, 0, 0, 0, 0, 0, SPAD, SPAD);

  softmax_rows16<<<dim3(28800), blk, 0, stream>>>(Sh);

  // out2 = rel_map @ q3 -> Ap16 (overwrites Apre)
  mfma_out2<<<dim3(8, 4, 32), blk, 0, stream>>>(Sh, q3T, Ap16);

  // out = relu(out2 Wo3a + O Wo3b + b_o3) + relu(x Wv4 + b_v4) -> f32
  mfma_tn<0,3,1,0,128><<<dim3(225, 4), blk, 0, stream>>>(
      Ap16, Wo3h, O16, Wo3h + 512, x16, Wv4h, b_o3, b_v4, out,
      28800, 512, 512, 512, 1024, 512, 512, 1024, 512, 512, 512, 512, 512);
}

// Round 9
// 505.855 us; speedup vs baseline: 6.8585x; 1.0673x over previous
//
#include <hip/hip_runtime.h>

#define BATCH 32
#define HW_ 900
#define NL_ 20
#define DIM_ 512
#define LIN_ 768
#define SPAD 928        // S row stride, K-padded to 29*32 (cols 900..927)

typedef _Float16 half8 __attribute__((ext_vector_type(8)));
typedef _Float16 half4v __attribute__((ext_vector_type(4)));
typedef float f32x4 __attribute__((ext_vector_type(4)));

#define WAITV(N) asm volatile("s_waitcnt vmcnt(" #N ")" ::: "memory")
#define MFMA16(a, b, c) __builtin_amdgcn_mfma_f32_16x16x32_f16(a, b, c, 0, 0, 0)

// fast tanh: 1 - 2/(e^2x + 1); correct saturation at +-inf, err ~1e-6.
__device__ __forceinline__ float tanh_fast(float x) {
  float t = __expf(2.f * x);
  return 1.f - 2.f / (t + 1.f);
}

// ---------------------------------------------------------------------------
// XCD-bijective block swizzle (m204).
// ---------------------------------------------------------------------------
__device__ __forceinline__ void swz2(int& mt, int& nt) {
  const int nm = gridDim.x, nn = gridDim.y;
  const int total = nm * nn;
  const int bid = blockIdx.x + nm * blockIdx.y;
  const int q = total >> 3, r = total & 7;
  const int xcd = bid & 7, idx = bid >> 3;
  const int wg = (xcd < r ? xcd * (q + 1) : r * (q + 1) + (xcd - r) * q) + idx;
  mt = wg / nn; nt = wg - mt * nn;
}

// ---------------------------------------------------------------------------
__device__ __forceinline__ void gload16(const void* g, void* l) {
  __builtin_amdgcn_global_load_lds(
      (const __attribute__((address_space(1))) void*)(unsigned long long)g,
      (__attribute__((address_space(3))) void*)(unsigned int)(unsigned long long)l,
      16, 0, 0);
}

// Stage 128x32 A-tile + BNTx32 W-tile; linear LDS dest + inverse-swizzled
// global source (rule 21).  4 gload16/wave at BNT=128.
template<int BNT>
__device__ __forceinline__ void stage_tile(
    const _Float16* __restrict__ A, const _Float16* __restrict__ W,
    _Float16* As, _Float16* Ws, int m0, int n0, int lda, int ldw, int kt,
    int w, int lane)
{
  const int rr = lane >> 2;
  const int ks = (lane & 3) ^ ((rr >> 1) & 3);
  #pragma unroll
  for (int t = 0; t < 2; ++t) {
    int row = 16 * (w + 4 * t) + rr;
    const _Float16* gp = A + (long)(m0 + row) * lda + kt * 32 + ks * 8;
    gload16(gp, As + (w + 4 * t) * 512);
  }
  #pragma unroll
  for (int t = 0; t < BNT / 64; ++t) {
    int row = 16 * (w + 4 * t) + rr;
    const _Float16* gp = W + (long)(n0 + row) * ldw + kt * 32 + ks * 8;
    gload16(gp, Ws + (w + 4 * t) * 512);
  }
}

// A-only staging for attention Q slab.
__device__ __forceinline__ void stage_q(
    const _Float16* __restrict__ Q, long rowbase, _Float16* dst, int kt,
    int w, int lane)
{
  const int rr = lane >> 2;
  const int ks = (lane & 3) ^ ((rr >> 1) & 3);
  #pragma unroll
  for (int t = 0; t < 2; ++t) {
    int row = 16 * (w + 4 * t) + rr;
    const _Float16* gp = Q + (rowbase + row) * DIM_ + kt * 32 + ks * 8;
    gload16(gp, dst + (w + 4 * t) * 512);
  }
}

// One BK=32 step: FRx4 fragments, swizzled LDS read, setprio'd MFMA cluster.
template<int FR>
__device__ __forceinline__ void comp_tile(
    const _Float16* As, const _Float16* Ws, int wr0, int wc0, int lane,
    f32x4 (&acc)[FR][4])
{
  half8 af[FR], wf[4];
  const int r = lane & 15;
  const int cs = (lane >> 4) ^ ((r >> 1) & 3);
  const int lo = r * 32 + cs * 8;
  #pragma unroll
  for (int i = 0; i < FR; ++i)
    af[i] = *(const half8*)&As[(wr0 + 16 * i) * 32 + lo];
  #pragma unroll
  for (int j = 0; j < 4; ++j)
    wf[j] = *(const half8*)&Ws[(wc0 + 16 * j) * 32 + lo];
  __builtin_amdgcn_s_setprio(1);
  #pragma unroll
  for (int i = 0; i < FR; ++i)
    #pragma unroll
    for (int j = 0; j < 4; ++j)
      acc[i][j] = MFMA16(af[i], wf[j], acc[i][j]);
  __builtin_amdgcn_s_setprio(0);
}

// ---------------------------------------------------------------------------
// f16-in / f32-acc TN GEMM.  3-buffer LDS ring, depth-2 prefetch, counted
// vmcnt(4).  OUTMODE: 0 = f32 scalar epilogue; 1 = f16 repack half8 stores;
// 2 = EXPSUM: store exp(min(v,10)) f16 + per-row sums (cols<900) atomically
//     into rsum (fused softmax numerator; 1/sum applied in mfma_out2);
// 3 = f16 repack + 3-way column split.
// ACT==2 uses tanh_fast.  nwr = writable col bound.
// C/D layout (verified m89/m91): col = lane&15, row = (lane>>4)*4 + reg.
// ---------------------------------------------------------------------------
template<int ACT, int NPASS, int SPLITQ, int OUTMODE, int BNT>
__global__ __launch_bounds__(256, 2)
void mfma_tn(const _Float16* __restrict__ A1, const _Float16* __restrict__ W1,
             const _Float16* __restrict__ A2, const _Float16* __restrict__ W2,
             const _Float16* __restrict__ A3, const _Float16* __restrict__ W3,
             const float* __restrict__ b1, const float* __restrict__ b2,
             void* __restrict__ Cv,
             int M, int N, int K1, int lda1, int ldw1,
             int K2, int lda2, int ldw2, int K3, int lda3, int ldw3, int ldc,
             int nwr, float* __restrict__ rsum)
{
  constexpr int FR = (BNT == 128) ? 4 : 2;
  constexpr int ASZ = 128 * 32, WSZ = BNT * 32;
  __shared__ _Float16 lds[3 * ASZ + 3 * WSZ];
  const int tid = threadIdx.x, w = tid >> 6, lane = tid & 63;
  int mt, nt;
  swz2(mt, nt);
  const int m0 = mt * 128, n0 = nt * BNT;
  const int wr0 = (BNT == 128) ? (w >> 1) * 64 : w * 32;
  const int wc0 = (BNT == 128) ? (w & 1) * 64 : 0;
  f32x4 acc[FR][4] = {};
  f32x4 acc2[FR][4] = {};

  #pragma unroll
  for (int p = 0; p < NPASS; ++p) {
    const _Float16* A = (p == 0) ? A1 : (p == 1) ? A2 : A3;
    const _Float16* W = (p == 0) ? W1 : (p == 1) ? W2 : W3;
    const int K   = (p == 0) ? K1   : (p == 1) ? K2   : K3;
    const int lda = (p == 0) ? lda1 : (p == 1) ? lda2 : lda3;
    const int ldw = (p == 0) ? ldw1 : (p == 1) ? ldw2 : ldw3;
    const int NT = K / 32;
    __builtin_amdgcn_s_barrier();
    stage_tile<BNT>(A, W, lds, lds + 3 * ASZ, m0, n0, lda, ldw, 0, w, lane);
    if (NT > 1)
      stage_tile<BNT>(A, W, lds + ASZ, lds + 3 * ASZ + WSZ, m0, n0, lda, ldw, 1, w, lane);
    for (int kt = 0; kt < NT; ++kt) {
      if (kt + 1 < NT) { WAITV(4); } else { WAITV(0); }
      __builtin_amdgcn_s_barrier();
      __builtin_amdgcn_sched_barrier(0);
      if (kt + 2 < NT) {
        int sb = (kt + 2) % 3;
        stage_tile<BNT>(A, W, lds + sb * ASZ, lds + 3 * ASZ + sb * WSZ,
                        m0, n0, lda, ldw, kt + 2, w, lane);
      }
      int cb_ = kt % 3;
      if (SPLITQ && p == 2)
        comp_tile<FR>(lds + cb_ * ASZ, lds + 3 * ASZ + cb_ * WSZ, wr0, wc0, lane, acc2);
      else
        comp_tile<FR>(lds + cb_ * ASZ, lds + 3 * ASZ + cb_ * WSZ, wr0, wc0, lane, acc);
    }
  }

  const int lo = lane & 15, hi = lane >> 4;
  if (OUTMODE == 0) {
    const int cb = n0 + wc0 + lo;
    const int r0 = m0 + wr0 + hi * 4;
    #pragma unroll
    for (int j = 0; j < 4; ++j) {
      int col = cb + j * 16;
      if (col >= N) continue;
      float bv1 = b1 ? b1[col] : 0.f;
      float bv2 = (NPASS == 2 && b2) ? b2[col] : 0.f;
      float bq  = (SPLITQ && b2) ? b2[col] : 0.f;
      #pragma unroll
      for (int i = 0; i < FR; ++i) {
        #pragma unroll
        for (int jj = 0; jj < 4; ++jj) {
          int row = r0 + i * 16 + jj;
          if (row >= M) continue;
          float v = acc[i][j][jj] + bv1 + bv2;
          if (SPLITQ) v = fmaxf(v, 0.f) + fmaxf(acc2[i][j][jj] + bq, 0.f);
          else if (ACT == 1) v = fmaxf(v, 0.f);
          else if (ACT == 2) v = tanh_fast(v);
          ((float*)Cv)[(long)row * ldc + col] = v;
        }
      }
    }
  } else {
    // f16 repack epilogue: acc -> per-wave LDS scratch -> half8 stores.
    __syncthreads();
    _Float16* scr = lds + w * 64 * 72;
    #pragma unroll
    for (int j = 0; j < 4; ++j) {
      int col = n0 + wc0 + 16 * j + lo;
      float bv1 = (b1 && col < N) ? b1[col] : 0.f;
      float bv2 = (NPASS == 2 && b2 && col < N) ? b2[col] : 0.f;
      #pragma unroll
      for (int i = 0; i < FR; ++i) {
        #pragma unroll
        for (int jj = 0; jj < 4; ++jj) {
          float v = acc[i][j][jj] + bv1 + bv2;
          if (ACT == 1) v = fmaxf(v, 0.f);
          if (ACT == 2) v = tanh_fast(v);
          if (OUTMODE == 2) v = __expf(fminf(v, 10.f));
          scr[(16 * i + 4 * hi + jj) * 72 + 16 * j + lo] = (_Float16)v;
        }
      }
    }
    const int rl = lane >> 3, cl = (lane & 7) * 8;
    #pragma unroll
    for (int it = 0; it < 8; ++it) {
      half8 hv = *(const half8*)&scr[(it * 8 + rl) * 72 + cl];
      int row = m0 + wr0 + it * 8 + rl;
      int col = n0 + wc0 + cl;
      if (row < M && col < nwr) {
        if (OUTMODE == 1 || OUTMODE == 2) {
          *(half8*)&((_Float16*)Cv)[(long)row * ldc + col] = hv;
        } else {
          int which = col >> 9, c = col & 511;
          _Float16* dp = (which == 0) ? (_Float16*)Cv
                       : (which == 1) ? const_cast<_Float16*>(A2)
                                      : const_cast<_Float16*>(A3);
          *(half8*)&dp[(long)row * 512 + c] = hv;
        }
      }
      if (OUTMODE == 2) {
        float s = 0.f;
        #pragma unroll
        for (int k = 0; k < 8; ++k)
          if (col + k < 900) s += (float)hv[k];
        #pragma unroll
        for (int m = 1; m <= 4; m <<= 1) s += __shfl_xor(s, m, 64);
        if ((lane & 7) == 0 && row < M) atomicAdd(&rsum[row], s);
      }
    }
  }
}

// ---------------------------------------------------------------------------
// out2 = E @ q3 / rsum (fused softmax denominator), grid.z = 32 batches.
// ---------------------------------------------------------------------------
__global__ __launch_bounds__(256, 2)
void mfma_out2(const _Float16* __restrict__ Sh, const _Float16* __restrict__ q3T,
               _Float16* __restrict__ C, const float* __restrict__ rsum)
{
  constexpr int ASZ = 128 * 32;
  __shared__ _Float16 lds[6 * ASZ];
  const int tid = threadIdx.x, w = tid >> 6, lane = tid & 63;
  const int z = blockIdx.z;
  const _Float16* A = Sh + (long)z * 900 * SPAD;
  const _Float16* W = q3T + ((long)z * 512) * SPAD;
  _Float16* Cz = C + (long)z * 900 * 512;
  int mt, nt;
  swz2(mt, nt);
  const int m0 = mt * 128, n0 = nt * 128;
  const int wr0 = (w >> 1) * 64, wc0 = (w & 1) * 64;
  f32x4 acc[4][4] = {};
  const int NT = SPAD / 32;
  stage_tile<128>(A, W, lds, lds + 3 * ASZ, m0, n0, SPAD, SPAD, 0, w, lane);
  stage_tile<128>(A, W, lds + ASZ, lds + 4 * ASZ, m0, n0, SPAD, SPAD, 1, w, lane);
  for (int kt = 0; kt < NT; ++kt) {
    if (kt + 1 < NT) { WAITV(4); } else { WAITV(0); }
    __builtin_amdgcn_s_barrier();
    __builtin_amdgcn_sched_barrier(0);
    if (kt + 2 < NT) {
      int sb = (kt + 2) % 3;
      stage_tile<128>(A, W, lds + sb * ASZ, lds + (3 + sb) * ASZ,
                      m0, n0, SPAD, SPAD, kt + 2, w, lane);
    }
    int cb_ = kt % 3;
    comp_tile<4>(lds + cb_ * ASZ, lds + (3 + cb_) * ASZ, wr0, wc0, lane, acc);
  }
  __syncthreads();
  const int lo = lane & 15, hi = lane >> 4;
  _Float16* scr = lds + w * 64 * 72;
  #pragma unroll
  for (int i = 0; i < 4; ++i)
    #pragma unroll
    for (int jj = 0; jj < 4; ++jj) {
      int rloc = m0 + wr0 + 16 * i + 4 * hi + jj;
      float inv = (rloc < 900) ? 1.f / rsum[z * 900 + rloc] : 0.f;
      #pragma unroll
      for (int j = 0; j < 4; ++j)
        scr[(16 * i + 4 * hi + jj) * 72 + 16 * j + lo] =
            (_Float16)(acc[i][j][jj] * inv);
    }
  const int rl = lane >> 3, cl = (lane & 7) * 8;
  #pragma unroll
  for (int it = 0; it < 8; ++it) {
    half8 hv = *(const half8*)&scr[(it * 8 + rl) * 72 + cl];
    int row = m0 + wr0 + it * 8 + rl;
    if (row < 900)
      *(half8*)&Cz[(long)row * 512 + n0 + wc0 + cl] = hv;
  }
}

// ---------------------------------------------------------------------------
// MFMA fused attention (round-7, verified).
// ---------------------------------------------------------------------------
__global__ __launch_bounds__(256, 2)
void attn_mfma(const _Float16* __restrict__ Q, const float* __restrict__ Lt,
               const float* __restrict__ lmask, _Float16* __restrict__ O)
{
  __shared__ _Float16 ltN[32 * 512];
  __shared__ _Float16 Qs[2][128 * 32];
  __shared__ float smask[32];
  _Float16* P = Qs[0];

  const int z = blockIdx.y;
  const int m0 = blockIdx.x * 128;
  const int tid = threadIdx.x, w = tid >> 6, lane = tid & 63;
  const int lo = lane & 15, hi = lane >> 4;
  const int wr0 = w * 32;
  const long rowbase = (long)z * HW_ + m0;

  const float* Lb = Lt + (long)z * NL_ * DIM_;
  for (int i = tid; i < NL_ * 256; i += 256) {
    int n = i >> 8, d = (i & 255) * 2;
    float2 v2 = *(const float2*)&Lb[n * DIM_ + d];
    int c0 = (((d >> 3) ^ (n & 7)) << 3) + (d & 7);
    ltN[n * 512 + c0]     = (_Float16)v2.x;
    ltN[n * 512 + c0 + 1] = (_Float16)v2.y;
  }
  for (int i = tid; i < 12 * 512; i += 256)
    ltN[(20 + (i >> 9)) * 512 + (i & 511)] = (_Float16)0.f;
  if (tid < 32)
    smask[tid] = (tid < NL_) ? 10000.f * lmask[z * NL_ + tid] - 10000.f : -1e30f;

  f32x4 accS[2][2] = {};
  const int csA = hi ^ ((lo >> 1) & 3);
  stage_q(Q, rowbase, Qs[0], 0, w, lane);
  __syncthreads();
  for (int kt = 0; kt < 16; ++kt) {
    if (kt + 1 < 16) stage_q(Q, rowbase, Qs[(kt + 1) & 1], kt + 1, w, lane);
    const _Float16* Qc = Qs[kt & 1];
    half8 a0 = *(const half8*)&Qc[(wr0 + lo) * 32 + csA * 8];
    half8 a1 = *(const half8*)&Qc[(wr0 + 16 + lo) * 32 + csA * 8];
    int co = (((kt * 4 + hi) ^ (lo & 7)) << 3);
    half8 b0 = *(const half8*)&ltN[lo * 512 + co];
    half8 b1 = *(const half8*)&ltN[(16 + lo) * 512 + co];
    accS[0][0] = MFMA16(a0, b0, accS[0][0]);
    accS[0][1] = MFMA16(a0, b1, accS[0][1]);
    accS[1][0] = MFMA16(a1, b0, accS[1][0]);
    accS[1][1] = MFMA16(a1, b1, accS[1][1]);
    __syncthreads();
  }

  #pragma unroll
  for (int i = 0; i < 2; ++i)
    #pragma unroll
    for (int jj = 0; jj < 4; ++jj) {
      float v0 = accS[i][0][jj] + smask[lo];
      float v1 = accS[i][1][jj] + smask[16 + lo];
      float mx = fmaxf(v0, v1);
      #pragma unroll
      for (int m = 1; m <= 8; m <<= 1) mx = fmaxf(mx, __shfl_xor(mx, m, 64));
      float e0 = __expf(v0 - mx), e1 = __expf(v1 - mx);
      float s = e0 + e1;
      #pragma unroll
      for (int m = 1; m <= 8; m <<= 1) s += __shfl_xor(s, m, 64);
      float iv = 1.f / s;
      int r = wr0 + 16 * i + 4 * hi + jj;
      int key = (r >> 1) & 3;
      P[r * 32 + ((((lo >> 3) ^ key) << 3) + (lo & 7))]       = (_Float16)(e0 * iv);
      P[r * 32 + ((((2 + (lo >> 3)) ^ key) << 3) + (lo & 7))] = (_Float16)(e1 * iv);
    }
  __syncthreads();

  half8 pa0 = *(const half8*)&P[(wr0 + lo) * 32 + csA * 8];
  half8 pa1 = *(const half8*)&P[(wr0 + 16 + lo) * 32 + csA * 8];
  for (int dc = 0; dc < 4; ++dc) {
    f32x4 accO[2][8] = {};
    #pragma unroll
    for (int cf = 0; cf < 8; ++cf) {
      int d = dc * 128 + cf * 16 + lo;
      int dsl = d >> 3, dw = d & 7;
      half8 bf;
      #pragma unroll
      for (int i2 = 0; i2 < 8; ++i2)
        bf[i2] = ltN[(8 * hi + i2) * 512 + (((dsl ^ i2) << 3) + dw)];
      accO[0][cf] = MFMA16(pa0, bf, accO[0][cf]);
      accO[1][cf] = MFMA16(pa1, bf, accO[1][cf]);
    }
    #pragma unroll
    for (int i = 0; i < 2; ++i)
      #pragma unroll
      for (int cf = 0; cf < 8; ++cf)
        #pragma unroll
        for (int jj = 0; jj < 4; ++jj) {
          int rloc = m0 + wr0 + 16 * i + 4 * hi + jj;
          if (rloc < HW_) {
            int d = dc * 128 + cf * 16 + lo;
            O[((long)z * HW_ + rloc) * 512 + d] = (_Float16)accO[i][cf][jj];
          }
        }
  }
}

// ---------------------------------------------------------------------------
// Batched 64x64 LDS-tiled transpose: q3T[b][d][h] = q3[b][h][d].
// ---------------------------------------------------------------------------
__global__ __launch_bounds__(256)
void transpose_q3(const _Float16* __restrict__ q3, _Float16* __restrict__ q3T)
{
  __shared__ _Float16 t[64][72];
  const int b = blockIdx.z;
  const int h0 = blockIdx.x * 64, d0 = blockIdx.y * 64;
  const int tid = threadIdx.x;
  const int r = tid >> 2, c0 = (tid & 3) * 16;
  half8 v0 = {}, v1 = {};
  if (h0 + r < 900) {
    const _Float16* src = q3 + ((long)b * 900 + h0 + r) * 512 + d0 + c0;
    v0 = *(const half8*)src;
    v1 = *(const half8*)(src + 8);
  }
  *(half8*)&t[r][c0] = v0;
  *(half8*)&t[r][c0 + 8] = v1;
  __syncthreads();
  const int dr = tid >> 2, hcb = (tid & 3) * 16;
  _Float16* dst = q3T + ((long)b * 512 + d0 + dr) * SPAD;
  #pragma unroll
  for (int s = 0; s < 2; ++s) {
    int hc = hcb + s * 8;
    if (h0 + hc + 8 <= SPAD) {
      half8 v;
      #pragma unroll
      for (int k = 0; k < 8; ++k) {
        int h = h0 + hc + k;
        v[k] = (h < 900) ? t[hc + k][dr] : (_Float16)0.f;
      }
      *(half8*)&dst[h0 + hc] = v;
    }
  }
}

// ---------------------------------------------------------------------------
// Transpose l -> f16 + concat q-biases + zero rsum.
// ---------------------------------------------------------------------------
__global__ __launch_bounds__(256)
void transpose_l(const float* __restrict__ l, _Float16* __restrict__ Ltr,
                 const float* __restrict__ bv1, const float* __restrict__ bv2,
                 const float* __restrict__ bv3, float* __restrict__ bcat,
                 float* __restrict__ rsum)
{
  const int b = blockIdx.x;
  if (b < 6) {
    int i = b * 256 + threadIdx.x;
    if (i < 1536)
      bcat[i] = (i < 512) ? bv1[i] : (i < 1024) ? bv2[i - 512] : bv3[i - 1024];
  }
  for (int i = b * 256 + threadIdx.x; i < 28800; i += 32 * 256)
    rsum[i] = 0.f;
  const float* lb = l + (long)b * LIN_ * NL_;
  _Float16* ob = Ltr + (long)b * NL_ * LIN_;
  for (int i = threadIdx.x; i < LIN_ * NL_; i += 256) {
    int c = i / NL_, n = i % NL_;
    ob[(long)n * LIN_ + c] = (_Float16)lb[i];
  }
}

// ---------------------------------------------------------------------------
__global__ __launch_bounds__(256)
void cvt_x(const float* __restrict__ src, _Float16* __restrict__ dst, long n8)
{
  const float4* s4 = (const float4*)src;
  half8* d = (half8*)dst;
  for (long i = (long)blockIdx.x * 256 + threadIdx.x; i < n8;
       i += (long)gridDim.x * 256) {
    float4 u = s4[2 * i], v = s4[2 * i + 1];
    half8 h;
    h[0] = (_Float16)u.x; h[1] = (_Float16)u.y; h[2] = (_Float16)u.z; h[3] = (_Float16)u.w;
    h[4] = (_Float16)v.x; h[5] = (_Float16)v.y; h[6] = (_Float16)v.z; h[7] = (_Float16)v.w;
    d[i] = h;
  }
}

__global__ __launch_bounds__(256)
void cvt_w(const float* s0, const float* s1, const float* s2, const float* s3,
           const float* s4, const float* s5, const float* s6, const float* s7,
           const float* s8, _Float16* __restrict__ dst)
{
  const long off[10] = {0, 262144, 524288, 786432, 1048576, 1310720,
                        1572864, 1966080, 2426880, 2951168};
  const int t = blockIdx.y;
  const float* src;
  switch (t) {
    case 0: src = s0; break; case 1: src = s1; break; case 2: src = s2; break;
    case 3: src = s3; break; case 4: src = s4; break; case 5: src = s5; break;
    case 6: src = s6; break; case 7: src = s7; break; default: src = s8; break;
  }
  long n8 = (off[t + 1] - off[t]) >> 3;
  const float4* s4p = (const float4*)src;
  half8* d = (half8*)(dst + off[t]);
  for (long i = (long)blockIdx.x * 256 + threadIdx.x; i < n8;
       i += (long)gridDim.x * 256) {
    float4 u = s4p[2 * i], v = s4p[2 * i + 1];
    half8 h;
    h[0] = (_Float16)u.x; h[1] = (_Float16)u.y; h[2] = (_Float16)u.z; h[3] = (_Float16)u.w;
    h[4] = (_Float16)v.x; h[5] = (_Float16)v.y; h[6] = (_Float16)v.z; h[7] = (_Float16)v.w;
    d[i] = h;
  }
}

// ---------------------------------------------------------------------------
__global__ void diag_kernel(float* out, long n, float ws_mb)
{
  long i = (long)blockIdx.x * 256 + threadIdx.x;
  if (i < n) out[i] = 0.f;
  if (i == 0) out[0] = ws_mb;
}

// ---------------------------------------------------------------------------
extern "C" void kernel_launch(void* const* d_in, const int* in_sizes, int n_in,
                              void* d_out, int out_size, void* d_ws, size_t ws_size,
                              hipStream_t stream) {
  const float* x      = (const float*)d_in[0];
  const float* l      = (const float*)d_in[1];
  const float* lmask  = (const float*)d_in[2];
  const float* W_lang = (const float*)d_in[3];
  const float* b_lang = (const float*)d_in[4];
  const float* W_v1   = (const float*)d_in[5];  const float* b_v1   = (const float*)d_in[6];
  const float* W_v2   = (const float*)d_in[7];  const float* b_v2   = (const float*)d_in[8];
  const float* W_v3   = (const float*)d_in[9];  const float* b_v3   = (const float*)d_in[10];
  const float* W_v4   = (const float*)d_in[11]; const float* b_v4   = (const float*)d_in[12];
  const float* W_out1 = (const float*)d_in[13]; const float* b_out1 = (const float*)d_in[14];
  const float* W_v22  = (const float*)d_in[15]; const float* b_v22  = (const float*)d_in[16];
  const float* W_a    = (const float*)d_in[17]; const float* b_a    = (const float*)d_in[18];
  const float* W_o3   = (const float*)d_in[19]; const float* b_o3   = (const float*)d_in[20];
  float* out = (float*)d_out;

  const long NC16 = 28800L * 512;
  const size_t need =
      4 * (size_t)NC16 * 2
      + (size_t)32 * 512 * SPAD * 2
      + (size_t)640 * 512 * 4
      + (size_t)BATCH * NL_ * LIN_ * 2
      + (size_t)7200 * SPAD * 2
      + (size_t)2951168 * 2
      + 6144 + 115200;
  if (ws_size < need) {
    long n = (long)out_size;
    diag_kernel<<<dim3((unsigned)((n + 255) / 256)), dim3(256), 0, stream>>>(
        out, n, (float)(ws_size >> 20));
    return;
  }

  _Float16* x16  = (_Float16*)d_ws;
  _Float16* O16  = x16 + NC16;
  _Float16* q2h  = O16 + NC16;
  _Float16* Ap16 = q2h + NC16;
  _Float16* q3T  = Ap16 + NC16;
  float* Lt      = (float*)(q3T + 32L * 512 * SPAD);
  _Float16* Ltr16 = (_Float16*)(Lt + 640L * 512);
  _Float16* Wh   = Ltr16 + (long)BATCH * NL_ * LIN_ + 7200L * SPAD;
  _Float16 *Wv4h = Wh + 786432, *Wout1h = Wh + 1048576, *Wv22h = Wh + 1310720,
           *Wlangh = Wh + 1572864, *Wah = Wh + 1966080, *Wo3h = Wh + 2426880;
  float* bcat = (float*)(Wh + 2951168);
  float* rsum = bcat + 1536;
  _Float16* Sh  = (_Float16*)out;
  _Float16* q3h = (_Float16*)out;

  dim3 blk(256);

  cvt_x<<<dim3(2048), blk, 0, stream>>>(x, x16, NC16 / 8);
  cvt_w<<<dim3(64, 9), blk, 0, stream>>>(W_v1, W_v2, W_v3, W_v4, W_out1, W_v22,
                                         W_lang, W_a, W_o3, Wh);
  transpose_l<<<dim3(BATCH), blk, 0, stream>>>(l, Ltr16, b_v1, b_v2, b_v3,
                                               bcat, rsum);

  // Lt = Ltr @ W_lang^T + b_lang  -> f32
  mfma_tn<0,1,0,0,128><<<dim3(5, 4), blk, 0, stream>>>(
      Ltr16, Wlangh, nullptr, nullptr, nullptr, nullptr, b_lang, nullptr, Lt,
      640, 512, 768, 768, 768, 0, 0, 0, 0, 0, 0, 512, 512, nullptr);

  // mega-Q: relu(x @ [Wv1|Wv2|Wv3]^T + bcat); q1->Ap16, q2->q2h, q3->d_out
  mfma_tn<1,1,0,3,128><<<dim3(225, 12), blk, 0, stream>>>(
      x16, Wh, q2h, nullptr, q3h, nullptr, bcat, nullptr, Ap16,
      28800, 1536, 512, 512, 512, 0, 0, 0, 0, 0, 0, 512, 1536, nullptr);

  // q3T[b][d][h] = q3[b][h][d]
  transpose_q3<<<dim3(15, 8, 32), blk, 0, stream>>>(q3h, q3T);

  // attention: O16 = softmax(q1 Lt^T + mask) Lt
  attn_mfma<<<dim3(8, 32), blk, 0, stream>>>(Ap16, Lt, lmask, O16);

  // Apre = tanh(O W_out1^T + q2 W_v22^T + b + b) -> f16 (overwrites q1)
  mfma_tn<2,2,0,1,128><<<dim3(225, 4), blk, 0, stream>>>(
      O16, Wout1h, q2h, Wv22h, nullptr, nullptr, b_out1, b_v22, Ap16,
      28800, 512, 512, 512, 512, 512, 512, 512, 0, 0, 0, 512, 512, nullptr);

  // E = exp(Apre @ W_a^T + b_a) -> f16 Sh (in d_out) + row sums -> rsum
  mfma_tn<0,1,0,2,128><<<dim3(225, 8), blk, 0, stream>>>(
      Ap16, Wah, nullptr, nullptr, nullptr, nullptr, b_a, nullptr, Sh,
      28800, 900, 512, 512, 512, 0, 0, 0, 0, 0, 0, SPAD, SPAD, rsum);

  // out2 = E @ q3 / rsum -> Ap16 (overwrites Apre)
  mfma_out2<<<dim3(8, 4, 32), blk, 0, stream>>>(Sh, q3T, Ap16, rsum);

  // out = relu(out2 Wo3a + O Wo3b + b_o3) + relu(x Wv4 + b_v4) -> f32
  mfma_tn<0,3,1,0,128><<<dim3(225, 4), blk, 0, stream>>>(
      Ap16, Wo3h, O16, Wo3h + 512, x16, Wv4h, b_o3, b_v4, out,
      28800, 512, 512, 512, 1024, 512, 512, 1024, 512, 512, 512, 512, 512,
      nullptr);
}